// Round 1
// baseline (9005.075 us; speedup 1.0000x reference)
//
#include <hip/hip_runtime.h>

#define MUL 128

// scale constants
__device__ __constant__ float kINV_UP   = 0.08838834764831845f;  // 1/sqrt(128)
__device__ __constant__ float kINV_L1   = 0.35355339059327373f;  // 1/sqrt(8)
__device__ __constant__ float kINV_L2   = 0.125f;                // 1/sqrt(64)
__device__ __constant__ float kINV_L3   = 0.125f;
__device__ __constant__ float kINV_LIN  = 0.00390625f;           // 1/(sqrt(256)*16)
__device__ __constant__ float kINV_SK   = 0.044194173824159216f; // 1/sqrt(512)
__device__ __constant__ float kINV_SQ3  = 0.5773502691896258f;   // 1/sqrt(3)

// ---------------------------------------------------------------------------
// Kernel A: node up-projection.
//   s_up[n][w]      = sum_u nf[n][u]      * W0[u][w] * inv_up      (w<128)
//   v_up[n][i][w]   = sum_u nf[n][128+3u+i]* W1[u][w] * inv_up     (i<3)
// 16 nodes per block, 256 threads: thread (n = t>>4, g = t&15) does w in [8g,8g+8).
// ---------------------------------------------------------------------------
__global__ __launch_bounds__(256) void k_up(const float* __restrict__ nf,
                                            const float* __restrict__ W0,
                                            const float* __restrict__ W1,
                                            float* __restrict__ s_up,
                                            float* __restrict__ v_up,
                                            int N) {
  __shared__ float lin[16 * 516];  // 512 staged + pad (stride 516 -> bank offset 4n)
  const int nb = blockIdx.x * 16;
  const int t = threadIdx.x;

  for (int idx = t * 4; idx < 16 * 512; idx += 256 * 4) {
    int n = idx >> 9, w = idx & 511;
    if (nb + n < N) {
      float4 v = *reinterpret_cast<const float4*>(nf + (size_t)(nb + n) * 512 + w);
      *reinterpret_cast<float4*>(&lin[n * 516 + w]) = v;
    }
  }
  __syncthreads();

  const int n = t >> 4, g = t & 15, w0 = g * 8;
  const int node = nb + n;
  if (node >= N) return;

  float accs[8] = {};
  float accv[3][8] = {};
  const float* base = &lin[n * 516];

  for (int u = 0; u < 128; ++u) {
    float4 a0 = *reinterpret_cast<const float4*>(W0 + u * 128 + w0);
    float4 a1 = *reinterpret_cast<const float4*>(W0 + u * 128 + w0 + 4);
    float4 b0 = *reinterpret_cast<const float4*>(W1 + u * 128 + w0);
    float4 b1 = *reinterpret_cast<const float4*>(W1 + u * 128 + w0 + 4);
    float su = base[u];
    float v0 = base[128 + u * 3 + 0];
    float v1 = base[128 + u * 3 + 1];
    float v2 = base[128 + u * 3 + 2];
    float wa[8] = {a0.x, a0.y, a0.z, a0.w, a1.x, a1.y, a1.z, a1.w};
    float wb[8] = {b0.x, b0.y, b0.z, b0.w, b1.x, b1.y, b1.z, b1.w};
#pragma unroll
    for (int j = 0; j < 8; ++j) {
      accs[j]    += su * wa[j];
      accv[0][j] += v0 * wb[j];
      accv[1][j] += v1 * wb[j];
      accv[2][j] += v2 * wb[j];
    }
  }

  {
    float4 x0, x1;
    x0.x = accs[0] * kINV_UP; x0.y = accs[1] * kINV_UP; x0.z = accs[2] * kINV_UP; x0.w = accs[3] * kINV_UP;
    x1.x = accs[4] * kINV_UP; x1.y = accs[5] * kINV_UP; x1.z = accs[6] * kINV_UP; x1.w = accs[7] * kINV_UP;
    *reinterpret_cast<float4*>(s_up + (size_t)node * 128 + w0) = x0;
    *reinterpret_cast<float4*>(s_up + (size_t)node * 128 + w0 + 4) = x1;
  }
#pragma unroll
  for (int i = 0; i < 3; ++i) {
    float4 x0, x1;
    x0.x = accv[i][0] * kINV_UP; x0.y = accv[i][1] * kINV_UP; x0.z = accv[i][2] * kINV_UP; x0.w = accv[i][3] * kINV_UP;
    x1.x = accv[i][4] * kINV_UP; x1.y = accv[i][5] * kINV_UP; x1.z = accv[i][6] * kINV_UP; x1.w = accv[i][7] * kINV_UP;
    *reinterpret_cast<float4*>(v_up + (size_t)node * 384 + i * 128 + w0) = x0;
    *reinterpret_cast<float4*>(v_up + (size_t)node * 384 + i * 128 + w0 + 4) = x1;
  }
}

// ---------------------------------------------------------------------------
// Kernel B: per-edge MLP + messages + atomic segment sum.
// 32 edges per block, 256 threads: thread (el = t>>3, c = t&7).
// tpw columns: [0,128)=w_a [128,256)=w_b [256,384)=w_c [384,512)=w_d; chunk c
// owns columns [64c, 64c+64) so each thread handles exactly one message type.
// Ms layout [n][u] (u<256: m0 then m1). Mv layout [n][i][u] (u<256: m2 then m3).
// ---------------------------------------------------------------------------
__global__ __launch_bounds__(256) void k_edge(const float* __restrict__ ef,
                                              const float* __restrict__ eattr,
                                              const int* __restrict__ eidx,
                                              const float* __restrict__ W1,
                                              const float* __restrict__ W2,
                                              const float* __restrict__ W3,
                                              const float* __restrict__ s_up,
                                              const float* __restrict__ v_up,
                                              float* __restrict__ Ms,
                                              float* __restrict__ Mv,
                                              int E) {
  __shared__ float sW1[8 * 64];
  __shared__ float sW2[64 * 64];
  __shared__ float sef[32][12];     // stride 12 breaks bank aliasing, keeps 16B align
  __shared__ float sh1[32][65];
  __shared__ float sh2[32][65];
  __shared__ float sea[32][4];
  __shared__ int   ssnd[32], srcv[32];

  const int t = threadIdx.x;
  const int eb = blockIdx.x * 32;
  if (eb >= E) return;

  for (int i = t * 4; i < 512; i += 1024)
    *reinterpret_cast<float4*>(&sW1[i]) = *reinterpret_cast<const float4*>(W1 + i);
  for (int i = t * 4; i < 4096; i += 1024)
    *reinterpret_cast<float4*>(&sW2[i]) = *reinterpret_cast<const float4*>(W2 + i);
  if (t < 32) {
    int e = eb + t;
    ssnd[t] = eidx[e];
    srcv[t] = eidx[E + e];
    *reinterpret_cast<float4*>(sea[t]) = *reinterpret_cast<const float4*>(eattr + (size_t)e * 4);
  }
  for (int i = t * 4; i < 32 * 8; i += 1024) {
    int e = i >> 3, k = i & 7;
    *reinterpret_cast<float4*>(&sef[e][k]) = *reinterpret_cast<const float4*>(ef + (size_t)(eb + e) * 8 + k);
  }
  __syncthreads();

  const int el = t >> 3;
  const int c  = t & 7;

  // layer 1 -> sh1
  {
    float acc[8] = {};
#pragma unroll
    for (int k = 0; k < 8; ++k) {
      float x = sef[el][k];
#pragma unroll
      for (int j = 0; j < 8; ++j) acc[j] += x * sW1[k * 64 + c * 8 + j];
    }
#pragma unroll
    for (int j = 0; j < 8; ++j) {
      float x = acc[j] * kINV_L1;
      sh1[el][c * 8 + j] = x / (1.f + __expf(-x));
    }
  }
  __syncthreads();

  // layer 2 -> sh2
  {
    float acc[8] = {};
    for (int k = 0; k < 64; ++k) {
      float x = sh1[el][k];
#pragma unroll
      for (int j = 0; j < 8; ++j) acc[j] += x * sW2[k * 64 + c * 8 + j];
    }
#pragma unroll
    for (int j = 0; j < 8; ++j) {
      float x = acc[j] * kINV_L2;
      sh2[el][c * 8 + j] = x / (1.f + __expf(-x));
    }
  }
  __syncthreads();

  // layer 3: 64 tpw columns per thread, streamed W3 (L1/L2 resident)
  float tp[64];
#pragma unroll
  for (int i = 0; i < 64; ++i) tp[i] = 0.f;
  const float* W3c = W3 + c * 64;
  for (int k = 0; k < 64; ++k) {
    float x = sh2[el][k];
    const float* row = W3c + (size_t)k * 512;
#pragma unroll
    for (int q = 0; q < 16; ++q) {
      float4 w = *reinterpret_cast<const float4*>(row + q * 4);
      tp[q * 4 + 0] += x * w.x;
      tp[q * 4 + 1] += x * w.y;
      tp[q * 4 + 2] += x * w.z;
      tp[q * 4 + 3] += x * w.w;
    }
  }

  const int snd = ssnd[el], rcv = srcv[el];
  const float eas = sea[el][0];
  const float ev0 = sea[el][1], ev1 = sea[el][2], ev2 = sea[el][3];
  const int ub = (c & 1) * 64;

  if (c < 2) {  // w_a -> m0 -> Ms[rcv][u]
    const float* xs = s_up + (size_t)snd * 128 + ub;
    float* dst = Ms + (size_t)rcv * 256 + ub;
#pragma unroll 4
    for (int oo = 0; oo < 64; ++oo) {
      float m = tp[oo] * kINV_L3 * xs[oo] * eas;
      atomicAdd(dst + oo, m);
    }
  } else if (c < 4) {  // w_b -> m1 -> Ms[rcv][128+u]
    const float* xv = v_up + (size_t)snd * 384;
    float* dst = Ms + (size_t)rcv * 256 + 128 + ub;
#pragma unroll 4
    for (int oo = 0; oo < 64; ++oo) {
      int u = ub + oo;
      float dot = xv[u] * ev0 + xv[128 + u] * ev1 + xv[256 + u] * ev2;
      float m = tp[oo] * kINV_L3 * dot * kINV_SQ3;
      atomicAdd(dst + oo, m);
    }
  } else if (c < 6) {  // w_c -> m2 -> Mv[rcv][i][u]
    const float* xs = s_up + (size_t)snd * 128 + ub;
    float* dst = Mv + (size_t)rcv * 768;
#pragma unroll 2
    for (int oo = 0; oo < 64; ++oo) {
      int u = ub + oo;
      float wc = tp[oo] * kINV_L3 * xs[oo];
      atomicAdd(dst + u,        wc * ev0);
      atomicAdd(dst + 256 + u,  wc * ev1);
      atomicAdd(dst + 512 + u,  wc * ev2);
    }
  } else {  // w_d -> m3 -> Mv[rcv][i][128+u]
    const float* xv = v_up + (size_t)snd * 384;
    float* dst = Mv + (size_t)rcv * 768 + 128;
#pragma unroll 2
    for (int oo = 0; oo < 64; ++oo) {
      int u = ub + oo;
      float wd = tp[oo] * kINV_L3 * eas;
      atomicAdd(dst + u,        wd * xv[u]);
      atomicAdd(dst + 256 + u,  wd * xv[128 + u]);
      atomicAdd(dst + 512 + u,  wd * xv[256 + u]);
    }
  }
}

// ---------------------------------------------------------------------------
// Kernel C1: linear after aggregation.
//   S[n][w]    = sum_{u<256} Ms[n][u]    * Wl0[u][w] * inv_lin
//   V[n][i][w] = sum_{u<256} Mv[n][i][u] * Wl1[u][w] * inv_lin
// ---------------------------------------------------------------------------
__global__ __launch_bounds__(256) void k_lin(const float* __restrict__ Ms,
                                             const float* __restrict__ Mv,
                                             const float* __restrict__ Wl0,
                                             const float* __restrict__ Wl1,
                                             float* __restrict__ S,
                                             float* __restrict__ V,
                                             int N) {
  __shared__ float lms[16 * 260];
  __shared__ float lmv[16 * 772];
  const int nb = blockIdx.x * 16;
  const int t = threadIdx.x;

  for (int i = t * 4; i < 16 * 256; i += 1024) {
    int n = i >> 8, u = i & 255;
    if (nb + n < N)
      *reinterpret_cast<float4*>(&lms[n * 260 + u]) =
          *reinterpret_cast<const float4*>(Ms + (size_t)(nb + n) * 256 + u);
  }
  for (int i = t * 4; i < 16 * 768; i += 1024) {
    int n = i / 768, j = i % 768;
    if (nb + n < N)
      *reinterpret_cast<float4*>(&lmv[n * 772 + j]) =
          *reinterpret_cast<const float4*>(Mv + (size_t)(nb + n) * 768 + j);
  }
  __syncthreads();

  const int n = t >> 4, g = t & 15, w0 = g * 8;
  const int node = nb + n;
  if (node >= N) return;

  float accs[8] = {};
  float accv[3][8] = {};
  for (int u = 0; u < 256; ++u) {
    float4 a0 = *reinterpret_cast<const float4*>(Wl0 + u * 128 + w0);
    float4 a1 = *reinterpret_cast<const float4*>(Wl0 + u * 128 + w0 + 4);
    float4 b0 = *reinterpret_cast<const float4*>(Wl1 + u * 128 + w0);
    float4 b1 = *reinterpret_cast<const float4*>(Wl1 + u * 128 + w0 + 4);
    float msu = lms[n * 260 + u];
    float m0 = lmv[n * 772 + u];
    float m1 = lmv[n * 772 + 256 + u];
    float m2 = lmv[n * 772 + 512 + u];
    float wa[8] = {a0.x, a0.y, a0.z, a0.w, a1.x, a1.y, a1.z, a1.w};
    float wb[8] = {b0.x, b0.y, b0.z, b0.w, b1.x, b1.y, b1.z, b1.w};
#pragma unroll
    for (int j = 0; j < 8; ++j) {
      accs[j]    += msu * wa[j];
      accv[0][j] += m0 * wb[j];
      accv[1][j] += m1 * wb[j];
      accv[2][j] += m2 * wb[j];
    }
  }

  {
    float4 x0, x1;
    x0.x = accs[0] * kINV_LIN; x0.y = accs[1] * kINV_LIN; x0.z = accs[2] * kINV_LIN; x0.w = accs[3] * kINV_LIN;
    x1.x = accs[4] * kINV_LIN; x1.y = accs[5] * kINV_LIN; x1.z = accs[6] * kINV_LIN; x1.w = accs[7] * kINV_LIN;
    *reinterpret_cast<float4*>(S + (size_t)node * 128 + w0) = x0;
    *reinterpret_cast<float4*>(S + (size_t)node * 128 + w0 + 4) = x1;
  }
#pragma unroll
  for (int i = 0; i < 3; ++i) {
    float4 x0, x1;
    x0.x = accv[i][0] * kINV_LIN; x0.y = accv[i][1] * kINV_LIN; x0.z = accv[i][2] * kINV_LIN; x0.w = accv[i][3] * kINV_LIN;
    x1.x = accv[i][4] * kINV_LIN; x1.y = accv[i][5] * kINV_LIN; x1.z = accv[i][6] * kINV_LIN; x1.w = accv[i][7] * kINV_LIN;
    *reinterpret_cast<float4*>(V + (size_t)node * 384 + i * 128 + w0) = x0;
    *reinterpret_cast<float4*>(V + (size_t)node * 384 + i * 128 + w0 + 4) = x1;
  }
}

// ---------------------------------------------------------------------------
// Kernel C2: skip contraction + combine + output.
//   sc_s[n][w]    = sum_{u,v} S[n][u]    * attr[n][v] * Wsk0[u][v][w] * inv_sk
//   sc_v[n][i][w] = sum_{u,v} V[n][i][u] * attr[n][v] * Wsk1[u][v][w] * inv_sk
//   out[n][w][0]   = c_old*S + c_new*sc_s ; out[n][w][1+i] = c_old*V + c_new*sc_v
// ---------------------------------------------------------------------------
__global__ __launch_bounds__(256) void k_skip(const float* __restrict__ S,
                                              const float* __restrict__ V,
                                              const float* __restrict__ attrs,
                                              const float* __restrict__ Wsk0,
                                              const float* __restrict__ Wsk1,
                                              const float* __restrict__ upd,
                                              float* __restrict__ out,
                                              int N) {
  __shared__ float ls[16 * 520];  // per node: S[0,128) V[128,512) attrs[512,516)
  const int nb = blockIdx.x * 16;
  const int t = threadIdx.x;

  for (int i = t * 4; i < 16 * 128; i += 1024) {
    int n = i >> 7, w = i & 127;
    if (nb + n < N)
      *reinterpret_cast<float4*>(&ls[n * 520 + w]) =
          *reinterpret_cast<const float4*>(S + (size_t)(nb + n) * 128 + w);
  }
  for (int i = t * 4; i < 16 * 384; i += 1024) {
    int n = i / 384, j = i % 384;
    if (nb + n < N)
      *reinterpret_cast<float4*>(&ls[n * 520 + 128 + j]) =
          *reinterpret_cast<const float4*>(V + (size_t)(nb + n) * 384 + j);
  }
  if (t < 16 && nb + t < N)
    *reinterpret_cast<float4*>(&ls[t * 520 + 512]) =
        *reinterpret_cast<const float4*>(attrs + (size_t)(nb + t) * 4);
  __syncthreads();

  const int n = t >> 4, g = t & 15, w0 = g * 8;
  const int node = nb + n;
  if (node >= N) return;

  const float av[4] = {ls[n * 520 + 512], ls[n * 520 + 513], ls[n * 520 + 514], ls[n * 520 + 515]};
  float accs[8] = {};
  float accv[3][8] = {};

  for (int u = 0; u < 128; ++u) {
    float su = ls[n * 520 + u];
    float v0 = ls[n * 520 + 128 + u];
    float v1 = ls[n * 520 + 256 + u];
    float v2 = ls[n * 520 + 384 + u];
    const float* r0 = Wsk0 + (size_t)(u * 4) * 128 + w0;
    const float* r1 = Wsk1 + (size_t)(u * 4) * 128 + w0;
#pragma unroll
    for (int v = 0; v < 4; ++v) {
      float a = av[v];
      float cs = su * a;
      float c0 = v0 * a, c1 = v1 * a, c2 = v2 * a;
      float4 q0 = *reinterpret_cast<const float4*>(r0 + v * 128);
      float4 q1 = *reinterpret_cast<const float4*>(r0 + v * 128 + 4);
      float4 p0 = *reinterpret_cast<const float4*>(r1 + v * 128);
      float4 p1 = *reinterpret_cast<const float4*>(r1 + v * 128 + 4);
      float wq[8] = {q0.x, q0.y, q0.z, q0.w, q1.x, q1.y, q1.z, q1.w};
      float wp[8] = {p0.x, p0.y, p0.z, p0.w, p1.x, p1.y, p1.z, p1.w};
#pragma unroll
      for (int j = 0; j < 8; ++j) {
        accs[j]    += cs * wq[j];
        accv[0][j] += c0 * wp[j];
        accv[1][j] += c1 * wp[j];
        accv[2][j] += c2 * wp[j];
      }
    }
  }

  const float p = upd[0];
  const float cc = 1.f / (1.f + __expf(-p));
  const float c_old = rsqrtf(cc * cc + 1.f);
  const float c_new = cc * c_old;

#pragma unroll
  for (int j = 0; j < 8; ++j) {
    int w = w0 + j;
    float4 o;
    o.x = c_old * ls[n * 520 + w]        + c_new * accs[j]    * kINV_SK;
    o.y = c_old * ls[n * 520 + 128 + w]  + c_new * accv[0][j] * kINV_SK;
    o.z = c_old * ls[n * 520 + 256 + w]  + c_new * accv[1][j] * kINV_SK;
    o.w = c_old * ls[n * 520 + 384 + w]  + c_new * accv[2][j] * kINV_SK;
    *reinterpret_cast<float4*>(out + ((size_t)node * 128 + w) * 4) = o;
  }
}

extern "C" void kernel_launch(void* const* d_in, const int* in_sizes, int n_in,
                              void* d_out, int out_size, void* d_ws, size_t ws_size,
                              hipStream_t stream) {
  const float* node_attrs = (const float*)d_in[0];
  const float* node_feats = (const float*)d_in[1];
  const float* edge_attrs = (const float*)d_in[2];
  const float* edge_feats = (const float*)d_in[3];
  const int*   edge_index = (const int*)d_in[4];
  const float* W_up0  = (const float*)d_in[5];
  const float* W_up1  = (const float*)d_in[6];
  const float* W_mlp1 = (const float*)d_in[7];
  const float* W_mlp2 = (const float*)d_in[8];
  const float* W_mlp3 = (const float*)d_in[9];
  const float* W_lin0 = (const float*)d_in[10];
  const float* W_lin1 = (const float*)d_in[11];
  const float* W_skip0 = (const float*)d_in[12];
  const float* W_skip1 = (const float*)d_in[13];
  const float* upd = (const float*)d_in[14];
  float* out = (float*)d_out;

  const int N = in_sizes[0] / 4;
  const int E = in_sizes[4] / 2;

  float* ws = (float*)d_ws;
  float* s_up = ws;                          // N*128
  float* v_up = s_up + (size_t)N * 128;      // N*384  [n][i][u]
  float* Ms   = v_up + (size_t)N * 384;      // N*256
  float* Mv   = Ms + (size_t)N * 256;        // N*768  [n][i][u]
  float* Sl   = Mv + (size_t)N * 768;        // N*128
  float* Vl   = Sl + (size_t)N * 128;        // N*384  [n][i][w]

  // zero the aggregation buffers (Ms and Mv are contiguous)
  hipMemsetAsync(Ms, 0, (size_t)N * 1024 * sizeof(float), stream);

  k_up<<<(N + 15) / 16, 256, 0, stream>>>(node_feats, W_up0, W_up1, s_up, v_up, N);
  k_edge<<<(E + 31) / 32, 256, 0, stream>>>(edge_feats, edge_attrs, edge_index,
                                            W_mlp1, W_mlp2, W_mlp3, s_up, v_up, Ms, Mv, E);
  k_lin<<<(N + 15) / 16, 256, 0, stream>>>(Ms, Mv, W_lin0, W_lin1, Sl, Vl, N);
  k_skip<<<(N + 15) / 16, 256, 0, stream>>>(Sl, Vl, node_attrs, W_skip0, W_skip1, upd, out, N);
}

// Round 2
// 670.076 us; speedup vs baseline: 13.4389x; 13.4389x over previous
//
#include <hip/hip_runtime.h>

#define MUL 128

// scale constants
__device__ __constant__ float kINV_UP   = 0.08838834764831845f;  // 1/sqrt(128)
__device__ __constant__ float kINV_L1   = 0.35355339059327373f;  // 1/sqrt(8)
__device__ __constant__ float kINV_L2   = 0.125f;                // 1/sqrt(64)
__device__ __constant__ float kINV_L3   = 0.125f;
__device__ __constant__ float kINV_LIN  = 0.00390625f;           // 1/(sqrt(256)*16)
__device__ __constant__ float kINV_SK   = 0.044194173824159216f; // 1/sqrt(512)
__device__ __constant__ float kINV_SQ3  = 0.5773502691896258f;   // 1/sqrt(3)

// ---------------------------------------------------------------------------
// Kernel A: node up-projection (unchanged from R1 — passed).
// ---------------------------------------------------------------------------
__global__ __launch_bounds__(256) void k_up(const float* __restrict__ nf,
                                            const float* __restrict__ W0,
                                            const float* __restrict__ W1,
                                            float* __restrict__ s_up,
                                            float* __restrict__ v_up,
                                            int N) {
  __shared__ float lin[16 * 516];
  const int nb = blockIdx.x * 16;
  const int t = threadIdx.x;

  for (int idx = t * 4; idx < 16 * 512; idx += 256 * 4) {
    int n = idx >> 9, w = idx & 511;
    if (nb + n < N) {
      float4 v = *reinterpret_cast<const float4*>(nf + (size_t)(nb + n) * 512 + w);
      *reinterpret_cast<float4*>(&lin[n * 516 + w]) = v;
    }
  }
  __syncthreads();

  const int n = t >> 4, g = t & 15, w0 = g * 8;
  const int node = nb + n;
  if (node >= N) return;

  float accs[8] = {};
  float accv[3][8] = {};
  const float* base = &lin[n * 516];

  for (int u = 0; u < 128; ++u) {
    float4 a0 = *reinterpret_cast<const float4*>(W0 + u * 128 + w0);
    float4 a1 = *reinterpret_cast<const float4*>(W0 + u * 128 + w0 + 4);
    float4 b0 = *reinterpret_cast<const float4*>(W1 + u * 128 + w0);
    float4 b1 = *reinterpret_cast<const float4*>(W1 + u * 128 + w0 + 4);
    float su = base[u];
    float v0 = base[128 + u * 3 + 0];
    float v1 = base[128 + u * 3 + 1];
    float v2 = base[128 + u * 3 + 2];
    float wa[8] = {a0.x, a0.y, a0.z, a0.w, a1.x, a1.y, a1.z, a1.w};
    float wb[8] = {b0.x, b0.y, b0.z, b0.w, b1.x, b1.y, b1.z, b1.w};
#pragma unroll
    for (int j = 0; j < 8; ++j) {
      accs[j]    += su * wa[j];
      accv[0][j] += v0 * wb[j];
      accv[1][j] += v1 * wb[j];
      accv[2][j] += v2 * wb[j];
    }
  }

  {
    float4 x0, x1;
    x0.x = accs[0] * kINV_UP; x0.y = accs[1] * kINV_UP; x0.z = accs[2] * kINV_UP; x0.w = accs[3] * kINV_UP;
    x1.x = accs[4] * kINV_UP; x1.y = accs[5] * kINV_UP; x1.z = accs[6] * kINV_UP; x1.w = accs[7] * kINV_UP;
    *reinterpret_cast<float4*>(s_up + (size_t)node * 128 + w0) = x0;
    *reinterpret_cast<float4*>(s_up + (size_t)node * 128 + w0 + 4) = x1;
  }
#pragma unroll
  for (int i = 0; i < 3; ++i) {
    float4 x0, x1;
    x0.x = accv[i][0] * kINV_UP; x0.y = accv[i][1] * kINV_UP; x0.z = accv[i][2] * kINV_UP; x0.w = accv[i][3] * kINV_UP;
    x1.x = accv[i][4] * kINV_UP; x1.y = accv[i][5] * kINV_UP; x1.z = accv[i][6] * kINV_UP; x1.w = accv[i][7] * kINV_UP;
    *reinterpret_cast<float4*>(v_up + (size_t)node * 384 + i * 128 + w0) = x0;
    *reinterpret_cast<float4*>(v_up + (size_t)node * 384 + i * 128 + w0 + 4) = x1;
  }
}

// ---------------------------------------------------------------------------
// Counting sort of edges by receiver: count -> scan -> scatter.
// ---------------------------------------------------------------------------
__global__ void k_count(const int* __restrict__ eidx, int* __restrict__ cnt, int E) {
  int e = blockIdx.x * 256 + threadIdx.x;
  if (e < E) atomicAdd(&cnt[eidx[E + e]], 1);
}

__global__ __launch_bounds__(1024) void k_scan(const int* __restrict__ cnt,
                                               int* __restrict__ offs,
                                               int* __restrict__ cursor, int N) {
  __shared__ int part[1024];
  const int t = threadIdx.x;
  int CH = (N + 1023) >> 10;
  if (CH > 16) CH = 16;
  const int base = t * CH;
  int loc[16];
  int s = 0;
  for (int i = 0; i < CH; ++i) {
    int idx = base + i;
    loc[i] = (idx < N) ? cnt[idx] : 0;
    s += loc[i];
  }
  part[t] = s;
  __syncthreads();
  for (int off = 1; off < 1024; off <<= 1) {
    int v = part[t];
    int add = (t >= off) ? part[t - off] : 0;
    __syncthreads();
    part[t] = v + add;
    __syncthreads();
  }
  int excl = part[t] - s;
  for (int i = 0; i < CH; ++i) {
    int idx = base + i;
    if (idx < N) { offs[idx] = excl; cursor[idx] = excl; }
    excl += loc[i];
  }
  if (t == 1023) offs[N] = part[1023];
}

__global__ void k_scatter(const int* __restrict__ eidx, int* __restrict__ cursor,
                          int* __restrict__ sorted, int E) {
  int e = blockIdx.x * 256 + threadIdx.x;
  if (e < E) {
    int r = eidx[E + e];
    int p = atomicAdd(&cursor[r], 1);
    sorted[p] = e;
  }
}

// ---------------------------------------------------------------------------
// Kernel B: fused per-edge MLP + owner-computes aggregation.
// One block (256 threads) per receiver node; edges in batches of 8.
// Layer-3 column ownership: thread t owns tpw cols {t, t+256} == exactly the
// {w_a,w_c} (t<128) or {w_b,w_d} (t>=128) pair its accumulator needs, so tpw
// never leaves registers. Accumulators: Ms[n][t], Mv[n][i*256+t].
// Inactive batch slots are zero-filled -> contribute exact zeros (full unroll).
// ---------------------------------------------------------------------------
__global__ __launch_bounds__(256) void k_gather(
    const int* __restrict__ sorted, const int* __restrict__ offs,
    const float* __restrict__ ef, const float* __restrict__ eattr,
    const int* __restrict__ eidx,
    const float* __restrict__ W1, const float* __restrict__ W2,
    const float* __restrict__ W3,
    const float* __restrict__ s_up, const float* __restrict__ v_up,
    float* __restrict__ Ms, float* __restrict__ Mv) {
  __shared__ float sW1[8 * 64];
  __shared__ float sW2[64 * 64];
  __shared__ float sh1[8][68];
  __shared__ float sh2T[64][8];   // transposed h2: [k][le]
  __shared__ float sef[8][8];
  __shared__ float sea[8][4];
  __shared__ int   ssnd[8];

  const int n = blockIdx.x;
  const int t = threadIdx.x;

  for (int i = t * 4; i < 512; i += 1024)
    *reinterpret_cast<float4*>(&sW1[i]) = *reinterpret_cast<const float4*>(W1 + i);
  for (int i = t * 4; i < 4096; i += 1024)
    *reinterpret_cast<float4*>(&sW2[i]) = *reinterpret_cast<const float4*>(W2 + i);

  float aMs = 0.f, aV0 = 0.f, aV1 = 0.f, aV2 = 0.f;

  const int e0 = offs[n], eEnd = offs[n + 1];
  const int le5 = t >> 5;          // l1/l2 edge slot
  const int c2  = (t & 31) * 2;    // l1/l2 column pair

  for (int eb = e0; eb < eEnd; eb += 8) {
    const int nb8 = min(8, eEnd - eb);
    __syncthreads();  // protect sef/sea/ssnd/sh1/sh2T from previous batch use

    if (t < 64) {
      int le = t >> 3, k = t & 7;
      int eid = (le < nb8) ? sorted[eb + le] : -1;
      sef[le][k] = (eid >= 0) ? ef[(size_t)eid * 8 + k] : 0.f;
      if (k < 4) sea[le][k] = (eid >= 0) ? eattr[(size_t)eid * 4 + k] : 0.f;
      if (k == 0) ssnd[le] = (eid >= 0) ? eidx[eid] : 0;
    }
    __syncthreads();

    // layer 1: 8 -> 64
    {
      float a0 = 0.f, a1 = 0.f;
#pragma unroll
      for (int k = 0; k < 8; ++k) {
        float x = sef[le5][k];
        float2 w = *reinterpret_cast<const float2*>(&sW1[k * 64 + c2]);
        a0 += x * w.x;
        a1 += x * w.y;
      }
      a0 *= kINV_L1; a1 *= kINV_L1;
      sh1[le5][c2]     = a0 / (1.f + __expf(-a0));
      sh1[le5][c2 + 1] = a1 / (1.f + __expf(-a1));
    }
    __syncthreads();

    // layer 2: 64 -> 64, write transposed
    {
      float a0 = 0.f, a1 = 0.f;
#pragma unroll 4
      for (int k = 0; k < 64; k += 4) {
        float4 h = *reinterpret_cast<const float4*>(&sh1[le5][k]);
        float2 w0 = *reinterpret_cast<const float2*>(&sW2[(k + 0) * 64 + c2]);
        float2 w1 = *reinterpret_cast<const float2*>(&sW2[(k + 1) * 64 + c2]);
        float2 w2 = *reinterpret_cast<const float2*>(&sW2[(k + 2) * 64 + c2]);
        float2 w3 = *reinterpret_cast<const float2*>(&sW2[(k + 3) * 64 + c2]);
        a0 += h.x * w0.x + h.y * w1.x + h.z * w2.x + h.w * w3.x;
        a1 += h.x * w0.y + h.y * w1.y + h.z * w2.y + h.w * w3.y;
      }
      a0 *= kINV_L2; a1 *= kINV_L2;
      float h20 = (le5 < nb8) ? a0 / (1.f + __expf(-a0)) : 0.f;
      float h21 = (le5 < nb8) ? a1 / (1.f + __expf(-a1)) : 0.f;
      sh2T[c2][le5]     = h20;
      sh2T[c2 + 1][le5] = h21;
    }
    __syncthreads();

    // layer 3: thread t accumulates tpw cols {t, t+256} for all 8 slots
    float tpA[8] = {}, tpB[8] = {};
    const float* w3p = W3 + t;
#pragma unroll 4
    for (int k = 0; k < 64; ++k) {
      float wA = w3p[k * 512];
      float wB = w3p[k * 512 + 256];
      float4 h0 = *reinterpret_cast<const float4*>(&sh2T[k][0]);
      float4 h1 = *reinterpret_cast<const float4*>(&sh2T[k][4]);
      tpA[0] += h0.x * wA; tpA[1] += h0.y * wA; tpA[2] += h0.z * wA; tpA[3] += h0.w * wA;
      tpA[4] += h1.x * wA; tpA[5] += h1.y * wA; tpA[6] += h1.z * wA; tpA[7] += h1.w * wA;
      tpB[0] += h0.x * wB; tpB[1] += h0.y * wB; tpB[2] += h0.z * wB; tpB[3] += h0.w * wB;
      tpB[4] += h1.x * wB; tpB[5] += h1.y * wB; tpB[6] += h1.z * wB; tpB[7] += h1.w * wB;
    }

    // accumulate messages (inactive slots contribute exact zeros)
    if (t < 128) {
      const int u = t;
#pragma unroll
      for (int le = 0; le < 8; ++le) {
        float xs  = s_up[(size_t)ssnd[le] * 128 + u];
        float eas = sea[le][0];
        aMs += tpA[le] * kINV_L3 * xs * eas;                 // m0 = w_a*xs*ea_s
        float wc = tpB[le] * kINV_L3 * xs;                   // w_c*xs
        aV0 += wc * sea[le][1];
        aV1 += wc * sea[le][2];
        aV2 += wc * sea[le][3];
      }
    } else {
      const int u = t - 128;
#pragma unroll
      for (int le = 0; le < 8; ++le) {
        const float* xv = v_up + (size_t)ssnd[le] * 384 + u;
        float x0 = xv[0], x1 = xv[128], x2 = xv[256];
        float ev0 = sea[le][1], ev1 = sea[le][2], ev2 = sea[le][3];
        float dot = x0 * ev0 + x1 * ev1 + x2 * ev2;
        aMs += tpA[le] * kINV_L3 * dot * kINV_SQ3;           // m1 = w_b*dot/sqrt3
        float wd = tpB[le] * kINV_L3 * sea[le][0];           // w_d*ea_s
        aV0 += wd * x0; aV1 += wd * x1; aV2 += wd * x2;
      }
    }
  }

  Ms[(size_t)n * 256 + t]        = aMs;
  Mv[(size_t)n * 768 + t]        = aV0;
  Mv[(size_t)n * 768 + 256 + t]  = aV1;
  Mv[(size_t)n * 768 + 512 + t]  = aV2;
}

// ---------------------------------------------------------------------------
// Kernel C1: linear after aggregation (unchanged from R1).
// ---------------------------------------------------------------------------
__global__ __launch_bounds__(256) void k_lin(const float* __restrict__ Ms,
                                             const float* __restrict__ Mv,
                                             const float* __restrict__ Wl0,
                                             const float* __restrict__ Wl1,
                                             float* __restrict__ S,
                                             float* __restrict__ V,
                                             int N) {
  __shared__ float lms[16 * 260];
  __shared__ float lmv[16 * 772];
  const int nb = blockIdx.x * 16;
  const int t = threadIdx.x;

  for (int i = t * 4; i < 16 * 256; i += 1024) {
    int n = i >> 8, u = i & 255;
    if (nb + n < N)
      *reinterpret_cast<float4*>(&lms[n * 260 + u]) =
          *reinterpret_cast<const float4*>(Ms + (size_t)(nb + n) * 256 + u);
  }
  for (int i = t * 4; i < 16 * 768; i += 1024) {
    int n = i / 768, j = i % 768;
    if (nb + n < N)
      *reinterpret_cast<float4*>(&lmv[n * 772 + j]) =
          *reinterpret_cast<const float4*>(Mv + (size_t)(nb + n) * 768 + j);
  }
  __syncthreads();

  const int n = t >> 4, g = t & 15, w0 = g * 8;
  const int node = nb + n;
  if (node >= N) return;

  float accs[8] = {};
  float accv[3][8] = {};
  for (int u = 0; u < 256; ++u) {
    float4 a0 = *reinterpret_cast<const float4*>(Wl0 + u * 128 + w0);
    float4 a1 = *reinterpret_cast<const float4*>(Wl0 + u * 128 + w0 + 4);
    float4 b0 = *reinterpret_cast<const float4*>(Wl1 + u * 128 + w0);
    float4 b1 = *reinterpret_cast<const float4*>(Wl1 + u * 128 + w0 + 4);
    float msu = lms[n * 260 + u];
    float m0 = lmv[n * 772 + u];
    float m1 = lmv[n * 772 + 256 + u];
    float m2 = lmv[n * 772 + 512 + u];
    float wa[8] = {a0.x, a0.y, a0.z, a0.w, a1.x, a1.y, a1.z, a1.w};
    float wb[8] = {b0.x, b0.y, b0.z, b0.w, b1.x, b1.y, b1.z, b1.w};
#pragma unroll
    for (int j = 0; j < 8; ++j) {
      accs[j]    += msu * wa[j];
      accv[0][j] += m0 * wb[j];
      accv[1][j] += m1 * wb[j];
      accv[2][j] += m2 * wb[j];
    }
  }

  {
    float4 x0, x1;
    x0.x = accs[0] * kINV_LIN; x0.y = accs[1] * kINV_LIN; x0.z = accs[2] * kINV_LIN; x0.w = accs[3] * kINV_LIN;
    x1.x = accs[4] * kINV_LIN; x1.y = accs[5] * kINV_LIN; x1.z = accs[6] * kINV_LIN; x1.w = accs[7] * kINV_LIN;
    *reinterpret_cast<float4*>(S + (size_t)node * 128 + w0) = x0;
    *reinterpret_cast<float4*>(S + (size_t)node * 128 + w0 + 4) = x1;
  }
#pragma unroll
  for (int i = 0; i < 3; ++i) {
    float4 x0, x1;
    x0.x = accv[i][0] * kINV_LIN; x0.y = accv[i][1] * kINV_LIN; x0.z = accv[i][2] * kINV_LIN; x0.w = accv[i][3] * kINV_LIN;
    x1.x = accv[i][4] * kINV_LIN; x1.y = accv[i][5] * kINV_LIN; x1.z = accv[i][6] * kINV_LIN; x1.w = accv[i][7] * kINV_LIN;
    *reinterpret_cast<float4*>(V + (size_t)node * 384 + i * 128 + w0) = x0;
    *reinterpret_cast<float4*>(V + (size_t)node * 384 + i * 128 + w0 + 4) = x1;
  }
}

// ---------------------------------------------------------------------------
// Kernel C2: skip contraction + combine + output (unchanged from R1).
// ---------------------------------------------------------------------------
__global__ __launch_bounds__(256) void k_skip(const float* __restrict__ S,
                                              const float* __restrict__ V,
                                              const float* __restrict__ attrs,
                                              const float* __restrict__ Wsk0,
                                              const float* __restrict__ Wsk1,
                                              const float* __restrict__ upd,
                                              float* __restrict__ out,
                                              int N) {
  __shared__ float ls[16 * 520];
  const int nb = blockIdx.x * 16;
  const int t = threadIdx.x;

  for (int i = t * 4; i < 16 * 128; i += 1024) {
    int n = i >> 7, w = i & 127;
    if (nb + n < N)
      *reinterpret_cast<float4*>(&ls[n * 520 + w]) =
          *reinterpret_cast<const float4*>(S + (size_t)(nb + n) * 128 + w);
  }
  for (int i = t * 4; i < 16 * 384; i += 1024) {
    int n = i / 384, j = i % 384;
    if (nb + n < N)
      *reinterpret_cast<float4*>(&ls[n * 520 + 128 + j]) =
          *reinterpret_cast<const float4*>(V + (size_t)(nb + n) * 384 + j);
  }
  if (t < 16 && nb + t < N)
    *reinterpret_cast<float4*>(&ls[t * 520 + 512]) =
        *reinterpret_cast<const float4*>(attrs + (size_t)(nb + t) * 4);
  __syncthreads();

  const int n = t >> 4, g = t & 15, w0 = g * 8;
  const int node = nb + n;
  if (node >= N) return;

  const float av[4] = {ls[n * 520 + 512], ls[n * 520 + 513], ls[n * 520 + 514], ls[n * 520 + 515]};
  float accs[8] = {};
  float accv[3][8] = {};

  for (int u = 0; u < 128; ++u) {
    float su = ls[n * 520 + u];
    float v0 = ls[n * 520 + 128 + u];
    float v1 = ls[n * 520 + 256 + u];
    float v2 = ls[n * 520 + 384 + u];
    const float* r0 = Wsk0 + (size_t)(u * 4) * 128 + w0;
    const float* r1 = Wsk1 + (size_t)(u * 4) * 128 + w0;
#pragma unroll
    for (int v = 0; v < 4; ++v) {
      float a = av[v];
      float cs = su * a;
      float c0 = v0 * a, c1 = v1 * a, c2 = v2 * a;
      float4 q0 = *reinterpret_cast<const float4*>(r0 + v * 128);
      float4 q1 = *reinterpret_cast<const float4*>(r0 + v * 128 + 4);
      float4 p0 = *reinterpret_cast<const float4*>(r1 + v * 128);
      float4 p1 = *reinterpret_cast<const float4*>(r1 + v * 128 + 4);
      float wq[8] = {q0.x, q0.y, q0.z, q0.w, q1.x, q1.y, q1.z, q1.w};
      float wp[8] = {p0.x, p0.y, p0.z, p0.w, p1.x, p1.y, p1.z, p1.w};
#pragma unroll
      for (int j = 0; j < 8; ++j) {
        accs[j]    += cs * wq[j];
        accv[0][j] += c0 * wp[j];
        accv[1][j] += c1 * wp[j];
        accv[2][j] += c2 * wp[j];
      }
    }
  }

  const float p = upd[0];
  const float cc = 1.f / (1.f + __expf(-p));
  const float c_old = rsqrtf(cc * cc + 1.f);
  const float c_new = cc * c_old;

#pragma unroll
  for (int j = 0; j < 8; ++j) {
    int w = w0 + j;
    float4 o;
    o.x = c_old * ls[n * 520 + w]        + c_new * accs[j]    * kINV_SK;
    o.y = c_old * ls[n * 520 + 128 + w]  + c_new * accv[0][j] * kINV_SK;
    o.z = c_old * ls[n * 520 + 256 + w]  + c_new * accv[1][j] * kINV_SK;
    o.w = c_old * ls[n * 520 + 384 + w]  + c_new * accv[2][j] * kINV_SK;
    *reinterpret_cast<float4*>(out + ((size_t)node * 128 + w) * 4) = o;
  }
}

extern "C" void kernel_launch(void* const* d_in, const int* in_sizes, int n_in,
                              void* d_out, int out_size, void* d_ws, size_t ws_size,
                              hipStream_t stream) {
  const float* node_attrs = (const float*)d_in[0];
  const float* node_feats = (const float*)d_in[1];
  const float* edge_attrs = (const float*)d_in[2];
  const float* edge_feats = (const float*)d_in[3];
  const int*   edge_index = (const int*)d_in[4];
  const float* W_up0  = (const float*)d_in[5];
  const float* W_up1  = (const float*)d_in[6];
  const float* W_mlp1 = (const float*)d_in[7];
  const float* W_mlp2 = (const float*)d_in[8];
  const float* W_mlp3 = (const float*)d_in[9];
  const float* W_lin0 = (const float*)d_in[10];
  const float* W_lin1 = (const float*)d_in[11];
  const float* W_skip0 = (const float*)d_in[12];
  const float* W_skip1 = (const float*)d_in[13];
  const float* upd = (const float*)d_in[14];
  float* out = (float*)d_out;

  const int N = in_sizes[0] / 4;
  const int E = in_sizes[4] / 2;

  float* ws = (float*)d_ws;
  float* s_up = ws;                          // N*128
  float* v_up = s_up + (size_t)N * 128;      // N*384  [n][i][u]
  float* Ms   = v_up + (size_t)N * 384;      // N*256
  float* Mv   = Ms + (size_t)N * 256;        // N*768  [n][i][u]
  float* Sl   = Mv + (size_t)N * 768;        // N*128
  float* Vl   = Sl + (size_t)N * 128;        // N*384  [n][i][w]
  int* cnt    = (int*)(Vl + (size_t)N * 384); // N
  int* offs   = cnt + N;                      // N+1
  int* cursor = offs + N + 1;                 // N
  int* sorted = cursor + N;                   // E

  hipMemsetAsync(cnt, 0, (size_t)N * sizeof(int), stream);

  k_up<<<(N + 15) / 16, 256, 0, stream>>>(node_feats, W_up0, W_up1, s_up, v_up, N);
  k_count<<<(E + 255) / 256, 256, 0, stream>>>(edge_index, cnt, E);
  k_scan<<<1, 1024, 0, stream>>>(cnt, offs, cursor, N);
  k_scatter<<<(E + 255) / 256, 256, 0, stream>>>(edge_index, cursor, sorted, E);
  k_gather<<<N, 256, 0, stream>>>(sorted, offs, edge_feats, edge_attrs, edge_index,
                                  W_mlp1, W_mlp2, W_mlp3, s_up, v_up, Ms, Mv);
  k_lin<<<(N + 15) / 16, 256, 0, stream>>>(Ms, Mv, W_lin0, W_lin1, Sl, Vl, N);
  k_skip<<<(N + 15) / 16, 256, 0, stream>>>(Sl, Vl, node_attrs, W_skip0, W_skip1, upd, out, N);
}

// Round 3
// 413.388 us; speedup vs baseline: 21.7836x; 1.6209x over previous
//
#include <hip/hip_runtime.h>

#define MUL 128

typedef __attribute__((ext_vector_type(8))) short bf16x8;
typedef __attribute__((ext_vector_type(4))) float f32x4;

__device__ __constant__ float kINV_UP   = 0.08838834764831845f;  // 1/sqrt(128)
__device__ __constant__ float kINV_L1   = 0.35355339059327373f;  // 1/sqrt(8)
__device__ __constant__ float kINV_L2   = 0.125f;                // 1/sqrt(64)
__device__ __constant__ float kINV_L3   = 0.125f;
__device__ __constant__ float kINV_LIN  = 0.00390625f;           // 1/(sqrt(256)*16)
__device__ __constant__ float kINV_SK   = 0.044194173824159216f; // 1/sqrt(512)
__device__ __constant__ float kINV_SQ3  = 0.5773502691896258f;   // 1/sqrt(3)

static __device__ __forceinline__ short f2bf(float f) {
  unsigned u = __float_as_uint(f);
  unsigned r = (u + 0x7FFFu + ((u >> 16) & 1u)) >> 16;  // RNE
  return (short)r;
}

// ---------------------------------------------------------------------------
// Weight conversion to bf16, transposed to [out_col][k] so MFMA B-fragments
// are contiguous 16B loads.  Wsk folded: WskT[w][v*128+u] = Wsk[u][v][w].
// ---------------------------------------------------------------------------
__global__ __launch_bounds__(256) void k_cvt(
    const float* __restrict__ W_up0, const float* __restrict__ W_up1,
    const float* __restrict__ W_lin0, const float* __restrict__ W_lin1,
    const float* __restrict__ W_sk0, const float* __restrict__ W_sk1,
    short* __restrict__ W0T, short* __restrict__ W1T,
    short* __restrict__ Wl0T, short* __restrict__ Wl1T,
    short* __restrict__ Wsk0T, short* __restrict__ Wsk1T) {
  int id = blockIdx.x * 256 + threadIdx.x;
  if (id < 16384) {
    int w = id >> 7, u = id & 127;
    W0T[id] = f2bf(W_up0[u * 128 + w]);
    return;
  }
  id -= 16384;
  if (id < 16384) {
    int w = id >> 7, u = id & 127;
    W1T[id] = f2bf(W_up1[u * 128 + w]);
    return;
  }
  id -= 16384;
  if (id < 32768) {
    int w = id >> 8, u = id & 255;
    Wl0T[id] = f2bf(W_lin0[u * 128 + w]);
    return;
  }
  id -= 32768;
  if (id < 32768) {
    int w = id >> 8, u = id & 255;
    Wl1T[id] = f2bf(W_lin1[u * 128 + w]);
    return;
  }
  id -= 32768;
  if (id < 65536) {
    int w = id >> 9, k = id & 511;
    int v = k >> 7, u = k & 127;
    Wsk0T[id] = f2bf(W_sk0[(u * 4 + v) * 128 + w]);
    return;
  }
  id -= 65536;
  if (id < 65536) {
    int w = id >> 9, k = id & 511;
    int v = k >> 7, u = k & 127;
    Wsk1T[id] = f2bf(W_sk1[(u * 4 + v) * 128 + w]);
  }
}

// ---------------------------------------------------------------------------
// Kernel A (MFMA): node up-projection. 16 nodes/block, 4 waves = comps
// {s, v0, v1, v2}. A staged bf16 in LDS [comp][node][k], stride 136 (16B ok,
// uniform bank spread). B streamed from transposed bf16 weights (L1/L2).
// ---------------------------------------------------------------------------
__global__ __launch_bounds__(256) void k_up_mfma(const float* __restrict__ nf,
                                                 const short* __restrict__ W0T,
                                                 const short* __restrict__ W1T,
                                                 float* __restrict__ s_up,
                                                 float* __restrict__ v_up,
                                                 int N) {
  __shared__ __align__(16) short lsA[4][16][136];
  const int nb = blockIdx.x * 16;
  const int t = threadIdx.x;

  for (int base = t * 8; base < 16 * 512; base += 256 * 8) {
    int n = base >> 9, j0 = base & 511;
    float vals[8];
    if (nb + n < N) {
      float4 q0 = *reinterpret_cast<const float4*>(nf + (size_t)(nb + n) * 512 + j0);
      float4 q1 = *reinterpret_cast<const float4*>(nf + (size_t)(nb + n) * 512 + j0 + 4);
      vals[0] = q0.x; vals[1] = q0.y; vals[2] = q0.z; vals[3] = q0.w;
      vals[4] = q1.x; vals[5] = q1.y; vals[6] = q1.z; vals[7] = q1.w;
    } else {
#pragma unroll
      for (int e = 0; e < 8; ++e) vals[e] = 0.f;
    }
#pragma unroll
    for (int e = 0; e < 8; ++e) {
      int idx = j0 + e;
      if (idx < 128) {
        lsA[0][n][idx] = f2bf(vals[e]);
      } else {
        unsigned q = idx - 128;
        unsigned u = q / 3u;
        unsigned i = q - u * 3u;
        lsA[1 + i][n][u] = f2bf(vals[e]);
      }
    }
  }
  __syncthreads();

  const int c = t >> 6;
  const int lane = t & 63;
  const int col = lane & 15;   // A-row index AND B/D-col index
  const int g = lane >> 4;

  const short* WT = c ? W1T : W0T;

  bf16x8 af[4];
#pragma unroll
  for (int kk = 0; kk < 4; ++kk)
    af[kk] = *reinterpret_cast<const bf16x8*>(&lsA[c][col][kk * 32 + g * 8]);

#pragma unroll
  for (int nt = 0; nt < 8; ++nt) {
    f32x4 acc = {0.f, 0.f, 0.f, 0.f};
#pragma unroll
    for (int kk = 0; kk < 4; ++kk) {
      bf16x8 bf = *reinterpret_cast<const bf16x8*>(&WT[(size_t)(nt * 16 + col) * 128 + kk * 32 + g * 8]);
      acc = __builtin_amdgcn_mfma_f32_16x16x32_bf16(af[kk], bf, acc, 0, 0, 0);
    }
#pragma unroll
    for (int r = 0; r < 4; ++r) {
      int nd = nb + g * 4 + r;
      if (nd < N) {
        float val = acc[r] * kINV_UP;
        if (c == 0) s_up[(size_t)nd * 128 + nt * 16 + col] = val;
        else        v_up[(size_t)nd * 384 + (c - 1) * 128 + nt * 16 + col] = val;
      }
    }
  }
}

// ---------------------------------------------------------------------------
// Counting sort of edges by receiver: count -> scan -> scatter.
// ---------------------------------------------------------------------------
__global__ void k_count(const int* __restrict__ eidx, int* __restrict__ cnt, int E) {
  int e = blockIdx.x * 256 + threadIdx.x;
  if (e < E) atomicAdd(&cnt[eidx[E + e]], 1);
}

__global__ __launch_bounds__(1024) void k_scan(const int* __restrict__ cnt,
                                               int* __restrict__ offs,
                                               int* __restrict__ cursor, int N) {
  __shared__ int part[1024];
  const int t = threadIdx.x;
  int CH = (N + 1023) >> 10;
  if (CH > 16) CH = 16;
  const int base = t * CH;
  int loc[16];
  int s = 0;
  for (int i = 0; i < CH; ++i) {
    int idx = base + i;
    loc[i] = (idx < N) ? cnt[idx] : 0;
    s += loc[i];
  }
  part[t] = s;
  __syncthreads();
  for (int off = 1; off < 1024; off <<= 1) {
    int v = part[t];
    int add = (t >= off) ? part[t - off] : 0;
    __syncthreads();
    part[t] = v + add;
    __syncthreads();
  }
  int excl = part[t] - s;
  for (int i = 0; i < CH; ++i) {
    int idx = base + i;
    if (idx < N) { offs[idx] = excl; cursor[idx] = excl; }
    excl += loc[i];
  }
  if (t == 1023) offs[N] = part[1023];
}

__global__ void k_scatter(const int* __restrict__ eidx, int* __restrict__ cursor,
                          int* __restrict__ sorted, int E) {
  int e = blockIdx.x * 256 + threadIdx.x;
  if (e < E) {
    int r = eidx[E + e];
    int p = atomicAdd(&cursor[r], 1);
    sorted[p] = e;
  }
}

// ---------------------------------------------------------------------------
// Kernel B: fused per-edge MLP + owner-computes aggregation (unchanged R2).
// ---------------------------------------------------------------------------
__global__ __launch_bounds__(256) void k_gather(
    const int* __restrict__ sorted, const int* __restrict__ offs,
    const float* __restrict__ ef, const float* __restrict__ eattr,
    const int* __restrict__ eidx,
    const float* __restrict__ W1, const float* __restrict__ W2,
    const float* __restrict__ W3,
    const float* __restrict__ s_up, const float* __restrict__ v_up,
    float* __restrict__ Ms, float* __restrict__ Mv) {
  __shared__ float sW1[8 * 64];
  __shared__ float sW2[64 * 64];
  __shared__ float sh1[8][68];
  __shared__ float sh2T[64][8];
  __shared__ float sef[8][8];
  __shared__ float sea[8][4];
  __shared__ int   ssnd[8];

  const int n = blockIdx.x;
  const int t = threadIdx.x;

  for (int i = t * 4; i < 512; i += 1024)
    *reinterpret_cast<float4*>(&sW1[i]) = *reinterpret_cast<const float4*>(W1 + i);
  for (int i = t * 4; i < 4096; i += 1024)
    *reinterpret_cast<float4*>(&sW2[i]) = *reinterpret_cast<const float4*>(W2 + i);

  float aMs = 0.f, aV0 = 0.f, aV1 = 0.f, aV2 = 0.f;

  const int e0 = offs[n], eEnd = offs[n + 1];
  const int le5 = t >> 5;
  const int c2  = (t & 31) * 2;

  for (int eb = e0; eb < eEnd; eb += 8) {
    const int nb8 = min(8, eEnd - eb);
    __syncthreads();

    if (t < 64) {
      int le = t >> 3, k = t & 7;
      int eid = (le < nb8) ? sorted[eb + le] : -1;
      sef[le][k] = (eid >= 0) ? ef[(size_t)eid * 8 + k] : 0.f;
      if (k < 4) sea[le][k] = (eid >= 0) ? eattr[(size_t)eid * 4 + k] : 0.f;
      if (k == 0) ssnd[le] = (eid >= 0) ? eidx[eid] : 0;
    }
    __syncthreads();

    {
      float a0 = 0.f, a1 = 0.f;
#pragma unroll
      for (int k = 0; k < 8; ++k) {
        float x = sef[le5][k];
        float2 w = *reinterpret_cast<const float2*>(&sW1[k * 64 + c2]);
        a0 += x * w.x;
        a1 += x * w.y;
      }
      a0 *= kINV_L1; a1 *= kINV_L1;
      sh1[le5][c2]     = a0 / (1.f + __expf(-a0));
      sh1[le5][c2 + 1] = a1 / (1.f + __expf(-a1));
    }
    __syncthreads();

    {
      float a0 = 0.f, a1 = 0.f;
#pragma unroll 4
      for (int k = 0; k < 64; k += 4) {
        float4 h = *reinterpret_cast<const float4*>(&sh1[le5][k]);
        float2 w0 = *reinterpret_cast<const float2*>(&sW2[(k + 0) * 64 + c2]);
        float2 w1 = *reinterpret_cast<const float2*>(&sW2[(k + 1) * 64 + c2]);
        float2 w2 = *reinterpret_cast<const float2*>(&sW2[(k + 2) * 64 + c2]);
        float2 w3 = *reinterpret_cast<const float2*>(&sW2[(k + 3) * 64 + c2]);
        a0 += h.x * w0.x + h.y * w1.x + h.z * w2.x + h.w * w3.x;
        a1 += h.x * w0.y + h.y * w1.y + h.z * w2.y + h.w * w3.y;
      }
      a0 *= kINV_L2; a1 *= kINV_L2;
      float h20 = (le5 < nb8) ? a0 / (1.f + __expf(-a0)) : 0.f;
      float h21 = (le5 < nb8) ? a1 / (1.f + __expf(-a1)) : 0.f;
      sh2T[c2][le5]     = h20;
      sh2T[c2 + 1][le5] = h21;
    }
    __syncthreads();

    float tpA[8] = {}, tpB[8] = {};
    const float* w3p = W3 + t;
#pragma unroll 4
    for (int k = 0; k < 64; ++k) {
      float wA = w3p[k * 512];
      float wB = w3p[k * 512 + 256];
      float4 h0 = *reinterpret_cast<const float4*>(&sh2T[k][0]);
      float4 h1 = *reinterpret_cast<const float4*>(&sh2T[k][4]);
      tpA[0] += h0.x * wA; tpA[1] += h0.y * wA; tpA[2] += h0.z * wA; tpA[3] += h0.w * wA;
      tpA[4] += h1.x * wA; tpA[5] += h1.y * wA; tpA[6] += h1.z * wA; tpA[7] += h1.w * wA;
      tpB[0] += h0.x * wB; tpB[1] += h0.y * wB; tpB[2] += h0.z * wB; tpB[3] += h0.w * wB;
      tpB[4] += h1.x * wB; tpB[5] += h1.y * wB; tpB[6] += h1.z * wB; tpB[7] += h1.w * wB;
    }

    const int tl = t;
    if (tl < 128) {
      const int u = tl;
#pragma unroll
      for (int le = 0; le < 8; ++le) {
        float xs  = s_up[(size_t)ssnd[le] * 128 + u];
        float eas = sea[le][0];
        aMs += tpA[le] * kINV_L3 * xs * eas;
        float wc = tpB[le] * kINV_L3 * xs;
        aV0 += wc * sea[le][1];
        aV1 += wc * sea[le][2];
        aV2 += wc * sea[le][3];
      }
    } else {
      const int u = tl - 128;
#pragma unroll
      for (int le = 0; le < 8; ++le) {
        const float* xv = v_up + (size_t)ssnd[le] * 384 + u;
        float x0 = xv[0], x1 = xv[128], x2 = xv[256];
        float ev0 = sea[le][1], ev1 = sea[le][2], ev2 = sea[le][3];
        float dot = x0 * ev0 + x1 * ev1 + x2 * ev2;
        aMs += tpA[le] * kINV_L3 * dot * kINV_SQ3;
        float wd = tpB[le] * kINV_L3 * sea[le][0];
        aV0 += wd * x0; aV1 += wd * x1; aV2 += wd * x2;
      }
    }
  }

  Ms[(size_t)n * 256 + t]        = aMs;
  Mv[(size_t)n * 768 + t]        = aV0;
  Mv[(size_t)n * 768 + 256 + t]  = aV1;
  Mv[(size_t)n * 768 + 512 + t]  = aV2;
}

// ---------------------------------------------------------------------------
// Kernel C (MFMA): fused lin + skip + combine. 16 nodes/block, 4 waves =
// comps {s, v0, v1, v2}.
// Stage 1: S = A1 @ WlT (K=256) -> Sreg (f32) + lsS (bf16).
// Stage 2: per species v: tmp = S @ WskT[:, v*128:...] (K=128), fin += attr*tmp.
// Final:   out = c_old*S + c_new*fin*inv_sk, interleaved [n][w][4].
// ---------------------------------------------------------------------------
__global__ __launch_bounds__(256) void k_linskip(
    const float* __restrict__ Ms, const float* __restrict__ Mv,
    const short* __restrict__ Wl0T, const short* __restrict__ Wl1T,
    const short* __restrict__ Wsk0T, const short* __restrict__ Wsk1T,
    const float* __restrict__ attrs, const float* __restrict__ upd,
    float* __restrict__ out, int N) {
  __shared__ __align__(16) short lsA[4][16][264];
  __shared__ __align__(16) short lsS[4][16][136];
  __shared__ float sat[16][4];
  const int nb = blockIdx.x * 16;
  const int t = threadIdx.x;

  for (int base = t * 4; base < 16 * 1024; base += 1024) {
    int n = base >> 10, j = base & 1023;
    int comp = j >> 8, u = j & 255;
    float4 q = {0.f, 0.f, 0.f, 0.f};
    if (nb + n < N) {
      const float* src = (comp == 0) ? (Ms + (size_t)(nb + n) * 256 + u)
                                     : (Mv + (size_t)(nb + n) * 768 + (size_t)(comp - 1) * 256 + u);
      q = *reinterpret_cast<const float4*>(src);
    }
    lsA[comp][n][u + 0] = f2bf(q.x);
    lsA[comp][n][u + 1] = f2bf(q.y);
    lsA[comp][n][u + 2] = f2bf(q.z);
    lsA[comp][n][u + 3] = f2bf(q.w);
  }
  if (t < 64) {
    int n = t >> 2, v = t & 3;
    sat[n][v] = (nb + n < N) ? attrs[(size_t)(nb + n) * 4 + v] : 0.f;
  }
  __syncthreads();

  const int c = t >> 6;
  const int lane = t & 63;
  const int col = lane & 15;
  const int g = lane >> 4;

  const short* WLT = c ? Wl1T : Wl0T;
  const short* WST = c ? Wsk1T : Wsk0T;

  // stage-1 A fragments (K=256 -> 8 frags)
  bf16x8 af1[8];
#pragma unroll
  for (int kk = 0; kk < 8; ++kk)
    af1[kk] = *reinterpret_cast<const bf16x8*>(&lsA[c][col][kk * 32 + g * 8]);

  f32x4 Sreg[8];
#pragma unroll
  for (int nt = 0; nt < 8; ++nt) {
    f32x4 acc = {0.f, 0.f, 0.f, 0.f};
#pragma unroll
    for (int kk = 0; kk < 8; ++kk) {
      bf16x8 bf = *reinterpret_cast<const bf16x8*>(&WLT[(size_t)(nt * 16 + col) * 256 + kk * 32 + g * 8]);
      acc = __builtin_amdgcn_mfma_f32_16x16x32_bf16(af1[kk], bf, acc, 0, 0, 0);
    }
#pragma unroll
    for (int r = 0; r < 4; ++r) acc[r] *= kINV_LIN;
    Sreg[nt] = acc;
#pragma unroll
    for (int r = 0; r < 4; ++r)
      lsS[c][g * 4 + r][nt * 16 + col] = f2bf(acc[r]);
  }

  // per-lane attr rows
  float satr[4][4];
#pragma unroll
  for (int r = 0; r < 4; ++r)
#pragma unroll
    for (int v = 0; v < 4; ++v) satr[r][v] = sat[g * 4 + r][v];

  // stage-2 A fragments (K=128 over S)
  bf16x8 af2[4];
#pragma unroll
  for (int kk = 0; kk < 4; ++kk)
    af2[kk] = *reinterpret_cast<const bf16x8*>(&lsS[c][col][kk * 32 + g * 8]);

  const float p = upd[0];
  const float cc = 1.f / (1.f + __expf(-p));
  const float c_old = rsqrtf(cc * cc + 1.f);
  const float c_new = cc * c_old;

#pragma unroll
  for (int nt = 0; nt < 8; ++nt) {
    float fin[4] = {0.f, 0.f, 0.f, 0.f};
#pragma unroll
    for (int v = 0; v < 4; ++v) {
      f32x4 tmp = {0.f, 0.f, 0.f, 0.f};
#pragma unroll
      for (int kk = 0; kk < 4; ++kk) {
        bf16x8 bf = *reinterpret_cast<const bf16x8*>(&WST[(size_t)(nt * 16 + col) * 512 + v * 128 + kk * 32 + g * 8]);
        tmp = __builtin_amdgcn_mfma_f32_16x16x32_bf16(af2[kk], bf, tmp, 0, 0, 0);
      }
#pragma unroll
      for (int r = 0; r < 4; ++r) fin[r] += satr[r][v] * tmp[r];
    }
#pragma unroll
    for (int r = 0; r < 4; ++r) {
      int nd = nb + g * 4 + r;
      if (nd < N) {
        float val = c_old * Sreg[nt][r] + c_new * fin[r] * kINV_SK;
        out[((size_t)nd * 128 + nt * 16 + col) * 4 + c] = val;
      }
    }
  }
}

extern "C" void kernel_launch(void* const* d_in, const int* in_sizes, int n_in,
                              void* d_out, int out_size, void* d_ws, size_t ws_size,
                              hipStream_t stream) {
  const float* node_attrs = (const float*)d_in[0];
  const float* node_feats = (const float*)d_in[1];
  const float* edge_attrs = (const float*)d_in[2];
  const float* edge_feats = (const float*)d_in[3];
  const int*   edge_index = (const int*)d_in[4];
  const float* W_up0  = (const float*)d_in[5];
  const float* W_up1  = (const float*)d_in[6];
  const float* W_mlp1 = (const float*)d_in[7];
  const float* W_mlp2 = (const float*)d_in[8];
  const float* W_mlp3 = (const float*)d_in[9];
  const float* W_lin0 = (const float*)d_in[10];
  const float* W_lin1 = (const float*)d_in[11];
  const float* W_skip0 = (const float*)d_in[12];
  const float* W_skip1 = (const float*)d_in[13];
  const float* upd = (const float*)d_in[14];
  float* out = (float*)d_out;

  const int N = in_sizes[0] / 4;
  const int E = in_sizes[4] / 2;

  float* ws = (float*)d_ws;
  float* s_up = ws;                          // N*128
  float* v_up = s_up + (size_t)N * 128;      // N*384  [n][i][u]
  float* Ms   = v_up + (size_t)N * 384;      // N*256
  float* Mv   = Ms + (size_t)N * 256;        // N*768  [n][i][u]
  int* cnt    = (int*)(Mv + (size_t)N * 768); // N
  int* offs   = cnt + N;                      // N+1
  int* cursor = offs + N + 1;                 // N
  int* sorted = cursor + N;                   // E

  // bf16 weight arrays, 16B-aligned
  short* wbase = (short*)((((uintptr_t)(sorted + E)) + 15) & ~(uintptr_t)15);
  short* W0T   = wbase;            // 128*128
  short* W1T   = W0T + 16384;      // 128*128
  short* Wl0T  = W1T + 16384;      // 128*256
  short* Wl1T  = Wl0T + 32768;     // 128*256
  short* Wsk0T = Wl1T + 32768;     // 128*512
  short* Wsk1T = Wsk0T + 65536;    // 128*512

  hipMemsetAsync(cnt, 0, (size_t)N * sizeof(int), stream);

  k_cvt<<<(229376 + 255) / 256, 256, 0, stream>>>(W_up0, W_up1, W_lin0, W_lin1,
                                                  W_skip0, W_skip1,
                                                  W0T, W1T, Wl0T, Wl1T, Wsk0T, Wsk1T);
  k_up_mfma<<<(N + 15) / 16, 256, 0, stream>>>(node_feats, W0T, W1T, s_up, v_up, N);
  k_count<<<(E + 255) / 256, 256, 0, stream>>>(edge_index, cnt, E);
  k_scan<<<1, 1024, 0, stream>>>(cnt, offs, cursor, N);
  k_scatter<<<(E + 255) / 256, 256, 0, stream>>>(edge_index, cursor, sorted, E);
  k_gather<<<N, 256, 0, stream>>>(sorted, offs, edge_feats, edge_attrs, edge_index,
                                  W_mlp1, W_mlp2, W_mlp3, s_up, v_up, Ms, Mv);
  k_linskip<<<(N + 15) / 16, 256, 0, stream>>>(Ms, Mv, Wl0T, Wl1T, Wsk0T, Wsk1T,
                                               node_attrs, upd, out, N);
}

// Round 4
// 347.086 us; speedup vs baseline: 25.9448x; 1.1910x over previous
//
#include <hip/hip_runtime.h>

#define MUL 128

typedef __attribute__((ext_vector_type(8))) short bf16x8;
typedef __attribute__((ext_vector_type(4))) short bf16x4;
typedef __attribute__((ext_vector_type(4))) float f32x4;

__device__ __constant__ float kINV_UP   = 0.08838834764831845f;  // 1/sqrt(128)
__device__ __constant__ float kINV_L1   = 0.35355339059327373f;  // 1/sqrt(8)
__device__ __constant__ float kINV_L2   = 0.125f;                // 1/sqrt(64)
__device__ __constant__ float kINV_L3   = 0.125f;
__device__ __constant__ float kINV_LIN  = 0.00390625f;           // 1/(sqrt(256)*16)
__device__ __constant__ float kINV_SK   = 0.044194173824159216f; // 1/sqrt(512)
__device__ __constant__ float kINV_SQ3  = 0.5773502691896258f;   // 1/sqrt(3)

static __device__ __forceinline__ short f2bf(float f) {
  unsigned u = __float_as_uint(f);
  unsigned r = (u + 0x7FFFu + ((u >> 16) & 1u)) >> 16;  // RNE
  return (short)r;
}
static __device__ __forceinline__ float bf2f(short s) {
  return __uint_as_float(((unsigned)(unsigned short)s) << 16);
}

// ---------------------------------------------------------------------------
// Weight conversion to bf16, transposed to [out_col][k].
// Wsk folded: WskT[w][v*128+u] = Wsk[u][v][w].  W2T/W3T for the edge MLP.
// ---------------------------------------------------------------------------
__global__ __launch_bounds__(256) void k_cvt(
    const float* __restrict__ W_up0, const float* __restrict__ W_up1,
    const float* __restrict__ W_lin0, const float* __restrict__ W_lin1,
    const float* __restrict__ W_sk0, const float* __restrict__ W_sk1,
    const float* __restrict__ W_mlp2, const float* __restrict__ W_mlp3,
    short* __restrict__ W0T, short* __restrict__ W1T,
    short* __restrict__ Wl0T, short* __restrict__ Wl1T,
    short* __restrict__ Wsk0T, short* __restrict__ Wsk1T,
    short* __restrict__ W2T, short* __restrict__ W3T) {
  int id = blockIdx.x * 256 + threadIdx.x;
  if (id < 16384) {
    int w = id >> 7, u = id & 127;
    W0T[id] = f2bf(W_up0[u * 128 + w]);
    return;
  }
  id -= 16384;
  if (id < 16384) {
    int w = id >> 7, u = id & 127;
    W1T[id] = f2bf(W_up1[u * 128 + w]);
    return;
  }
  id -= 16384;
  if (id < 32768) {
    int w = id >> 8, u = id & 255;
    Wl0T[id] = f2bf(W_lin0[u * 128 + w]);
    return;
  }
  id -= 32768;
  if (id < 32768) {
    int w = id >> 8, u = id & 255;
    Wl1T[id] = f2bf(W_lin1[u * 128 + w]);
    return;
  }
  id -= 32768;
  if (id < 65536) {
    int w = id >> 9, k = id & 511;
    int v = k >> 7, u = k & 127;
    Wsk0T[id] = f2bf(W_sk0[(u * 4 + v) * 128 + w]);
    return;
  }
  id -= 65536;
  if (id < 65536) {
    int w = id >> 9, k = id & 511;
    int v = k >> 7, u = k & 127;
    Wsk1T[id] = f2bf(W_sk1[(u * 4 + v) * 128 + w]);
    return;
  }
  id -= 65536;
  if (id < 4096) {
    int c = id >> 6, k = id & 63;
    W2T[id] = f2bf(W_mlp2[k * 64 + c]);
    return;
  }
  id -= 4096;
  if (id < 32768) {
    int c = id >> 6, k = id & 63;
    W3T[id] = f2bf(W_mlp3[k * 512 + c]);
  }
}

// ---------------------------------------------------------------------------
// Kernel A (MFMA): node up-projection (unchanged from R3 — passed).
// ---------------------------------------------------------------------------
__global__ __launch_bounds__(256) void k_up_mfma(const float* __restrict__ nf,
                                                 const short* __restrict__ W0T,
                                                 const short* __restrict__ W1T,
                                                 float* __restrict__ s_up,
                                                 float* __restrict__ v_up,
                                                 int N) {
  __shared__ __align__(16) short lsA[4][16][136];
  const int nb = blockIdx.x * 16;
  const int t = threadIdx.x;

  for (int base = t * 8; base < 16 * 512; base += 256 * 8) {
    int n = base >> 9, j0 = base & 511;
    float vals[8];
    if (nb + n < N) {
      float4 q0 = *reinterpret_cast<const float4*>(nf + (size_t)(nb + n) * 512 + j0);
      float4 q1 = *reinterpret_cast<const float4*>(nf + (size_t)(nb + n) * 512 + j0 + 4);
      vals[0] = q0.x; vals[1] = q0.y; vals[2] = q0.z; vals[3] = q0.w;
      vals[4] = q1.x; vals[5] = q1.y; vals[6] = q1.z; vals[7] = q1.w;
    } else {
#pragma unroll
      for (int e = 0; e < 8; ++e) vals[e] = 0.f;
    }
#pragma unroll
    for (int e = 0; e < 8; ++e) {
      int idx = j0 + e;
      if (idx < 128) {
        lsA[0][n][idx] = f2bf(vals[e]);
      } else {
        unsigned q = idx - 128;
        unsigned u = q / 3u;
        unsigned i = q - u * 3u;
        lsA[1 + i][n][u] = f2bf(vals[e]);
      }
    }
  }
  __syncthreads();

  const int c = t >> 6;
  const int lane = t & 63;
  const int col = lane & 15;
  const int g = lane >> 4;

  const short* WT = c ? W1T : W0T;

  bf16x8 af[4];
#pragma unroll
  for (int kk = 0; kk < 4; ++kk)
    af[kk] = *reinterpret_cast<const bf16x8*>(&lsA[c][col][kk * 32 + g * 8]);

#pragma unroll
  for (int nt = 0; nt < 8; ++nt) {
    f32x4 acc = {0.f, 0.f, 0.f, 0.f};
#pragma unroll
    for (int kk = 0; kk < 4; ++kk) {
      bf16x8 bf = *reinterpret_cast<const bf16x8*>(&WT[(size_t)(nt * 16 + col) * 128 + kk * 32 + g * 8]);
      acc = __builtin_amdgcn_mfma_f32_16x16x32_bf16(af[kk], bf, acc, 0, 0, 0);
    }
#pragma unroll
    for (int r = 0; r < 4; ++r) {
      int nd = nb + g * 4 + r;
      if (nd < N) {
        float val = acc[r] * kINV_UP;
        if (c == 0) s_up[(size_t)nd * 128 + nt * 16 + col] = val;
        else        v_up[(size_t)nd * 384 + (c - 1) * 128 + nt * 16 + col] = val;
      }
    }
  }
}

// ---------------------------------------------------------------------------
// Counting sort of edges by receiver: count -> scan -> scatter.
// ---------------------------------------------------------------------------
__global__ void k_count(const int* __restrict__ eidx, int* __restrict__ cnt, int E) {
  int e = blockIdx.x * 256 + threadIdx.x;
  if (e < E) atomicAdd(&cnt[eidx[E + e]], 1);
}

__global__ __launch_bounds__(1024) void k_scan(const int* __restrict__ cnt,
                                               int* __restrict__ offs,
                                               int* __restrict__ cursor, int N) {
  __shared__ int part[1024];
  const int t = threadIdx.x;
  int CH = (N + 1023) >> 10;
  if (CH > 16) CH = 16;
  const int base = t * CH;
  int loc[16];
  int s = 0;
  for (int i = 0; i < CH; ++i) {
    int idx = base + i;
    loc[i] = (idx < N) ? cnt[idx] : 0;
    s += loc[i];
  }
  part[t] = s;
  __syncthreads();
  for (int off = 1; off < 1024; off <<= 1) {
    int v = part[t];
    int add = (t >= off) ? part[t - off] : 0;
    __syncthreads();
    part[t] = v + add;
    __syncthreads();
  }
  int excl = part[t] - s;
  for (int i = 0; i < CH; ++i) {
    int idx = base + i;
    if (idx < N) { offs[idx] = excl; cursor[idx] = excl; }
    excl += loc[i];
  }
  if (t == 1023) offs[N] = part[1023];
}

__global__ void k_scatter(const int* __restrict__ eidx, int* __restrict__ cursor,
                          int* __restrict__ sorted, int E) {
  int e = blockIdx.x * 256 + threadIdx.x;
  if (e < E) {
    int r = eidx[E + e];
    int p = atomicAdd(&cursor[r], 1);
    sorted[p] = e;
  }
}

// ---------------------------------------------------------------------------
// Kernel MLP (MFMA): per-edge 3-layer MLP -> tpw[p][512] bf16, indexed by
// SORTED position p (so the gather reads contiguously). 64 positions/block,
// 4 waves. Layer1 VALU; layers 2-3 MFMA with swapped operands
// (A = weight^T rows = output cols, B = activations, D-col = edge), so each
// lane's 4 acc values are 4 consecutive output cols -> single 8B bf16x4 store.
// kINV_L3 is folded into tpw.
// ---------------------------------------------------------------------------
__global__ __launch_bounds__(256) void k_mlp(
    const int* __restrict__ sorted, const float* __restrict__ ef,
    const float* __restrict__ W1, const short* __restrict__ W2T,
    const short* __restrict__ W3T, short* __restrict__ tpw, int E) {
  __shared__ float sef[64][12];
  __shared__ float sW1[8 * 64];
  __shared__ __align__(16) short sW2T[64][72];
  __shared__ __align__(16) short sh1[64][72];
  __shared__ __align__(16) short sh2[64][72];

  const int pb = blockIdx.x * 64;
  const int t = threadIdx.x;

  for (int i = t * 4; i < 512; i += 1024)
    *reinterpret_cast<float4*>(&sW1[i]) = *reinterpret_cast<const float4*>(W1 + i);
  for (int i = t * 8; i < 4096; i += 2048) {
    int r = i >> 6, c = i & 63;
    *reinterpret_cast<bf16x8*>(&sW2T[r][c]) = *reinterpret_cast<const bf16x8*>(&W2T[r * 64 + c]);
  }
  if (t < 128) {
    int le = t >> 1, half = t & 1;
    int p = pb + le;
    float4 q = {0.f, 0.f, 0.f, 0.f};
    if (p < E) {
      int eid = sorted[p];
      q = *reinterpret_cast<const float4*>(ef + (size_t)eid * 8 + half * 4);
    }
    *reinterpret_cast<float4*>(&sef[le][half * 4]) = q;
  }
  __syncthreads();

  // layer 1 (VALU): wave w = col group, lane = edge slot
  {
    const int e = t & 63, cg = t >> 6;
    float acc[16] = {};
#pragma unroll
    for (int k = 0; k < 8; ++k) {
      float x = sef[e][k];
#pragma unroll
      for (int j = 0; j < 16; ++j) acc[j] += x * sW1[k * 64 + cg * 16 + j];
    }
#pragma unroll
    for (int j = 0; j < 16; ++j) {
      float a = acc[j] * kINV_L1;
      sh1[e][cg * 16 + j] = f2bf(a / (1.f + __expf(-a)));
    }
  }
  __syncthreads();

  const int lane = t & 63, w = t >> 6;
  const int li = lane & 15, g = lane >> 4;
  const int e = w * 16 + li;

  // layer 2 (MFMA, swapped): A = W2T (m=h2col), B = sh1 (n=edge)
  {
    bf16x8 b0 = *reinterpret_cast<const bf16x8*>(&sh1[e][g * 8]);
    bf16x8 b1 = *reinterpret_cast<const bf16x8*>(&sh1[e][32 + g * 8]);
#pragma unroll
    for (int ct = 0; ct < 4; ++ct) {
      bf16x8 a0 = *reinterpret_cast<const bf16x8*>(&sW2T[ct * 16 + li][g * 8]);
      bf16x8 a1 = *reinterpret_cast<const bf16x8*>(&sW2T[ct * 16 + li][32 + g * 8]);
      f32x4 acc = {0.f, 0.f, 0.f, 0.f};
      acc = __builtin_amdgcn_mfma_f32_16x16x32_bf16(a0, b0, acc, 0, 0, 0);
      acc = __builtin_amdgcn_mfma_f32_16x16x32_bf16(a1, b1, acc, 0, 0, 0);
      bf16x4 h;
#pragma unroll
      for (int r = 0; r < 4; ++r) {
        float a = acc[r] * kINV_L2;
        h[r] = f2bf(a / (1.f + __expf(-a)));
      }
      *reinterpret_cast<bf16x4*>(&sh2[e][ct * 16 + g * 4]) = h;
    }
  }
  __syncthreads();

  // layer 3 (MFMA, swapped): A = W3T (m=tpw col), B = sh2 (n=edge)
  {
    const int p = pb + e;
    bf16x8 b0 = *reinterpret_cast<const bf16x8*>(&sh2[e][g * 8]);
    bf16x8 b1 = *reinterpret_cast<const bf16x8*>(&sh2[e][32 + g * 8]);
#pragma unroll 4
    for (int rt = 0; rt < 32; ++rt) {
      bf16x8 a0 = *reinterpret_cast<const bf16x8*>(&W3T[(size_t)(rt * 16 + li) * 64 + g * 8]);
      bf16x8 a1 = *reinterpret_cast<const bf16x8*>(&W3T[(size_t)(rt * 16 + li) * 64 + 32 + g * 8]);
      f32x4 acc = {0.f, 0.f, 0.f, 0.f};
      acc = __builtin_amdgcn_mfma_f32_16x16x32_bf16(a0, b0, acc, 0, 0, 0);
      acc = __builtin_amdgcn_mfma_f32_16x16x32_bf16(a1, b1, acc, 0, 0, 0);
      if (p < E) {
        bf16x4 h;
#pragma unroll
        for (int r = 0; r < 4; ++r) h[r] = f2bf(acc[r] * kINV_L3);
        *reinterpret_cast<bf16x4*>(&tpw[(size_t)p * 512 + rt * 16 + g * 4]) = h;
      }
    }
  }
}

// ---------------------------------------------------------------------------
// Kernel B: owner-computes aggregation. One block per receiver node; reads
// precomputed tpw at contiguous sorted positions (coalesced 512B bursts).
// Thread t owns tpw cols {t, t+256} = the {w_a,w_c} (t<128) / {w_b,w_d}
// (t>=128) pair its accumulator needs.
// ---------------------------------------------------------------------------
__global__ __launch_bounds__(256) void k_gather(
    const int* __restrict__ sorted, const int* __restrict__ offs,
    const short* __restrict__ tpw, const float* __restrict__ eattr,
    const int* __restrict__ eidx,
    const float* __restrict__ s_up, const float* __restrict__ v_up,
    float* __restrict__ Ms, float* __restrict__ Mv) {
  __shared__ float sea[8][4];
  __shared__ int   ssnd[8];

  const int n = blockIdx.x;
  const int t = threadIdx.x;

  float aMs = 0.f, aV0 = 0.f, aV1 = 0.f, aV2 = 0.f;

  const int e0 = offs[n], eEnd = offs[n + 1];

  for (int eb = e0; eb < eEnd; eb += 8) {
    __syncthreads();
    if (t < 32) {
      int le = t >> 2, f = t & 3;
      int p = eb + le;
      int eid = (p < eEnd) ? sorted[p] : -1;
      if (f == 0) ssnd[le] = (eid >= 0) ? eidx[eid] : 0;
      sea[le][f] = (eid >= 0) ? eattr[(size_t)eid * 4 + f] : 0.f;
    }
    __syncthreads();

    float tpA[8], tpB[8];
#pragma unroll
    for (int le = 0; le < 8; ++le) {
      int p = eb + le;
      if (p < eEnd) {
        tpA[le] = bf2f(tpw[(size_t)p * 512 + t]);
        tpB[le] = bf2f(tpw[(size_t)p * 512 + 256 + t]);
      } else {
        tpA[le] = 0.f; tpB[le] = 0.f;
      }
    }

    if (t < 128) {
      const int u = t;
#pragma unroll
      for (int le = 0; le < 8; ++le) {
        float xs  = s_up[(size_t)ssnd[le] * 128 + u];
        float eas = sea[le][0];
        aMs += tpA[le] * xs * eas;                 // m0 = w_a*xs*ea_s
        float wc = tpB[le] * xs;                   // w_c*xs
        aV0 += wc * sea[le][1];
        aV1 += wc * sea[le][2];
        aV2 += wc * sea[le][3];
      }
    } else {
      const int u = t - 128;
#pragma unroll
      for (int le = 0; le < 8; ++le) {
        const float* xv = v_up + (size_t)ssnd[le] * 384 + u;
        float x0 = xv[0], x1 = xv[128], x2 = xv[256];
        float ev0 = sea[le][1], ev1 = sea[le][2], ev2 = sea[le][3];
        float dot = x0 * ev0 + x1 * ev1 + x2 * ev2;
        aMs += tpA[le] * dot * kINV_SQ3;           // m1 = w_b*dot/sqrt3
        float wd = tpB[le] * sea[le][0];           // w_d*ea_s
        aV0 += wd * x0; aV1 += wd * x1; aV2 += wd * x2;
      }
    }
  }

  Ms[(size_t)n * 256 + t]        = aMs;
  Mv[(size_t)n * 768 + t]        = aV0;
  Mv[(size_t)n * 768 + 256 + t]  = aV1;
  Mv[(size_t)n * 768 + 512 + t]  = aV2;
}

// ---------------------------------------------------------------------------
// Kernel C (MFMA): fused lin + skip + combine (unchanged from R3 — passed).
// ---------------------------------------------------------------------------
__global__ __launch_bounds__(256) void k_linskip(
    const float* __restrict__ Ms, const float* __restrict__ Mv,
    const short* __restrict__ Wl0T, const short* __restrict__ Wl1T,
    const short* __restrict__ Wsk0T, const short* __restrict__ Wsk1T,
    const float* __restrict__ attrs, const float* __restrict__ upd,
    float* __restrict__ out, int N) {
  __shared__ __align__(16) short lsA[4][16][264];
  __shared__ __align__(16) short lsS[4][16][136];
  __shared__ float sat[16][4];
  const int nb = blockIdx.x * 16;
  const int t = threadIdx.x;

  for (int base = t * 4; base < 16 * 1024; base += 1024) {
    int n = base >> 10, j = base & 1023;
    int comp = j >> 8, u = j & 255;
    float4 q = {0.f, 0.f, 0.f, 0.f};
    if (nb + n < N) {
      const float* src = (comp == 0) ? (Ms + (size_t)(nb + n) * 256 + u)
                                     : (Mv + (size_t)(nb + n) * 768 + (size_t)(comp - 1) * 256 + u);
      q = *reinterpret_cast<const float4*>(src);
    }
    lsA[comp][n][u + 0] = f2bf(q.x);
    lsA[comp][n][u + 1] = f2bf(q.y);
    lsA[comp][n][u + 2] = f2bf(q.z);
    lsA[comp][n][u + 3] = f2bf(q.w);
  }
  if (t < 64) {
    int n = t >> 2, v = t & 3;
    sat[n][v] = (nb + n < N) ? attrs[(size_t)(nb + n) * 4 + v] : 0.f;
  }
  __syncthreads();

  const int c = t >> 6;
  const int lane = t & 63;
  const int col = lane & 15;
  const int g = lane >> 4;

  const short* WLT = c ? Wl1T : Wl0T;
  const short* WST = c ? Wsk1T : Wsk0T;

  bf16x8 af1[8];
#pragma unroll
  for (int kk = 0; kk < 8; ++kk)
    af1[kk] = *reinterpret_cast<const bf16x8*>(&lsA[c][col][kk * 32 + g * 8]);

  f32x4 Sreg[8];
#pragma unroll
  for (int nt = 0; nt < 8; ++nt) {
    f32x4 acc = {0.f, 0.f, 0.f, 0.f};
#pragma unroll
    for (int kk = 0; kk < 8; ++kk) {
      bf16x8 bf = *reinterpret_cast<const bf16x8*>(&WLT[(size_t)(nt * 16 + col) * 256 + kk * 32 + g * 8]);
      acc = __builtin_amdgcn_mfma_f32_16x16x32_bf16(af1[kk], bf, acc, 0, 0, 0);
    }
#pragma unroll
    for (int r = 0; r < 4; ++r) acc[r] *= kINV_LIN;
    Sreg[nt] = acc;
#pragma unroll
    for (int r = 0; r < 4; ++r)
      lsS[c][g * 4 + r][nt * 16 + col] = f2bf(acc[r]);
  }

  float satr[4][4];
#pragma unroll
  for (int r = 0; r < 4; ++r)
#pragma unroll
    for (int v = 0; v < 4; ++v) satr[r][v] = sat[g * 4 + r][v];

  __syncthreads();

  bf16x8 af2[4];
#pragma unroll
  for (int kk = 0; kk < 4; ++kk)
    af2[kk] = *reinterpret_cast<const bf16x8*>(&lsS[c][col][kk * 32 + g * 8]);

  const float p = upd[0];
  const float cc = 1.f / (1.f + __expf(-p));
  const float c_old = rsqrtf(cc * cc + 1.f);
  const float c_new = cc * c_old;

#pragma unroll
  for (int nt = 0; nt < 8; ++nt) {
    float fin[4] = {0.f, 0.f, 0.f, 0.f};
#pragma unroll
    for (int v = 0; v < 4; ++v) {
      f32x4 tmp = {0.f, 0.f, 0.f, 0.f};
#pragma unroll
      for (int kk = 0; kk < 4; ++kk) {
        bf16x8 bf = *reinterpret_cast<const bf16x8*>(&WST[(size_t)(nt * 16 + col) * 512 + v * 128 + kk * 32 + g * 8]);
        tmp = __builtin_amdgcn_mfma_f32_16x16x32_bf16(af2[kk], bf, tmp, 0, 0, 0);
      }
#pragma unroll
      for (int r = 0; r < 4; ++r) fin[r] += satr[r][v] * tmp[r];
    }
#pragma unroll
    for (int r = 0; r < 4; ++r) {
      int nd = nb + g * 4 + r;
      if (nd < N) {
        float val = c_old * Sreg[nt][r] + c_new * fin[r] * kINV_SK;
        out[((size_t)nd * 128 + nt * 16 + col) * 4 + c] = val;
      }
    }
  }
}

extern "C" void kernel_launch(void* const* d_in, const int* in_sizes, int n_in,
                              void* d_out, int out_size, void* d_ws, size_t ws_size,
                              hipStream_t stream) {
  const float* node_attrs = (const float*)d_in[0];
  const float* node_feats = (const float*)d_in[1];
  const float* edge_attrs = (const float*)d_in[2];
  const float* edge_feats = (const float*)d_in[3];
  const int*   edge_index = (const int*)d_in[4];
  const float* W_up0  = (const float*)d_in[5];
  const float* W_up1  = (const float*)d_in[6];
  const float* W_mlp1 = (const float*)d_in[7];
  const float* W_mlp2 = (const float*)d_in[8];
  const float* W_mlp3 = (const float*)d_in[9];
  const float* W_lin0 = (const float*)d_in[10];
  const float* W_lin1 = (const float*)d_in[11];
  const float* W_skip0 = (const float*)d_in[12];
  const float* W_skip1 = (const float*)d_in[13];
  const float* upd = (const float*)d_in[14];
  float* out = (float*)d_out;

  const int N = in_sizes[0] / 4;
  const int E = in_sizes[4] / 2;

  float* ws = (float*)d_ws;
  float* s_up = ws;                          // N*128
  float* v_up = s_up + (size_t)N * 128;      // N*384  [n][i][u]
  float* Ms   = v_up + (size_t)N * 384;      // N*256
  float* Mv   = Ms + (size_t)N * 256;        // N*768  [n][i][u]
  int* cnt    = (int*)(Mv + (size_t)N * 768); // N
  int* offs   = cnt + N;                      // N+1
  int* cursor = offs + N + 1;                 // N
  int* sorted = cursor + N;                   // E

  // bf16 arrays, 16B-aligned
  short* wbase = (short*)((((uintptr_t)(sorted + E)) + 15) & ~(uintptr_t)15);
  short* W0T   = wbase;            // 128*128
  short* W1T   = W0T + 16384;      // 128*128
  short* Wl0T  = W1T + 16384;      // 128*256
  short* Wl1T  = Wl0T + 32768;     // 128*256
  short* Wsk0T = Wl1T + 32768;     // 128*512
  short* Wsk1T = Wsk0T + 65536;    // 128*512
  short* W2T   = Wsk1T + 65536;    // 64*64
  short* W3T   = W2T + 4096;       // 512*64
  short* tpw   = W3T + 32768;      // E*512

  hipMemsetAsync(cnt, 0, (size_t)N * sizeof(int), stream);

  k_cvt<<<(266240 + 255) / 256, 256, 0, stream>>>(W_up0, W_up1, W_lin0, W_lin1,
                                                  W_skip0, W_skip1, W_mlp2, W_mlp3,
                                                  W0T, W1T, Wl0T, Wl1T, Wsk0T, Wsk1T,
                                                  W2T, W3T);
  k_up_mfma<<<(N + 15) / 16, 256, 0, stream>>>(node_feats, W0T, W1T, s_up, v_up, N);
  k_count<<<(E + 255) / 256, 256, 0, stream>>>(edge_index, cnt, E);
  k_scan<<<1, 1024, 0, stream>>>(cnt, offs, cursor, N);
  k_scatter<<<(E + 255) / 256, 256, 0, stream>>>(edge_index, cursor, sorted, E);
  k_mlp<<<(E + 63) / 64, 256, 0, stream>>>(sorted, edge_feats, W_mlp1, W2T, W3T, tpw, E);
  k_gather<<<N, 256, 0, stream>>>(sorted, offs, tpw, edge_attrs, edge_index,
                                  s_up, v_up, Ms, Mv);
  k_linskip<<<(N + 15) / 16, 256, 0, stream>>>(Ms, Mv, Wl0T, Wl1T, Wsk0T, Wsk1T,
                                               node_attrs, upd, out, N);
}

// Round 5
// 327.160 us; speedup vs baseline: 27.5250x; 1.0609x over previous
//
#include <hip/hip_runtime.h>

#define MUL 128

typedef __attribute__((ext_vector_type(8))) short bf16x8;
typedef __attribute__((ext_vector_type(4))) short bf16x4;
typedef __attribute__((ext_vector_type(4))) float f32x4;

__device__ __constant__ float kINV_UP   = 0.08838834764831845f;  // 1/sqrt(128)
__device__ __constant__ float kINV_L1   = 0.35355339059327373f;  // 1/sqrt(8)
__device__ __constant__ float kINV_L2   = 0.125f;                // 1/sqrt(64)
__device__ __constant__ float kINV_L3   = 0.125f;
__device__ __constant__ float kINV_LIN  = 0.00390625f;           // 1/(sqrt(256)*16)
__device__ __constant__ float kINV_SK   = 0.044194173824159216f; // 1/sqrt(512)
__device__ __constant__ float kINV_SQ3  = 0.5773502691896258f;   // 1/sqrt(3)

static __device__ __forceinline__ short f2bf(float f) {
  unsigned u = __float_as_uint(f);
  unsigned r = (u + 0x7FFFu + ((u >> 16) & 1u)) >> 16;  // RNE
  return (short)r;
}

// ---------------------------------------------------------------------------
// Weight conversion to bf16, transposed to [out_col][k].
// ---------------------------------------------------------------------------
__global__ __launch_bounds__(256) void k_cvt(
    const float* __restrict__ W_up0, const float* __restrict__ W_up1,
    const float* __restrict__ W_lin0, const float* __restrict__ W_lin1,
    const float* __restrict__ W_sk0, const float* __restrict__ W_sk1,
    const float* __restrict__ W_mlp2, const float* __restrict__ W_mlp3,
    short* __restrict__ W0T, short* __restrict__ W1T,
    short* __restrict__ Wl0T, short* __restrict__ Wl1T,
    short* __restrict__ Wsk0T, short* __restrict__ Wsk1T,
    short* __restrict__ W2T, short* __restrict__ W3T) {
  int id = blockIdx.x * 256 + threadIdx.x;
  if (id < 16384) {
    int w = id >> 7, u = id & 127;
    W0T[id] = f2bf(W_up0[u * 128 + w]);
    return;
  }
  id -= 16384;
  if (id < 16384) {
    int w = id >> 7, u = id & 127;
    W1T[id] = f2bf(W_up1[u * 128 + w]);
    return;
  }
  id -= 16384;
  if (id < 32768) {
    int w = id >> 8, u = id & 255;
    Wl0T[id] = f2bf(W_lin0[u * 128 + w]);
    return;
  }
  id -= 32768;
  if (id < 32768) {
    int w = id >> 8, u = id & 255;
    Wl1T[id] = f2bf(W_lin1[u * 128 + w]);
    return;
  }
  id -= 32768;
  if (id < 65536) {
    int w = id >> 9, k = id & 511;
    int v = k >> 7, u = k & 127;
    Wsk0T[id] = f2bf(W_sk0[(u * 4 + v) * 128 + w]);
    return;
  }
  id -= 65536;
  if (id < 65536) {
    int w = id >> 9, k = id & 511;
    int v = k >> 7, u = k & 127;
    Wsk1T[id] = f2bf(W_sk1[(u * 4 + v) * 128 + w]);
    return;
  }
  id -= 65536;
  if (id < 4096) {
    int c = id >> 6, k = id & 63;
    W2T[id] = f2bf(W_mlp2[k * 64 + c]);
    return;
  }
  id -= 4096;
  if (id < 32768) {
    int c = id >> 6, k = id & 63;
    W3T[id] = f2bf(W_mlp3[k * 512 + c]);
  }
}

// ---------------------------------------------------------------------------
// Kernel A (MFMA): node up-projection (unchanged — passed).
// ---------------------------------------------------------------------------
__global__ __launch_bounds__(256) void k_up_mfma(const float* __restrict__ nf,
                                                 const short* __restrict__ W0T,
                                                 const short* __restrict__ W1T,
                                                 float* __restrict__ s_up,
                                                 float* __restrict__ v_up,
                                                 int N) {
  __shared__ __align__(16) short lsA[4][16][136];
  const int nb = blockIdx.x * 16;
  const int t = threadIdx.x;

  for (int base = t * 8; base < 16 * 512; base += 256 * 8) {
    int n = base >> 9, j0 = base & 511;
    float vals[8];
    if (nb + n < N) {
      float4 q0 = *reinterpret_cast<const float4*>(nf + (size_t)(nb + n) * 512 + j0);
      float4 q1 = *reinterpret_cast<const float4*>(nf + (size_t)(nb + n) * 512 + j0 + 4);
      vals[0] = q0.x; vals[1] = q0.y; vals[2] = q0.z; vals[3] = q0.w;
      vals[4] = q1.x; vals[5] = q1.y; vals[6] = q1.z; vals[7] = q1.w;
    } else {
#pragma unroll
      for (int e = 0; e < 8; ++e) vals[e] = 0.f;
    }
#pragma unroll
    for (int e = 0; e < 8; ++e) {
      int idx = j0 + e;
      if (idx < 128) {
        lsA[0][n][idx] = f2bf(vals[e]);
      } else {
        unsigned q = idx - 128;
        unsigned u = q / 3u;
        unsigned i = q - u * 3u;
        lsA[1 + i][n][u] = f2bf(vals[e]);
      }
    }
  }
  __syncthreads();

  const int c = t >> 6;
  const int lane = t & 63;
  const int col = lane & 15;
  const int g = lane >> 4;

  const short* WT = c ? W1T : W0T;

  bf16x8 af[4];
#pragma unroll
  for (int kk = 0; kk < 4; ++kk)
    af[kk] = *reinterpret_cast<const bf16x8*>(&lsA[c][col][kk * 32 + g * 8]);

#pragma unroll
  for (int nt = 0; nt < 8; ++nt) {
    f32x4 acc = {0.f, 0.f, 0.f, 0.f};
#pragma unroll
    for (int kk = 0; kk < 4; ++kk) {
      bf16x8 bf = *reinterpret_cast<const bf16x8*>(&WT[(size_t)(nt * 16 + col) * 128 + kk * 32 + g * 8]);
      acc = __builtin_amdgcn_mfma_f32_16x16x32_bf16(af[kk], bf, acc, 0, 0, 0);
    }
#pragma unroll
    for (int r = 0; r < 4; ++r) {
      int nd = nb + g * 4 + r;
      if (nd < N) {
        float val = acc[r] * kINV_UP;
        if (c == 0) s_up[(size_t)nd * 128 + nt * 16 + col] = val;
        else        v_up[(size_t)nd * 384 + (c - 1) * 128 + nt * 16 + col] = val;
      }
    }
  }
}

// ---------------------------------------------------------------------------
// Counting sort of edges by receiver: count -> scan -> scatter.
// ---------------------------------------------------------------------------
__global__ void k_count(const int* __restrict__ eidx, int* __restrict__ cnt, int E) {
  int e = blockIdx.x * 256 + threadIdx.x;
  if (e < E) atomicAdd(&cnt[eidx[E + e]], 1);
}

__global__ __launch_bounds__(1024) void k_scan(const int* __restrict__ cnt,
                                               int* __restrict__ offs,
                                               int* __restrict__ cursor, int N) {
  __shared__ int part[1024];
  const int t = threadIdx.x;
  int CH = (N + 1023) >> 10;
  if (CH > 16) CH = 16;
  const int base = t * CH;
  int loc[16];
  int s = 0;
  for (int i = 0; i < CH; ++i) {
    int idx = base + i;
    loc[i] = (idx < N) ? cnt[idx] : 0;
    s += loc[i];
  }
  part[t] = s;
  __syncthreads();
  for (int off = 1; off < 1024; off <<= 1) {
    int v = part[t];
    int add = (t >= off) ? part[t - off] : 0;
    __syncthreads();
    part[t] = v + add;
    __syncthreads();
  }
  int excl = part[t] - s;
  for (int i = 0; i < CH; ++i) {
    int idx = base + i;
    if (idx < N) { offs[idx] = excl; cursor[idx] = excl; }
    excl += loc[i];
  }
  if (t == 1023) offs[N] = part[1023];
}

__global__ void k_scatter(const int* __restrict__ eidx, int* __restrict__ cursor,
                          int* __restrict__ sorted, int E) {
  int e = blockIdx.x * 256 + threadIdx.x;
  if (e < E) {
    int r = eidx[E + e];
    int p = atomicAdd(&cursor[r], 1);
    sorted[p] = e;
  }
}

// ---------------------------------------------------------------------------
// Kernel MLP (MFMA): per-edge 3-layer MLP -> tpw2[p][256] uint, where dword u
// packs (lo = tpw col u, hi = tpw col u+256), i.e. the (w_a,w_c)/(w_b,w_d)
// pair the gather needs. Per rt: accA (cols rt*16..) and accB (cols
// 256+rt*16..) -> 4 packed dwords -> one 16B store (64B segments/wave).
// kINV_L3 folded in.
// ---------------------------------------------------------------------------
__global__ __launch_bounds__(256) void k_mlp(
    const int* __restrict__ sorted, const float* __restrict__ ef,
    const float* __restrict__ W1, const short* __restrict__ W2T,
    const short* __restrict__ W3T, unsigned* __restrict__ tpw2, int E) {
  __shared__ float sef[64][12];
  __shared__ float sW1[8 * 64];
  __shared__ __align__(16) short sW2T[64][72];
  __shared__ __align__(16) short sh1[64][72];
  __shared__ __align__(16) short sh2[64][72];

  const int pb = blockIdx.x * 64;
  const int t = threadIdx.x;

  for (int i = t * 4; i < 512; i += 1024)
    *reinterpret_cast<float4*>(&sW1[i]) = *reinterpret_cast<const float4*>(W1 + i);
  for (int i = t * 8; i < 4096; i += 2048) {
    int r = i >> 6, c = i & 63;
    *reinterpret_cast<bf16x8*>(&sW2T[r][c]) = *reinterpret_cast<const bf16x8*>(&W2T[r * 64 + c]);
  }
  if (t < 128) {
    int le = t >> 1, half = t & 1;
    int p = pb + le;
    float4 q = {0.f, 0.f, 0.f, 0.f};
    if (p < E) {
      int eid = sorted[p];
      q = *reinterpret_cast<const float4*>(ef + (size_t)eid * 8 + half * 4);
    }
    *reinterpret_cast<float4*>(&sef[le][half * 4]) = q;
  }
  __syncthreads();

  // layer 1 (VALU)
  {
    const int e = t & 63, cg = t >> 6;
    float acc[16] = {};
#pragma unroll
    for (int k = 0; k < 8; ++k) {
      float x = sef[e][k];
#pragma unroll
      for (int j = 0; j < 16; ++j) acc[j] += x * sW1[k * 64 + cg * 16 + j];
    }
#pragma unroll
    for (int j = 0; j < 16; ++j) {
      float a = acc[j] * kINV_L1;
      sh1[e][cg * 16 + j] = f2bf(a / (1.f + __expf(-a)));
    }
  }
  __syncthreads();

  const int lane = t & 63, w = t >> 6;
  const int li = lane & 15, g = lane >> 4;
  const int e = w * 16 + li;

  // layer 2 (MFMA, swapped)
  {
    bf16x8 b0 = *reinterpret_cast<const bf16x8*>(&sh1[e][g * 8]);
    bf16x8 b1 = *reinterpret_cast<const bf16x8*>(&sh1[e][32 + g * 8]);
#pragma unroll
    for (int ct = 0; ct < 4; ++ct) {
      bf16x8 a0 = *reinterpret_cast<const bf16x8*>(&sW2T[ct * 16 + li][g * 8]);
      bf16x8 a1 = *reinterpret_cast<const bf16x8*>(&sW2T[ct * 16 + li][32 + g * 8]);
      f32x4 acc = {0.f, 0.f, 0.f, 0.f};
      acc = __builtin_amdgcn_mfma_f32_16x16x32_bf16(a0, b0, acc, 0, 0, 0);
      acc = __builtin_amdgcn_mfma_f32_16x16x32_bf16(a1, b1, acc, 0, 0, 0);
      bf16x4 h;
#pragma unroll
      for (int r = 0; r < 4; ++r) {
        float a = acc[r] * kINV_L2;
        h[r] = f2bf(a / (1.f + __expf(-a)));
      }
      *reinterpret_cast<bf16x4*>(&sh2[e][ct * 16 + g * 4]) = h;
    }
  }
  __syncthreads();

  // layer 3 (MFMA, swapped), A-half (cols u) and B-half (cols u+256) paired
  {
    const int p = pb + e;
    bf16x8 b0 = *reinterpret_cast<const bf16x8*>(&sh2[e][g * 8]);
    bf16x8 b1 = *reinterpret_cast<const bf16x8*>(&sh2[e][32 + g * 8]);
#pragma unroll 4
    for (int rt = 0; rt < 16; ++rt) {
      const int rowA = rt * 16 + li;
      bf16x8 a0 = *reinterpret_cast<const bf16x8*>(&W3T[(size_t)rowA * 64 + g * 8]);
      bf16x8 a1 = *reinterpret_cast<const bf16x8*>(&W3T[(size_t)rowA * 64 + 32 + g * 8]);
      bf16x8 a2 = *reinterpret_cast<const bf16x8*>(&W3T[(size_t)(rowA + 256) * 64 + g * 8]);
      bf16x8 a3 = *reinterpret_cast<const bf16x8*>(&W3T[(size_t)(rowA + 256) * 64 + 32 + g * 8]);
      f32x4 accA = {0.f, 0.f, 0.f, 0.f};
      f32x4 accB = {0.f, 0.f, 0.f, 0.f};
      accA = __builtin_amdgcn_mfma_f32_16x16x32_bf16(a0, b0, accA, 0, 0, 0);
      accA = __builtin_amdgcn_mfma_f32_16x16x32_bf16(a1, b1, accA, 0, 0, 0);
      accB = __builtin_amdgcn_mfma_f32_16x16x32_bf16(a2, b0, accB, 0, 0, 0);
      accB = __builtin_amdgcn_mfma_f32_16x16x32_bf16(a3, b1, accB, 0, 0, 0);
      if (p < E) {
        uint4 d;
        unsigned* dp = &d.x;
#pragma unroll
        for (int r = 0; r < 4; ++r) {
          unsigned lo = (unsigned)(unsigned short)f2bf(accA[r] * kINV_L3);
          unsigned hi = (unsigned)(unsigned short)f2bf(accB[r] * kINV_L3);
          dp[r] = lo | (hi << 16);
        }
        *reinterpret_cast<uint4*>(&tpw2[(size_t)p * 256 + rt * 16 + g * 4]) = d;
      }
    }
  }
}

// ---------------------------------------------------------------------------
// Kernel B: barrier-free, divergence-free gather. One WAVE per node; grid is
// doubled: blocks [0,SB) do the s-side (w_a/w_c -> Ms[0:128), Mv[i][0:128)),
// blocks [SB,2SB) the v-side (w_b/w_d -> Ms[128:), Mv[i][128:)). Lane owns 2
// columns; tpw2 read as dword2 (packed pair), node rows as float2. Per-edge
// scalars are same-address wave broadcasts (L1). No LDS, no __syncthreads.
// ---------------------------------------------------------------------------
__global__ __launch_bounds__(256) void k_gather(
    const int* __restrict__ sorted, const int* __restrict__ offs,
    const unsigned* __restrict__ tpw2, const float* __restrict__ eattr,
    const int* __restrict__ eidx,
    const float* __restrict__ s_up, const float* __restrict__ v_up,
    float* __restrict__ Ms, float* __restrict__ Mv, int N, int SB) {
  const int t = threadIdx.x;
  const int vside = blockIdx.x >= SB;
  const int nb = (vside ? blockIdx.x - SB : blockIdx.x) * 4;
  const int n = nb + (t >> 6);
  if (n >= N) return;
  const int l = t & 63;
  const int u0 = l * 2;  // 2 columns per lane, u0 in [0,128)

  float aMs0 = 0.f, aMs1 = 0.f;
  float aV[3][2] = {};

  const int e0 = offs[n], e1 = offs[n + 1];

  if (!vside) {
    for (int p = e0; p < e1; ++p) {
      int eid = sorted[p];
      int snd = eidx[eid];
      float4 ea = *reinterpret_cast<const float4*>(eattr + (size_t)eid * 4);
      uint2 q = *reinterpret_cast<const uint2*>(tpw2 + (size_t)p * 256 + u0);
      float2 xs = *reinterpret_cast<const float2*>(s_up + (size_t)snd * 128 + u0);
      float tA0 = __uint_as_float(q.x << 16);
      float tB0 = __uint_as_float(q.x & 0xFFFF0000u);
      float tA1 = __uint_as_float(q.y << 16);
      float tB1 = __uint_as_float(q.y & 0xFFFF0000u);
      float xe0 = xs.x * ea.x, xe1 = xs.y * ea.x;
      aMs0 += tA0 * xe0;
      aMs1 += tA1 * xe1;
      float wc0 = tB0 * xs.x, wc1 = tB1 * xs.y;
      aV[0][0] += wc0 * ea.y; aV[0][1] += wc1 * ea.y;
      aV[1][0] += wc0 * ea.z; aV[1][1] += wc1 * ea.z;
      aV[2][0] += wc0 * ea.w; aV[2][1] += wc1 * ea.w;
    }
    *reinterpret_cast<float2*>(Ms + (size_t)n * 256 + u0) = make_float2(aMs0, aMs1);
#pragma unroll
    for (int i = 0; i < 3; ++i)
      *reinterpret_cast<float2*>(Mv + (size_t)n * 768 + i * 256 + u0) =
          make_float2(aV[i][0], aV[i][1]);
  } else {
    for (int p = e0; p < e1; ++p) {
      int eid = sorted[p];
      int snd = eidx[eid];
      float4 ea = *reinterpret_cast<const float4*>(eattr + (size_t)eid * 4);
      uint2 q = *reinterpret_cast<const uint2*>(tpw2 + (size_t)p * 256 + 128 + u0);
      const float* xv = v_up + (size_t)snd * 384 + u0;
      float2 x0 = *reinterpret_cast<const float2*>(xv);
      float2 x1 = *reinterpret_cast<const float2*>(xv + 128);
      float2 x2 = *reinterpret_cast<const float2*>(xv + 256);
      float tA0 = __uint_as_float(q.x << 16);
      float tB0 = __uint_as_float(q.x & 0xFFFF0000u);
      float tA1 = __uint_as_float(q.y << 16);
      float tB1 = __uint_as_float(q.y & 0xFFFF0000u);
      float dot0 = x0.x * ea.y + x1.x * ea.z + x2.x * ea.w;
      float dot1 = x0.y * ea.y + x1.y * ea.z + x2.y * ea.w;
      aMs0 += tA0 * dot0 * kINV_SQ3;
      aMs1 += tA1 * dot1 * kINV_SQ3;
      float wd0 = tB0 * ea.x, wd1 = tB1 * ea.x;
      aV[0][0] += wd0 * x0.x; aV[0][1] += wd1 * x0.y;
      aV[1][0] += wd0 * x1.x; aV[1][1] += wd1 * x1.y;
      aV[2][0] += wd0 * x2.x; aV[2][1] += wd1 * x2.y;
    }
    *reinterpret_cast<float2*>(Ms + (size_t)n * 256 + 128 + u0) = make_float2(aMs0, aMs1);
#pragma unroll
    for (int i = 0; i < 3; ++i)
      *reinterpret_cast<float2*>(Mv + (size_t)n * 768 + i * 256 + 128 + u0) =
          make_float2(aV[i][0], aV[i][1]);
  }
}

// ---------------------------------------------------------------------------
// Kernel C (MFMA): fused lin + skip + combine (unchanged — passed).
// ---------------------------------------------------------------------------
__global__ __launch_bounds__(256) void k_linskip(
    const float* __restrict__ Ms, const float* __restrict__ Mv,
    const short* __restrict__ Wl0T, const short* __restrict__ Wl1T,
    const short* __restrict__ Wsk0T, const short* __restrict__ Wsk1T,
    const float* __restrict__ attrs, const float* __restrict__ upd,
    float* __restrict__ out, int N) {
  __shared__ __align__(16) short lsA[4][16][264];
  __shared__ __align__(16) short lsS[4][16][136];
  __shared__ float sat[16][4];
  const int nb = blockIdx.x * 16;
  const int t = threadIdx.x;

  for (int base = t * 4; base < 16 * 1024; base += 1024) {
    int n = base >> 10, j = base & 1023;
    int comp = j >> 8, u = j & 255;
    float4 q = {0.f, 0.f, 0.f, 0.f};
    if (nb + n < N) {
      const float* src = (comp == 0) ? (Ms + (size_t)(nb + n) * 256 + u)
                                     : (Mv + (size_t)(nb + n) * 768 + (size_t)(comp - 1) * 256 + u);
      q = *reinterpret_cast<const float4*>(src);
    }
    lsA[comp][n][u + 0] = f2bf(q.x);
    lsA[comp][n][u + 1] = f2bf(q.y);
    lsA[comp][n][u + 2] = f2bf(q.z);
    lsA[comp][n][u + 3] = f2bf(q.w);
  }
  if (t < 64) {
    int n = t >> 2, v = t & 3;
    sat[n][v] = (nb + n < N) ? attrs[(size_t)(nb + n) * 4 + v] : 0.f;
  }
  __syncthreads();

  const int c = t >> 6;
  const int lane = t & 63;
  const int col = lane & 15;
  const int g = lane >> 4;

  const short* WLT = c ? Wl1T : Wl0T;
  const short* WST = c ? Wsk1T : Wsk0T;

  bf16x8 af1[8];
#pragma unroll
  for (int kk = 0; kk < 8; ++kk)
    af1[kk] = *reinterpret_cast<const bf16x8*>(&lsA[c][col][kk * 32 + g * 8]);

  f32x4 Sreg[8];
#pragma unroll
  for (int nt = 0; nt < 8; ++nt) {
    f32x4 acc = {0.f, 0.f, 0.f, 0.f};
#pragma unroll
    for (int kk = 0; kk < 8; ++kk) {
      bf16x8 bf = *reinterpret_cast<const bf16x8*>(&WLT[(size_t)(nt * 16 + col) * 256 + kk * 32 + g * 8]);
      acc = __builtin_amdgcn_mfma_f32_16x16x32_bf16(af1[kk], bf, acc, 0, 0, 0);
    }
#pragma unroll
    for (int r = 0; r < 4; ++r) acc[r] *= kINV_LIN;
    Sreg[nt] = acc;
#pragma unroll
    for (int r = 0; r < 4; ++r)
      lsS[c][g * 4 + r][nt * 16 + col] = f2bf(acc[r]);
  }

  float satr[4][4];
#pragma unroll
  for (int r = 0; r < 4; ++r)
#pragma unroll
    for (int v = 0; v < 4; ++v) satr[r][v] = sat[g * 4 + r][v];

  __syncthreads();

  bf16x8 af2[4];
#pragma unroll
  for (int kk = 0; kk < 4; ++kk)
    af2[kk] = *reinterpret_cast<const bf16x8*>(&lsS[c][col][kk * 32 + g * 8]);

  const float p = upd[0];
  const float cc = 1.f / (1.f + __expf(-p));
  const float c_old = rsqrtf(cc * cc + 1.f);
  const float c_new = cc * c_old;

#pragma unroll
  for (int nt = 0; nt < 8; ++nt) {
    float fin[4] = {0.f, 0.f, 0.f, 0.f};
#pragma unroll
    for (int v = 0; v < 4; ++v) {
      f32x4 tmp = {0.f, 0.f, 0.f, 0.f};
#pragma unroll
      for (int kk = 0; kk < 4; ++kk) {
        bf16x8 bf = *reinterpret_cast<const bf16x8*>(&WST[(size_t)(nt * 16 + col) * 512 + v * 128 + kk * 32 + g * 8]);
        tmp = __builtin_amdgcn_mfma_f32_16x16x32_bf16(af2[kk], bf, tmp, 0, 0, 0);
      }
#pragma unroll
      for (int r = 0; r < 4; ++r) fin[r] += satr[r][v] * tmp[r];
    }
#pragma unroll
    for (int r = 0; r < 4; ++r) {
      int nd = nb + g * 4 + r;
      if (nd < N) {
        float val = c_old * Sreg[nt][r] + c_new * fin[r] * kINV_SK;
        out[((size_t)nd * 128 + nt * 16 + col) * 4 + c] = val;
      }
    }
  }
}

extern "C" void kernel_launch(void* const* d_in, const int* in_sizes, int n_in,
                              void* d_out, int out_size, void* d_ws, size_t ws_size,
                              hipStream_t stream) {
  const float* node_attrs = (const float*)d_in[0];
  const float* node_feats = (const float*)d_in[1];
  const float* edge_attrs = (const float*)d_in[2];
  const float* edge_feats = (const float*)d_in[3];
  const int*   edge_index = (const int*)d_in[4];
  const float* W_up0  = (const float*)d_in[5];
  const float* W_up1  = (const float*)d_in[6];
  const float* W_mlp1 = (const float*)d_in[7];
  const float* W_mlp2 = (const float*)d_in[8];
  const float* W_mlp3 = (const float*)d_in[9];
  const float* W_lin0 = (const float*)d_in[10];
  const float* W_lin1 = (const float*)d_in[11];
  const float* W_skip0 = (const float*)d_in[12];
  const float* W_skip1 = (const float*)d_in[13];
  const float* upd = (const float*)d_in[14];
  float* out = (float*)d_out;

  const int N = in_sizes[0] / 4;
  const int E = in_sizes[4] / 2;

  float* ws = (float*)d_ws;
  float* s_up = ws;                          // N*128
  float* v_up = s_up + (size_t)N * 128;      // N*384  [n][i][u]
  float* Ms   = v_up + (size_t)N * 384;      // N*256
  float* Mv   = Ms + (size_t)N * 256;        // N*768  [n][i][u]
  int* cnt    = (int*)(Mv + (size_t)N * 768); // N
  int* offs   = cnt + N;                      // N+1
  int* cursor = offs + N + 1;                 // N
  int* sorted = cursor + N;                   // E

  short* wbase = (short*)((((uintptr_t)(sorted + E)) + 15) & ~(uintptr_t)15);
  short* W0T   = wbase;            // 128*128
  short* W1T   = W0T + 16384;      // 128*128
  short* Wl0T  = W1T + 16384;      // 128*256
  short* Wl1T  = Wl0T + 32768;     // 128*256
  short* Wsk0T = Wl1T + 32768;     // 128*512
  short* Wsk1T = Wsk0T + 65536;    // 128*512
  short* W2T   = Wsk1T + 65536;    // 64*64
  short* W3T   = W2T + 4096;       // 512*64
  unsigned* tpw2 = (unsigned*)(W3T + 32768); // E*256 dwords (already 16B-aligned)

  hipMemsetAsync(cnt, 0, (size_t)N * sizeof(int), stream);

  k_cvt<<<(266240 + 255) / 256, 256, 0, stream>>>(W_up0, W_up1, W_lin0, W_lin1,
                                                  W_skip0, W_skip1, W_mlp2, W_mlp3,
                                                  W0T, W1T, Wl0T, Wl1T, Wsk0T, Wsk1T,
                                                  W2T, W3T);
  k_up_mfma<<<(N + 15) / 16, 256, 0, stream>>>(node_feats, W0T, W1T, s_up, v_up, N);
  k_count<<<(E + 255) / 256, 256, 0, stream>>>(edge_index, cnt, E);
  k_scan<<<1, 1024, 0, stream>>>(cnt, offs, cursor, N);
  k_scatter<<<(E + 255) / 256, 256, 0, stream>>>(edge_index, cursor, sorted, E);
  k_mlp<<<(E + 63) / 64, 256, 0, stream>>>(sorted, edge_feats, W_mlp1, W2T, W3T, tpw2, E);
  const int SB = (N + 3) / 4;
  k_gather<<<2 * SB, 256, 0, stream>>>(sorted, offs, tpw2, edge_attrs, edge_index,
                                       s_up, v_up, Ms, Mv, N, SB);
  k_linskip<<<(N + 15) / 16, 256, 0, stream>>>(Ms, Mv, Wl0T, Wl1T, Wsk0T, Wsk1T,
                                               node_attrs, upd, out, N);
}

// Round 6
// 316.815 us; speedup vs baseline: 28.4238x; 1.0327x over previous
//
#include <hip/hip_runtime.h>

#define MUL 128

typedef __attribute__((ext_vector_type(8))) short bf16x8;
typedef __attribute__((ext_vector_type(4))) short bf16x4;
typedef __attribute__((ext_vector_type(4))) float f32x4;

__device__ __constant__ float kINV_UP   = 0.08838834764831845f;  // 1/sqrt(128)
__device__ __constant__ float kINV_L1   = 0.35355339059327373f;  // 1/sqrt(8)
__device__ __constant__ float kINV_L2   = 0.125f;                // 1/sqrt(64)
__device__ __constant__ float kINV_L3   = 0.125f;
__device__ __constant__ float kINV_LIN  = 0.00390625f;           // 1/(sqrt(256)*16)
__device__ __constant__ float kINV_SK   = 0.044194173824159216f; // 1/sqrt(512)
__device__ __constant__ float kINV_SQ3  = 0.5773502691896258f;   // 1/sqrt(3)

// intra-wave LDS ordering: drain ds ops; memory clobber keeps ds_reads below.
#define WAVE_LDS_SYNC() asm volatile("s_waitcnt lgkmcnt(0)" ::: "memory")

static __device__ __forceinline__ short f2bf(float f) {
  unsigned u = __float_as_uint(f);
  unsigned r = (u + 0x7FFFu + ((u >> 16) & 1u)) >> 16;  // RNE
  return (short)r;
}

// ---------------------------------------------------------------------------
// K1 (fused): weight conversion (blocks [0,CVT_B)) | receiver count (rest).
// ---------------------------------------------------------------------------
__global__ __launch_bounds__(256) void k_cvtcnt(
    const float* __restrict__ W_up0, const float* __restrict__ W_up1,
    const float* __restrict__ W_lin0, const float* __restrict__ W_lin1,
    const float* __restrict__ W_sk0, const float* __restrict__ W_sk1,
    const float* __restrict__ W_mlp2, const float* __restrict__ W_mlp3,
    short* __restrict__ W0T, short* __restrict__ W1T,
    short* __restrict__ Wl0T, short* __restrict__ Wl1T,
    short* __restrict__ Wsk0T, short* __restrict__ Wsk1T,
    short* __restrict__ W2T, short* __restrict__ W3T,
    const int* __restrict__ eidx, int* __restrict__ cnt, int E, int CVT_B) {
  int blk = blockIdx.x;
  if (blk >= CVT_B) {
    int e = (blk - CVT_B) * 256 + threadIdx.x;
    if (e < E) atomicAdd(&cnt[eidx[E + e]], 1);
    return;
  }
  int id = blk * 256 + threadIdx.x;
  if (id < 16384) {
    int w = id >> 7, u = id & 127;
    W0T[id] = f2bf(W_up0[u * 128 + w]);
    return;
  }
  id -= 16384;
  if (id < 16384) {
    int w = id >> 7, u = id & 127;
    W1T[id] = f2bf(W_up1[u * 128 + w]);
    return;
  }
  id -= 16384;
  if (id < 32768) {
    int w = id >> 8, u = id & 255;
    Wl0T[id] = f2bf(W_lin0[u * 128 + w]);
    return;
  }
  id -= 32768;
  if (id < 32768) {
    int w = id >> 8, u = id & 255;
    Wl1T[id] = f2bf(W_lin1[u * 128 + w]);
    return;
  }
  id -= 32768;
  if (id < 65536) {
    int w = id >> 9, k = id & 511;
    int v = k >> 7, u = k & 127;
    Wsk0T[id] = f2bf(W_sk0[(u * 4 + v) * 128 + w]);
    return;
  }
  id -= 65536;
  if (id < 65536) {
    int w = id >> 9, k = id & 511;
    int v = k >> 7, u = k & 127;
    Wsk1T[id] = f2bf(W_sk1[(u * 4 + v) * 128 + w]);
    return;
  }
  id -= 65536;
  if (id < 4096) {
    int c = id >> 6, k = id & 63;
    W2T[id] = f2bf(W_mlp2[k * 64 + c]);
    return;
  }
  id -= 4096;
  if (id < 32768) {
    int c = id >> 6, k = id & 63;
    W3T[id] = f2bf(W_mlp3[k * 512 + c]);
  }
}

// ---------------------------------------------------------------------------
// K2: exclusive scan over counts (1 block).
// ---------------------------------------------------------------------------
__global__ __launch_bounds__(1024) void k_scan(const int* __restrict__ cnt,
                                               int* __restrict__ offs,
                                               int* __restrict__ cursor, int N) {
  __shared__ int part[1024];
  const int t = threadIdx.x;
  int CH = (N + 1023) >> 10;
  if (CH > 16) CH = 16;
  const int base = t * CH;
  int loc[16];
  int s = 0;
  for (int i = 0; i < CH; ++i) {
    int idx = base + i;
    loc[i] = (idx < N) ? cnt[idx] : 0;
    s += loc[i];
  }
  part[t] = s;
  __syncthreads();
  for (int off = 1; off < 1024; off <<= 1) {
    int v = part[t];
    int add = (t >= off) ? part[t - off] : 0;
    __syncthreads();
    part[t] = v + add;
    __syncthreads();
  }
  int excl = part[t] - s;
  for (int i = 0; i < CH; ++i) {
    int idx = base + i;
    if (idx < N) { offs[idx] = excl; cursor[idx] = excl; }
    excl += loc[i];
  }
  if (t == 1023) offs[N] = part[1023];
}

// ---------------------------------------------------------------------------
// K3 (fused, block-range dispatch):
//   [0, MLP_B)            : per-edge MLP -> tpw2[eid] (wave-independent)
//   [MLP_B, MLP_B+UP_B)   : node up-projection (MFMA)
//   [MLP_B+UP_B, ...)     : scatter (counting-sort placement)
// All three are mutually independent -> they overlap within one dispatch.
// ---------------------------------------------------------------------------
__global__ __launch_bounds__(256) void k_fused3(
    const int* __restrict__ eidx, int* __restrict__ cursor, int* __restrict__ sorted,
    const float* __restrict__ nf, const short* __restrict__ W0T,
    const short* __restrict__ W1T, float* __restrict__ s_up, float* __restrict__ v_up,
    const float* __restrict__ ef, const float* __restrict__ W1f,
    const short* __restrict__ W2T, const short* __restrict__ W3T,
    unsigned* __restrict__ tpw2, int N, int E, int MLP_B, int UP_B) {
  __shared__ __align__(16) char smem[29696];
  const int t = threadIdx.x;
  int blk = blockIdx.x;

  if (blk < MLP_B) {
    // ---------------- MLP role: 64 edges/block, each wave owns 16 edges ----
    float* sW1  = (float*)smem;                 // 512 f32   (2048 B)
    short* sW2T = (short*)(smem + 2048);        // 64 x 72   (9216 B)
    short* sh1  = (short*)(smem + 11264);       // 4 x 16 x 72
    short* sh2  = (short*)(smem + 20480);       // 4 x 16 x 72

    for (int i = t * 4; i < 512; i += 1024)
      *reinterpret_cast<float4*>(&sW1[i]) = *reinterpret_cast<const float4*>(W1f + i);
    for (int i = t * 8; i < 4096; i += 2048) {
      int r = i >> 6, c = i & 63;
      *reinterpret_cast<bf16x8*>(&sW2T[r * 72 + c]) =
          *reinterpret_cast<const bf16x8*>(&W2T[r * 64 + c]);
    }
    __syncthreads();  // weights visible to all waves; no more block barriers

    const int w = t >> 6, l = t & 63, li = l & 15, g = l >> 4;
    const int e = blk * 64 + w * 16 + li;
    short* h1row = sh1 + (w * 16 + li) * 72;
    short* h2row = sh2 + (w * 16 + li) * 72;

    // layer 1: lane (li,g) computes h1[edge li][g*16 .. g*16+16)
    float4 qa = {0.f, 0.f, 0.f, 0.f}, qb = {0.f, 0.f, 0.f, 0.f};
    if (e < E) {
      qa = *reinterpret_cast<const float4*>(ef + (size_t)e * 8);
      qb = *reinterpret_cast<const float4*>(ef + (size_t)e * 8 + 4);
    }
    const float x[8] = {qa.x, qa.y, qa.z, qa.w, qb.x, qb.y, qb.z, qb.w};
    {
      bf16x8 p0, p1;
#pragma unroll
      for (int j = 0; j < 16; ++j) {
        int col = g * 16 + j;
        float a = 0.f;
#pragma unroll
        for (int k = 0; k < 8; ++k) a += x[k] * sW1[k * 64 + col];
        a *= kINV_L1;
        short hv = f2bf(a / (1.f + __expf(-a)));
        if (j < 8) p0[j] = hv; else p1[j - 8] = hv;
      }
      *reinterpret_cast<bf16x8*>(&h1row[g * 16])     = p0;
      *reinterpret_cast<bf16x8*>(&h1row[g * 16 + 8]) = p1;
    }
    WAVE_LDS_SYNC();

    // layer 2 (MFMA, swapped): A = W2T rows, B = h1 (n-col = edge li)
    {
      bf16x8 b0 = *reinterpret_cast<const bf16x8*>(&h1row[g * 8]);
      bf16x8 b1 = *reinterpret_cast<const bf16x8*>(&h1row[32 + g * 8]);
#pragma unroll
      for (int ct = 0; ct < 4; ++ct) {
        const short* wrow = &sW2T[(ct * 16 + li) * 72];
        bf16x8 a0 = *reinterpret_cast<const bf16x8*>(&wrow[g * 8]);
        bf16x8 a1 = *reinterpret_cast<const bf16x8*>(&wrow[32 + g * 8]);
        f32x4 acc = {0.f, 0.f, 0.f, 0.f};
        acc = __builtin_amdgcn_mfma_f32_16x16x32_bf16(a0, b0, acc, 0, 0, 0);
        acc = __builtin_amdgcn_mfma_f32_16x16x32_bf16(a1, b1, acc, 0, 0, 0);
        bf16x4 hq;
#pragma unroll
        for (int r = 0; r < 4; ++r) {
          float a = acc[r] * kINV_L2;
          hq[r] = f2bf(a / (1.f + __expf(-a)));
        }
        *reinterpret_cast<bf16x4*>(&h2row[ct * 16 + g * 4]) = hq;
      }
    }
    WAVE_LDS_SYNC();

    // layer 3 (MFMA, swapped): paired halves -> packed dwords -> 16B stores
    {
      bf16x8 b0 = *reinterpret_cast<const bf16x8*>(&h2row[g * 8]);
      bf16x8 b1 = *reinterpret_cast<const bf16x8*>(&h2row[32 + g * 8]);
#pragma unroll 4
      for (int rt = 0; rt < 16; ++rt) {
        const int rowA = rt * 16 + li;
        bf16x8 a0 = *reinterpret_cast<const bf16x8*>(&W3T[(size_t)rowA * 64 + g * 8]);
        bf16x8 a1 = *reinterpret_cast<const bf16x8*>(&W3T[(size_t)rowA * 64 + 32 + g * 8]);
        bf16x8 a2 = *reinterpret_cast<const bf16x8*>(&W3T[(size_t)(rowA + 256) * 64 + g * 8]);
        bf16x8 a3 = *reinterpret_cast<const bf16x8*>(&W3T[(size_t)(rowA + 256) * 64 + 32 + g * 8]);
        f32x4 accA = {0.f, 0.f, 0.f, 0.f};
        f32x4 accB = {0.f, 0.f, 0.f, 0.f};
        accA = __builtin_amdgcn_mfma_f32_16x16x32_bf16(a0, b0, accA, 0, 0, 0);
        accA = __builtin_amdgcn_mfma_f32_16x16x32_bf16(a1, b1, accA, 0, 0, 0);
        accB = __builtin_amdgcn_mfma_f32_16x16x32_bf16(a2, b0, accB, 0, 0, 0);
        accB = __builtin_amdgcn_mfma_f32_16x16x32_bf16(a3, b1, accB, 0, 0, 0);
        if (e < E) {
          uint4 d;
          unsigned* dp = &d.x;
#pragma unroll
          for (int r = 0; r < 4; ++r) {
            unsigned lo = (unsigned)(unsigned short)f2bf(accA[r] * kINV_L3);
            unsigned hi = (unsigned)(unsigned short)f2bf(accB[r] * kINV_L3);
            dp[r] = lo | (hi << 16);
          }
          *reinterpret_cast<uint4*>(&tpw2[(size_t)e * 256 + rt * 16 + g * 4]) = d;
        }
      }
    }
    return;
  }
  blk -= MLP_B;

  if (blk < UP_B) {
    // ---------------- UP role: node up-projection (MFMA) -------------------
    short* lsA = (short*)smem;  // [4][16][136]
    const int nb = blk * 16;

    for (int base = t * 8; base < 16 * 512; base += 256 * 8) {
      int n = base >> 9, j0 = base & 511;
      float vals[8];
      if (nb + n < N) {
        float4 q0 = *reinterpret_cast<const float4*>(nf + (size_t)(nb + n) * 512 + j0);
        float4 q1 = *reinterpret_cast<const float4*>(nf + (size_t)(nb + n) * 512 + j0 + 4);
        vals[0] = q0.x; vals[1] = q0.y; vals[2] = q0.z; vals[3] = q0.w;
        vals[4] = q1.x; vals[5] = q1.y; vals[6] = q1.z; vals[7] = q1.w;
      } else {
#pragma unroll
        for (int e = 0; e < 8; ++e) vals[e] = 0.f;
      }
#pragma unroll
      for (int e = 0; e < 8; ++e) {
        int idx = j0 + e;
        if (idx < 128) {
          lsA[(0 * 16 + n) * 136 + idx] = f2bf(vals[e]);
        } else {
          unsigned q = idx - 128;
          unsigned u = q / 3u;
          unsigned i = q - u * 3u;
          lsA[((1 + i) * 16 + n) * 136 + u] = f2bf(vals[e]);
        }
      }
    }
    __syncthreads();

    const int c = t >> 6;
    const int lane = t & 63;
    const int col = lane & 15;
    const int g = lane >> 4;

    const short* WT = c ? W1T : W0T;

    bf16x8 af[4];
#pragma unroll
    for (int kk = 0; kk < 4; ++kk)
      af[kk] = *reinterpret_cast<const bf16x8*>(&lsA[(c * 16 + col) * 136 + kk * 32 + g * 8]);

#pragma unroll
    for (int nt = 0; nt < 8; ++nt) {
      f32x4 acc = {0.f, 0.f, 0.f, 0.f};
#pragma unroll
      for (int kk = 0; kk < 4; ++kk) {
        bf16x8 bf = *reinterpret_cast<const bf16x8*>(&WT[(size_t)(nt * 16 + col) * 128 + kk * 32 + g * 8]);
        acc = __builtin_amdgcn_mfma_f32_16x16x32_bf16(af[kk], bf, acc, 0, 0, 0);
      }
#pragma unroll
      for (int r = 0; r < 4; ++r) {
        int nd = nb + g * 4 + r;
        if (nd < N) {
          float val = acc[r] * kINV_UP;
          if (c == 0) s_up[(size_t)nd * 128 + nt * 16 + col] = val;
          else        v_up[(size_t)nd * 384 + (c - 1) * 128 + nt * 16 + col] = val;
        }
      }
    }
    return;
  }
  blk -= UP_B;

  // ---------------- SCATTER role -------------------------------------------
  int e = blk * 256 + t;
  if (e < E) {
    int r = eidx[E + e];
    int p = atomicAdd(&cursor[r], 1);
    sorted[p] = e;
  }
}

// ---------------------------------------------------------------------------
// K4: barrier-free, divergence-free gather (tpw2 indexed by edge id).
// One wave per node; blocks [0,SB) s-side, [SB,2SB) v-side.
// ---------------------------------------------------------------------------
__global__ __launch_bounds__(256) void k_gather(
    const int* __restrict__ sorted, const int* __restrict__ offs,
    const unsigned* __restrict__ tpw2, const float* __restrict__ eattr,
    const int* __restrict__ eidx,
    const float* __restrict__ s_up, const float* __restrict__ v_up,
    float* __restrict__ Ms, float* __restrict__ Mv, int N, int SB) {
  const int t = threadIdx.x;
  const int vside = blockIdx.x >= SB;
  const int nb = (vside ? blockIdx.x - SB : blockIdx.x) * 4;
  const int n = nb + (t >> 6);
  if (n >= N) return;
  const int l = t & 63;
  const int u0 = l * 2;

  float aMs0 = 0.f, aMs1 = 0.f;
  float aV[3][2] = {};

  const int e0 = offs[n], e1 = offs[n + 1];

  if (!vside) {
    for (int p = e0; p < e1; ++p) {
      int eid = sorted[p];
      int snd = eidx[eid];
      float4 ea = *reinterpret_cast<const float4*>(eattr + (size_t)eid * 4);
      uint2 q = *reinterpret_cast<const uint2*>(tpw2 + (size_t)eid * 256 + u0);
      float2 xs = *reinterpret_cast<const float2*>(s_up + (size_t)snd * 128 + u0);
      float tA0 = __uint_as_float(q.x << 16);
      float tB0 = __uint_as_float(q.x & 0xFFFF0000u);
      float tA1 = __uint_as_float(q.y << 16);
      float tB1 = __uint_as_float(q.y & 0xFFFF0000u);
      float xe0 = xs.x * ea.x, xe1 = xs.y * ea.x;
      aMs0 += tA0 * xe0;
      aMs1 += tA1 * xe1;
      float wc0 = tB0 * xs.x, wc1 = tB1 * xs.y;
      aV[0][0] += wc0 * ea.y; aV[0][1] += wc1 * ea.y;
      aV[1][0] += wc0 * ea.z; aV[1][1] += wc1 * ea.z;
      aV[2][0] += wc0 * ea.w; aV[2][1] += wc1 * ea.w;
    }
    *reinterpret_cast<float2*>(Ms + (size_t)n * 256 + u0) = make_float2(aMs0, aMs1);
#pragma unroll
    for (int i = 0; i < 3; ++i)
      *reinterpret_cast<float2*>(Mv + (size_t)n * 768 + i * 256 + u0) =
          make_float2(aV[i][0], aV[i][1]);
  } else {
    for (int p = e0; p < e1; ++p) {
      int eid = sorted[p];
      int snd = eidx[eid];
      float4 ea = *reinterpret_cast<const float4*>(eattr + (size_t)eid * 4);
      uint2 q = *reinterpret_cast<const uint2*>(tpw2 + (size_t)eid * 256 + 128 + u0);
      const float* xv = v_up + (size_t)snd * 384 + u0;
      float2 x0 = *reinterpret_cast<const float2*>(xv);
      float2 x1 = *reinterpret_cast<const float2*>(xv + 128);
      float2 x2 = *reinterpret_cast<const float2*>(xv + 256);
      float tA0 = __uint_as_float(q.x << 16);
      float tB0 = __uint_as_float(q.x & 0xFFFF0000u);
      float tA1 = __uint_as_float(q.y << 16);
      float tB1 = __uint_as_float(q.y & 0xFFFF0000u);
      float dot0 = x0.x * ea.y + x1.x * ea.z + x2.x * ea.w;
      float dot1 = x0.y * ea.y + x1.y * ea.z + x2.y * ea.w;
      aMs0 += tA0 * dot0 * kINV_SQ3;
      aMs1 += tA1 * dot1 * kINV_SQ3;
      float wd0 = tB0 * ea.x, wd1 = tB1 * ea.x;
      aV[0][0] += wd0 * x0.x; aV[0][1] += wd1 * x0.y;
      aV[1][0] += wd0 * x1.x; aV[1][1] += wd1 * x1.y;
      aV[2][0] += wd0 * x2.x; aV[2][1] += wd1 * x2.y;
    }
    *reinterpret_cast<float2*>(Ms + (size_t)n * 256 + 128 + u0) = make_float2(aMs0, aMs1);
#pragma unroll
    for (int i = 0; i < 3; ++i)
      *reinterpret_cast<float2*>(Mv + (size_t)n * 768 + i * 256 + 128 + u0) =
          make_float2(aV[i][0], aV[i][1]);
  }
}

// ---------------------------------------------------------------------------
// K5 (MFMA): fused lin + skip + combine (unchanged — passed).
// ---------------------------------------------------------------------------
__global__ __launch_bounds__(256) void k_linskip(
    const float* __restrict__ Ms, const float* __restrict__ Mv,
    const short* __restrict__ Wl0T, const short* __restrict__ Wl1T,
    const short* __restrict__ Wsk0T, const short* __restrict__ Wsk1T,
    const float* __restrict__ attrs, const float* __restrict__ upd,
    float* __restrict__ out, int N) {
  __shared__ __align__(16) short lsA[4][16][264];
  __shared__ __align__(16) short lsS[4][16][136];
  __shared__ float sat[16][4];
  const int nb = blockIdx.x * 16;
  const int t = threadIdx.x;

  for (int base = t * 4; base < 16 * 1024; base += 1024) {
    int n = base >> 10, j = base & 1023;
    int comp = j >> 8, u = j & 255;
    float4 q = {0.f, 0.f, 0.f, 0.f};
    if (nb + n < N) {
      const float* src = (comp == 0) ? (Ms + (size_t)(nb + n) * 256 + u)
                                     : (Mv + (size_t)(nb + n) * 768 + (size_t)(comp - 1) * 256 + u);
      q = *reinterpret_cast<const float4*>(src);
    }
    lsA[comp][n][u + 0] = f2bf(q.x);
    lsA[comp][n][u + 1] = f2bf(q.y);
    lsA[comp][n][u + 2] = f2bf(q.z);
    lsA[comp][n][u + 3] = f2bf(q.w);
  }
  if (t < 64) {
    int n = t >> 2, v = t & 3;
    sat[n][v] = (nb + n < N) ? attrs[(size_t)(nb + n) * 4 + v] : 0.f;
  }
  __syncthreads();

  const int c = t >> 6;
  const int lane = t & 63;
  const int col = lane & 15;
  const int g = lane >> 4;

  const short* WLT = c ? Wl1T : Wl0T;
  const short* WST = c ? Wsk1T : Wsk0T;

  bf16x8 af1[8];
#pragma unroll
  for (int kk = 0; kk < 8; ++kk)
    af1[kk] = *reinterpret_cast<const bf16x8*>(&lsA[c][col][kk * 32 + g * 8]);

  f32x4 Sreg[8];
#pragma unroll
  for (int nt = 0; nt < 8; ++nt) {
    f32x4 acc = {0.f, 0.f, 0.f, 0.f};
#pragma unroll
    for (int kk = 0; kk < 8; ++kk) {
      bf16x8 bf = *reinterpret_cast<const bf16x8*>(&WLT[(size_t)(nt * 16 + col) * 256 + kk * 32 + g * 8]);
      acc = __builtin_amdgcn_mfma_f32_16x16x32_bf16(af1[kk], bf, acc, 0, 0, 0);
    }
#pragma unroll
    for (int r = 0; r < 4; ++r) acc[r] *= kINV_LIN;
    Sreg[nt] = acc;
#pragma unroll
    for (int r = 0; r < 4; ++r)
      lsS[c][g * 4 + r][nt * 16 + col] = f2bf(acc[r]);
  }

  float satr[4][4];
#pragma unroll
  for (int r = 0; r < 4; ++r)
#pragma unroll
    for (int v = 0; v < 4; ++v) satr[r][v] = sat[g * 4 + r][v];

  __syncthreads();

  bf16x8 af2[4];
#pragma unroll
  for (int kk = 0; kk < 4; ++kk)
    af2[kk] = *reinterpret_cast<const bf16x8*>(&lsS[c][col][kk * 32 + g * 8]);

  const float p = upd[0];
  const float cc = 1.f / (1.f + __expf(-p));
  const float c_old = rsqrtf(cc * cc + 1.f);
  const float c_new = cc * c_old;

#pragma unroll
  for (int nt = 0; nt < 8; ++nt) {
    float fin[4] = {0.f, 0.f, 0.f, 0.f};
#pragma unroll
    for (int v = 0; v < 4; ++v) {
      f32x4 tmp = {0.f, 0.f, 0.f, 0.f};
#pragma unroll
      for (int kk = 0; kk < 4; ++kk) {
        bf16x8 bf = *reinterpret_cast<const bf16x8*>(&WST[(size_t)(nt * 16 + col) * 512 + v * 128 + kk * 32 + g * 8]);
        tmp = __builtin_amdgcn_mfma_f32_16x16x32_bf16(af2[kk], bf, tmp, 0, 0, 0);
      }
#pragma unroll
      for (int r = 0; r < 4; ++r) fin[r] += satr[r][v] * tmp[r];
    }
#pragma unroll
    for (int r = 0; r < 4; ++r) {
      int nd = nb + g * 4 + r;
      if (nd < N) {
        float val = c_old * Sreg[nt][r] + c_new * fin[r] * kINV_SK;
        out[((size_t)nd * 128 + nt * 16 + col) * 4 + c] = val;
      }
    }
  }
}

extern "C" void kernel_launch(void* const* d_in, const int* in_sizes, int n_in,
                              void* d_out, int out_size, void* d_ws, size_t ws_size,
                              hipStream_t stream) {
  const float* node_attrs = (const float*)d_in[0];
  const float* node_feats = (const float*)d_in[1];
  const float* edge_attrs = (const float*)d_in[2];
  const float* edge_feats = (const float*)d_in[3];
  const int*   edge_index = (const int*)d_in[4];
  const float* W_up0  = (const float*)d_in[5];
  const float* W_up1  = (const float*)d_in[6];
  const float* W_mlp1 = (const float*)d_in[7];
  const float* W_mlp2 = (const float*)d_in[8];
  const float* W_mlp3 = (const float*)d_in[9];
  const float* W_lin0 = (const float*)d_in[10];
  const float* W_lin1 = (const float*)d_in[11];
  const float* W_skip0 = (const float*)d_in[12];
  const float* W_skip1 = (const float*)d_in[13];
  const float* upd = (const float*)d_in[14];
  float* out = (float*)d_out;

  const int N = in_sizes[0] / 4;
  const int E = in_sizes[4] / 2;

  float* ws = (float*)d_ws;
  float* s_up = ws;                          // N*128
  float* v_up = s_up + (size_t)N * 128;      // N*384  [n][i][u]
  float* Ms   = v_up + (size_t)N * 384;      // N*256
  float* Mv   = Ms + (size_t)N * 256;        // N*768  [n][i][u]
  int* cnt    = (int*)(Mv + (size_t)N * 768); // N
  int* offs   = cnt + N;                      // N+1
  int* cursor = offs + N + 1;                 // N
  int* sorted = cursor + N;                   // E

  short* wbase = (short*)((((uintptr_t)(sorted + E)) + 15) & ~(uintptr_t)15);
  short* W0T   = wbase;            // 128*128
  short* W1T   = W0T + 16384;      // 128*128
  short* Wl0T  = W1T + 16384;      // 128*256
  short* Wl1T  = Wl0T + 32768;     // 128*256
  short* Wsk0T = Wl1T + 32768;     // 128*512
  short* Wsk1T = Wsk0T + 65536;    // 128*512
  short* W2T   = Wsk1T + 65536;    // 64*64
  short* W3T   = W2T + 4096;       // 512*64
  unsigned* tpw2 = (unsigned*)(W3T + 32768); // E*256 dwords

  const int CVT_B = (266240 + 255) / 256;      // 1040
  const int CNT_B = (E + 255) / 256;
  const int MLP_B = (E + 63) / 64;
  const int UP_B  = (N + 15) / 16;
  const int SC_B  = (E + 255) / 256;
  const int SB    = (N + 3) / 4;

  hipMemsetAsync(cnt, 0, (size_t)N * sizeof(int), stream);

  k_cvtcnt<<<CVT_B + CNT_B, 256, 0, stream>>>(
      W_up0, W_up1, W_lin0, W_lin1, W_skip0, W_skip1, W_mlp2, W_mlp3,
      W0T, W1T, Wl0T, Wl1T, Wsk0T, Wsk1T, W2T, W3T,
      edge_index, cnt, E, CVT_B);
  k_scan<<<1, 1024, 0, stream>>>(cnt, offs, cursor, N);
  k_fused3<<<MLP_B + UP_B + SC_B, 256, 0, stream>>>(
      edge_index, cursor, sorted,
      node_feats, W0T, W1T, s_up, v_up,
      edge_feats, W_mlp1, W2T, W3T, tpw2, N, E, MLP_B, UP_B);
  k_gather<<<2 * SB, 256, 0, stream>>>(sorted, offs, tpw2, edge_attrs, edge_index,
                                       s_up, v_up, Ms, Mv, N, SB);
  k_linskip<<<(N + 15) / 16, 256, 0, stream>>>(Ms, Mv, Wl0T, Wl1T, Wsk0T, Wsk1T,
                                               node_attrs, upd, out, N);
}

// Round 8
// 282.240 us; speedup vs baseline: 31.9057x; 1.1225x over previous
//
#include <hip/hip_runtime.h>

#define MUL 128

typedef __attribute__((ext_vector_type(8))) short bf16x8;
typedef __attribute__((ext_vector_type(4))) short bf16x4;
typedef __attribute__((ext_vector_type(4))) float f32x4;

__device__ __constant__ float kINV_UP   = 0.08838834764831845f;  // 1/sqrt(128)
__device__ __constant__ float kINV_L1   = 0.35355339059327373f;  // 1/sqrt(8)
__device__ __constant__ float kINV_L2   = 0.125f;                // 1/sqrt(64)
__device__ __constant__ float kINV_L3   = 0.125f;
__device__ __constant__ float kINV_LIN  = 0.00390625f;           // 1/(sqrt(256)*16)
__device__ __constant__ float kINV_SK   = 0.044194173824159216f; // 1/sqrt(512)
__device__ __constant__ float kINV_SQ3  = 0.5773502691896258f;   // 1/sqrt(3)

// intra-wave LDS ordering: drain ds ops; memory clobber keeps ds_reads below.
#define WAVE_LDS_SYNC() asm volatile("s_waitcnt lgkmcnt(0)" ::: "memory")

static __device__ __forceinline__ short f2bf(float f) {
  unsigned u = __float_as_uint(f);
  unsigned r = (u + 0x7FFFu + ((u >> 16) & 1u)) >> 16;  // RNE
  return (short)r;
}

// ---------------------------------------------------------------------------
// K1 (fused): weight conversion (blocks [0,CVT_B)) | receiver count (rest).
// ---------------------------------------------------------------------------
__global__ __launch_bounds__(256) void k_cvtcnt(
    const float* __restrict__ W_up0, const float* __restrict__ W_up1,
    const float* __restrict__ W_lin0, const float* __restrict__ W_lin1,
    const float* __restrict__ W_sk0, const float* __restrict__ W_sk1,
    const float* __restrict__ W_mlp2, const float* __restrict__ W_mlp3,
    short* __restrict__ W0T, short* __restrict__ W1T,
    short* __restrict__ Wl0T, short* __restrict__ Wl1T,
    short* __restrict__ Wsk0T, short* __restrict__ Wsk1T,
    short* __restrict__ W2T, short* __restrict__ W3T,
    const int* __restrict__ eidx, int* __restrict__ cnt, int E, int CVT_B) {
  int blk = blockIdx.x;
  if (blk >= CVT_B) {
    int e = (blk - CVT_B) * 256 + threadIdx.x;
    if (e < E) atomicAdd(&cnt[eidx[E + e]], 1);
    return;
  }
  int id = blk * 256 + threadIdx.x;
  if (id < 16384) {
    int w = id >> 7, u = id & 127;
    W0T[id] = f2bf(W_up0[u * 128 + w]);
    return;
  }
  id -= 16384;
  if (id < 16384) {
    int w = id >> 7, u = id & 127;
    W1T[id] = f2bf(W_up1[u * 128 + w]);
    return;
  }
  id -= 16384;
  if (id < 32768) {
    int w = id >> 8, u = id & 255;
    Wl0T[id] = f2bf(W_lin0[u * 128 + w]);
    return;
  }
  id -= 32768;
  if (id < 32768) {
    int w = id >> 8, u = id & 255;
    Wl1T[id] = f2bf(W_lin1[u * 128 + w]);
    return;
  }
  id -= 32768;
  if (id < 65536) {
    int w = id >> 9, k = id & 511;
    int v = k >> 7, u = k & 127;
    Wsk0T[id] = f2bf(W_sk0[(u * 4 + v) * 128 + w]);
    return;
  }
  id -= 65536;
  if (id < 65536) {
    int w = id >> 9, k = id & 511;
    int v = k >> 7, u = k & 127;
    Wsk1T[id] = f2bf(W_sk1[(u * 4 + v) * 128 + w]);
    return;
  }
  id -= 65536;
  if (id < 4096) {
    int c = id >> 6, k = id & 63;
    W2T[id] = f2bf(W_mlp2[k * 64 + c]);
    return;
  }
  id -= 4096;
  if (id < 32768) {
    int c = id >> 6, k = id & 63;
    W3T[id] = f2bf(W_mlp3[k * 512 + c]);
  }
}

// ---------------------------------------------------------------------------
// K2: exclusive scan over counts (1 block).
// ---------------------------------------------------------------------------
__global__ __launch_bounds__(1024) void k_scan(const int* __restrict__ cnt,
                                               int* __restrict__ offs,
                                               int* __restrict__ cursor, int N) {
  __shared__ int part[1024];
  const int t = threadIdx.x;
  int CH = (N + 1023) >> 10;
  if (CH > 16) CH = 16;
  const int base = t * CH;
  int loc[16];
  int s = 0;
  for (int i = 0; i < CH; ++i) {
    int idx = base + i;
    loc[i] = (idx < N) ? cnt[idx] : 0;
    s += loc[i];
  }
  part[t] = s;
  __syncthreads();
  for (int off = 1; off < 1024; off <<= 1) {
    int v = part[t];
    int add = (t >= off) ? part[t - off] : 0;
    __syncthreads();
    part[t] = v + add;
    __syncthreads();
  }
  int excl = part[t] - s;
  for (int i = 0; i < CH; ++i) {
    int idx = base + i;
    if (idx < N) { offs[idx] = excl; cursor[idx] = excl; }
    excl += loc[i];
  }
  if (t == 1023) offs[N] = part[1023];
}

// ---------------------------------------------------------------------------
// K3 (fused, block-range dispatch):
//   [0, MLP_B)            : per-edge MLP -> tpw2[eid], 128 edges/block,
//                           32 edges/WAVE (2 MFMA B-sets), sw-pipelined L3
//   [MLP_B, MLP_B+UP_B)   : node up-projection (MFMA)
//   [MLP_B+UP_B, ...)     : scatter (counting-sort placement)
// LDS rows are 64 shorts long -> stride 72 (>=64, 16B-aligned; R6-proven).
// ---------------------------------------------------------------------------
__global__ __launch_bounds__(256) void k_fused3(
    const int* __restrict__ eidx, int* __restrict__ cursor, int* __restrict__ sorted,
    const float* __restrict__ nf, const short* __restrict__ W0T,
    const short* __restrict__ W1T, float* __restrict__ s_up, float* __restrict__ v_up,
    const float* __restrict__ ef, const float* __restrict__ W1f,
    const short* __restrict__ W2T, const short* __restrict__ W3T,
    unsigned* __restrict__ tpw2, int N, int E, int MLP_B, int UP_B) {
  __shared__ __align__(16) char smem[48128];
  const int t = threadIdx.x;
  int blk = blockIdx.x;

  if (blk < MLP_B) {
    // ---------------- MLP role: 128 edges/block, 32 edges per wave ---------
    // sW1 f32[512] @0 (2048B); sW2T short[64][72] @2048 (9216B);
    // sh1 short[128][72] @11264 (18432B); sh2 @29696 (18432B). Total 48128.
    float* sW1  = (float*)smem;
    short* sW2T = (short*)(smem + 2048);
    short* sh1  = (short*)(smem + 11264);
    short* sh2  = (short*)(smem + 29696);

    for (int i = t * 4; i < 512; i += 1024)
      *reinterpret_cast<float4*>(&sW1[i]) = *reinterpret_cast<const float4*>(W1f + i);
    for (int i = t * 8; i < 4096; i += 2048) {
      int r = i >> 6, c = i & 63;
      *reinterpret_cast<bf16x8*>(&sW2T[r * 72 + c]) =
          *reinterpret_cast<const bf16x8*>(&W2T[r * 64 + c]);
    }
    __syncthreads();  // weights visible; no more block barriers

    const int w = t >> 6, l = t & 63, li = l & 15, g = l >> 4;
    const int eb = blk * 128 + w * 32;
    const int es0 = eb + li, es1 = eb + 16 + li;
    short* h1r0 = sh1 + (w * 32 + li) * 72;
    short* h1r1 = sh1 + (w * 32 + 16 + li) * 72;
    short* h2r0 = sh2 + (w * 32 + li) * 72;
    short* h2r1 = sh2 + (w * 32 + 16 + li) * 72;

    // layer 1: lane (li,g) computes cols [g*16, g*16+16) for its 2 edges
    {
#pragma unroll
      for (int s = 0; s < 2; ++s) {
        const int e = s ? es1 : es0;
        short* h1row = s ? h1r1 : h1r0;
        float4 qa = {0.f, 0.f, 0.f, 0.f}, qb = {0.f, 0.f, 0.f, 0.f};
        if (e < E) {
          qa = *reinterpret_cast<const float4*>(ef + (size_t)e * 8);
          qb = *reinterpret_cast<const float4*>(ef + (size_t)e * 8 + 4);
        }
        const float x[8] = {qa.x, qa.y, qa.z, qa.w, qb.x, qb.y, qb.z, qb.w};
        bf16x8 p0, p1;
#pragma unroll
        for (int j = 0; j < 16; ++j) {
          int col = g * 16 + j;
          float a = 0.f;
#pragma unroll
          for (int k = 0; k < 8; ++k) a += x[k] * sW1[k * 64 + col];
          a *= kINV_L1;
          short hv = f2bf(a / (1.f + __expf(-a)));
          if (j < 8) p0[j] = hv; else p1[j - 8] = hv;
        }
        *reinterpret_cast<bf16x8*>(&h1row[g * 16])     = p0;
        *reinterpret_cast<bf16x8*>(&h1row[g * 16 + 8]) = p1;
      }
    }
    WAVE_LDS_SYNC();

    // layer 2 (MFMA, swapped): A = W2T rows, B = h1 (col = edge li), 2 sets
    {
      bf16x8 hb0[2], hb1[2];
      hb0[0] = *reinterpret_cast<const bf16x8*>(&h1r0[g * 8]);
      hb1[0] = *reinterpret_cast<const bf16x8*>(&h1r0[32 + g * 8]);
      hb0[1] = *reinterpret_cast<const bf16x8*>(&h1r1[g * 8]);
      hb1[1] = *reinterpret_cast<const bf16x8*>(&h1r1[32 + g * 8]);
#pragma unroll
      for (int ct = 0; ct < 4; ++ct) {
        const short* wrow = &sW2T[(ct * 16 + li) * 72];
        bf16x8 a0 = *reinterpret_cast<const bf16x8*>(&wrow[g * 8]);
        bf16x8 a1 = *reinterpret_cast<const bf16x8*>(&wrow[32 + g * 8]);
#pragma unroll
        for (int s = 0; s < 2; ++s) {
          f32x4 acc = {0.f, 0.f, 0.f, 0.f};
          acc = __builtin_amdgcn_mfma_f32_16x16x32_bf16(a0, hb0[s], acc, 0, 0, 0);
          acc = __builtin_amdgcn_mfma_f32_16x16x32_bf16(a1, hb1[s], acc, 0, 0, 0);
          bf16x4 hq;
#pragma unroll
          for (int r = 0; r < 4; ++r) {
            float a = acc[r] * kINV_L2;
            hq[r] = f2bf(a / (1.f + __expf(-a)));
          }
          *reinterpret_cast<bf16x4*>(&((s ? h2r1 : h2r0)[ct * 16 + g * 4])) = hq;
        }
      }
    }
    WAVE_LDS_SYNC();

    // layer 3 (MFMA, swapped, 2-deep software pipeline on W3T A-fragments)
    {
      bf16x8 b0[2], b1[2];
      b0[0] = *reinterpret_cast<const bf16x8*>(&h2r0[g * 8]);
      b1[0] = *reinterpret_cast<const bf16x8*>(&h2r0[32 + g * 8]);
      b0[1] = *reinterpret_cast<const bf16x8*>(&h2r1[g * 8]);
      b1[1] = *reinterpret_cast<const bf16x8*>(&h2r1[32 + g * 8]);
      const bool ok0 = es0 < E, ok1 = es1 < E;

      bf16x8 c0, c1, c2, c3;
      {
        const int rowA = li;
        c0 = *reinterpret_cast<const bf16x8*>(&W3T[(size_t)rowA * 64 + g * 8]);
        c1 = *reinterpret_cast<const bf16x8*>(&W3T[(size_t)rowA * 64 + 32 + g * 8]);
        c2 = *reinterpret_cast<const bf16x8*>(&W3T[(size_t)(rowA + 256) * 64 + g * 8]);
        c3 = *reinterpret_cast<const bf16x8*>(&W3T[(size_t)(rowA + 256) * 64 + 32 + g * 8]);
      }
#pragma unroll
      for (int rt = 0; rt < 16; ++rt) {
        bf16x8 n0, n1, n2, n3;
        const bool pf = (rt < 15);
        if (pf) {
          const int rowA = (rt + 1) * 16 + li;
          n0 = *reinterpret_cast<const bf16x8*>(&W3T[(size_t)rowA * 64 + g * 8]);
          n1 = *reinterpret_cast<const bf16x8*>(&W3T[(size_t)rowA * 64 + 32 + g * 8]);
          n2 = *reinterpret_cast<const bf16x8*>(&W3T[(size_t)(rowA + 256) * 64 + g * 8]);
          n3 = *reinterpret_cast<const bf16x8*>(&W3T[(size_t)(rowA + 256) * 64 + 32 + g * 8]);
        }
#pragma unroll
        for (int s = 0; s < 2; ++s) {
          f32x4 accA = {0.f, 0.f, 0.f, 0.f};
          f32x4 accB = {0.f, 0.f, 0.f, 0.f};
          accA = __builtin_amdgcn_mfma_f32_16x16x32_bf16(c0, b0[s], accA, 0, 0, 0);
          accA = __builtin_amdgcn_mfma_f32_16x16x32_bf16(c1, b1[s], accA, 0, 0, 0);
          accB = __builtin_amdgcn_mfma_f32_16x16x32_bf16(c2, b0[s], accB, 0, 0, 0);
          accB = __builtin_amdgcn_mfma_f32_16x16x32_bf16(c3, b1[s], accB, 0, 0, 0);
          if (s ? ok1 : ok0) {
            uint4 d;
            unsigned* dp = &d.x;
#pragma unroll
            for (int r = 0; r < 4; ++r) {
              unsigned lo = (unsigned)(unsigned short)f2bf(accA[r] * kINV_L3);
              unsigned hi = (unsigned)(unsigned short)f2bf(accB[r] * kINV_L3);
              dp[r] = lo | (hi << 16);
            }
            *reinterpret_cast<uint4*>(
                &tpw2[(size_t)(s ? es1 : es0) * 256 + rt * 16 + g * 4]) = d;
          }
        }
        if (pf) { c0 = n0; c1 = n1; c2 = n2; c3 = n3; }
      }
    }
    return;
  }
  blk -= MLP_B;

  if (blk < UP_B) {
    // ---------------- UP role: node up-projection (MFMA) -------------------
    short* lsA = (short*)smem;  // [4][16][136]
    const int nb = blk * 16;

    for (int base = t * 8; base < 16 * 512; base += 256 * 8) {
      int n = base >> 9, j0 = base & 511;
      float vals[8];
      if (nb + n < N) {
        float4 q0 = *reinterpret_cast<const float4*>(nf + (size_t)(nb + n) * 512 + j0);
        float4 q1 = *reinterpret_cast<const float4*>(nf + (size_t)(nb + n) * 512 + j0 + 4);
        vals[0] = q0.x; vals[1] = q0.y; vals[2] = q0.z; vals[3] = q0.w;
        vals[4] = q1.x; vals[5] = q1.y; vals[6] = q1.z; vals[7] = q1.w;
      } else {
#pragma unroll
        for (int e = 0; e < 8; ++e) vals[e] = 0.f;
      }
#pragma unroll
      for (int e = 0; e < 8; ++e) {
        int idx = j0 + e;
        if (idx < 128) {
          lsA[(0 * 16 + n) * 136 + idx] = f2bf(vals[e]);
        } else {
          unsigned q = idx - 128;
          unsigned u = q / 3u;
          unsigned i = q - u * 3u;
          lsA[((1 + i) * 16 + n) * 136 + u] = f2bf(vals[e]);
        }
      }
    }
    __syncthreads();

    const int c = t >> 6;
    const int lane = t & 63;
    const int col = lane & 15;
    const int g = lane >> 4;

    const short* WT = c ? W1T : W0T;

    bf16x8 af[4];
#pragma unroll
    for (int kk = 0; kk < 4; ++kk)
      af[kk] = *reinterpret_cast<const bf16x8*>(&lsA[(c * 16 + col) * 136 + kk * 32 + g * 8]);

#pragma unroll
    for (int nt = 0; nt < 8; ++nt) {
      f32x4 acc = {0.f, 0.f, 0.f, 0.f};
#pragma unroll
      for (int kk = 0; kk < 4; ++kk) {
        bf16x8 bf = *reinterpret_cast<const bf16x8*>(&WT[(size_t)(nt * 16 + col) * 128 + kk * 32 + g * 8]);
        acc = __builtin_amdgcn_mfma_f32_16x16x32_bf16(af[kk], bf, acc, 0, 0, 0);
      }
#pragma unroll
      for (int r = 0; r < 4; ++r) {
        int nd = nb + g * 4 + r;
        if (nd < N) {
          float val = acc[r] * kINV_UP;
          if (c == 0) s_up[(size_t)nd * 128 + nt * 16 + col] = val;
          else        v_up[(size_t)nd * 384 + (c - 1) * 128 + nt * 16 + col] = val;
        }
      }
    }
    return;
  }
  blk -= UP_B;

  // ---------------- SCATTER role -------------------------------------------
  int e = blk * 256 + t;
  if (e < E) {
    int r = eidx[E + e];
    int p = atomicAdd(&cursor[r], 1);
    sorted[p] = e;
  }
}

// ---------------------------------------------------------------------------
// K4: barrier-free, divergence-free gather (tpw2 indexed by edge id).
// One wave per node; blocks [0,SB) s-side, [SB,2SB) v-side.
// ---------------------------------------------------------------------------
__global__ __launch_bounds__(256) void k_gather(
    const int* __restrict__ sorted, const int* __restrict__ offs,
    const unsigned* __restrict__ tpw2, const float* __restrict__ eattr,
    const int* __restrict__ eidx,
    const float* __restrict__ s_up, const float* __restrict__ v_up,
    float* __restrict__ Ms, float* __restrict__ Mv, int N, int SB) {
  const int t = threadIdx.x;
  const int vside = blockIdx.x >= SB;
  const int nb = (vside ? blockIdx.x - SB : blockIdx.x) * 4;
  const int n = nb + (t >> 6);
  if (n >= N) return;
  const int l = t & 63;
  const int u0 = l * 2;

  float aMs0 = 0.f, aMs1 = 0.f;
  float aV[3][2] = {};

  const int e0 = offs[n], e1 = offs[n + 1];

  if (!vside) {
    for (int p = e0; p < e1; ++p) {
      int eid = sorted[p];
      int snd = eidx[eid];
      float4 ea = *reinterpret_cast<const float4*>(eattr + (size_t)eid * 4);
      uint2 q = *reinterpret_cast<const uint2*>(tpw2 + (size_t)eid * 256 + u0);
      float2 xs = *reinterpret_cast<const float2*>(s_up + (size_t)snd * 128 + u0);
      float tA0 = __uint_as_float(q.x << 16);
      float tB0 = __uint_as_float(q.x & 0xFFFF0000u);
      float tA1 = __uint_as_float(q.y << 16);
      float tB1 = __uint_as_float(q.y & 0xFFFF0000u);
      float xe0 = xs.x * ea.x, xe1 = xs.y * ea.x;
      aMs0 += tA0 * xe0;
      aMs1 += tA1 * xe1;
      float wc0 = tB0 * xs.x, wc1 = tB1 * xs.y;
      aV[0][0] += wc0 * ea.y; aV[0][1] += wc1 * ea.y;
      aV[1][0] += wc0 * ea.z; aV[1][1] += wc1 * ea.z;
      aV[2][0] += wc0 * ea.w; aV[2][1] += wc1 * ea.w;
    }
    *reinterpret_cast<float2*>(Ms + (size_t)n * 256 + u0) = make_float2(aMs0, aMs1);
#pragma unroll
    for (int i = 0; i < 3; ++i)
      *reinterpret_cast<float2*>(Mv + (size_t)n * 768 + i * 256 + u0) =
          make_float2(aV[i][0], aV[i][1]);
  } else {
    for (int p = e0; p < e1; ++p) {
      int eid = sorted[p];
      int snd = eidx[eid];
      float4 ea = *reinterpret_cast<const float4*>(eattr + (size_t)eid * 4);
      uint2 q = *reinterpret_cast<const uint2*>(tpw2 + (size_t)eid * 256 + 128 + u0);
      const float* xv = v_up + (size_t)snd * 384 + u0;
      float2 x0 = *reinterpret_cast<const float2*>(xv);
      float2 x1 = *reinterpret_cast<const float2*>(xv + 128);
      float2 x2 = *reinterpret_cast<const float2*>(xv + 256);
      float tA0 = __uint_as_float(q.x << 16);
      float tB0 = __uint_as_float(q.x & 0xFFFF0000u);
      float tA1 = __uint_as_float(q.y << 16);
      float tB1 = __uint_as_float(q.y & 0xFFFF0000u);
      float dot0 = x0.x * ea.y + x1.x * ea.z + x2.x * ea.w;
      float dot1 = x0.y * ea.y + x1.y * ea.z + x2.y * ea.w;
      aMs0 += tA0 * dot0 * kINV_SQ3;
      aMs1 += tA1 * dot1 * kINV_SQ3;
      float wd0 = tB0 * ea.x, wd1 = tB1 * ea.x;
      aV[0][0] += wd0 * x0.x; aV[0][1] += wd1 * x0.y;
      aV[1][0] += wd0 * x1.x; aV[1][1] += wd1 * x1.y;
      aV[2][0] += wd0 * x2.x; aV[2][1] += wd1 * x2.y;
    }
    *reinterpret_cast<float2*>(Ms + (size_t)n * 256 + 128 + u0) = make_float2(aMs0, aMs1);
#pragma unroll
    for (int i = 0; i < 3; ++i)
      *reinterpret_cast<float2*>(Mv + (size_t)n * 768 + i * 256 + 128 + u0) =
          make_float2(aV[i][0], aV[i][1]);
  }
}

// ---------------------------------------------------------------------------
// K5 (MFMA): fused lin + skip + combine (unchanged — passed).
// ---------------------------------------------------------------------------
__global__ __launch_bounds__(256) void k_linskip(
    const float* __restrict__ Ms, const float* __restrict__ Mv,
    const short* __restrict__ Wl0T, const short* __restrict__ Wl1T,
    const short* __restrict__ Wsk0T, const short* __restrict__ Wsk1T,
    const float* __restrict__ attrs, const float* __restrict__ upd,
    float* __restrict__ out, int N) {
  __shared__ __align__(16) short lsA[4][16][264];
  __shared__ __align__(16) short lsS[4][16][136];
  __shared__ float sat[16][4];
  const int nb = blockIdx.x * 16;
  const int t = threadIdx.x;

  for (int base = t * 4; base < 16 * 1024; base += 1024) {
    int n = base >> 10, j = base & 1023;
    int comp = j >> 8, u = j & 255;
    float4 q = {0.f, 0.f, 0.f, 0.f};
    if (nb + n < N) {
      const float* src = (comp == 0) ? (Ms + (size_t)(nb + n) * 256 + u)
                                     : (Mv + (size_t)(nb + n) * 768 + (size_t)(comp - 1) * 256 + u);
      q = *reinterpret_cast<const float4*>(src);
    }
    lsA[comp][n][u + 0] = f2bf(q.x);
    lsA[comp][n][u + 1] = f2bf(q.y);
    lsA[comp][n][u + 2] = f2bf(q.z);
    lsA[comp][n][u + 3] = f2bf(q.w);
  }
  if (t < 64) {
    int n = t >> 2, v = t & 3;
    sat[n][v] = (nb + n < N) ? attrs[(size_t)(nb + n) * 4 + v] : 0.f;
  }
  __syncthreads();

  const int c = t >> 6;
  const int lane = t & 63;
  const int col = lane & 15;
  const int g = lane >> 4;

  const short* WLT = c ? Wl1T : Wl0T;
  const short* WST = c ? Wsk1T : Wsk0T;

  bf16x8 af1[8];
#pragma unroll
  for (int kk = 0; kk < 8; ++kk)
    af1[kk] = *reinterpret_cast<const bf16x8*>(&lsA[c][col][kk * 32 + g * 8]);

  f32x4 Sreg[8];
#pragma unroll
  for (int nt = 0; nt < 8; ++nt) {
    f32x4 acc = {0.f, 0.f, 0.f, 0.f};
#pragma unroll
    for (int kk = 0; kk < 8; ++kk) {
      bf16x8 bf = *reinterpret_cast<const bf16x8*>(&WLT[(size_t)(nt * 16 + col) * 256 + kk * 32 + g * 8]);
      acc = __builtin_amdgcn_mfma_f32_16x16x32_bf16(af1[kk], bf, acc, 0, 0, 0);
    }
#pragma unroll
    for (int r = 0; r < 4; ++r) acc[r] *= kINV_LIN;
    Sreg[nt] = acc;
#pragma unroll
    for (int r = 0; r < 4; ++r)
      lsS[c][g * 4 + r][nt * 16 + col] = f2bf(acc[r]);
  }

  float satr[4][4];
#pragma unroll
  for (int r = 0; r < 4; ++r)
#pragma unroll
    for (int v = 0; v < 4; ++v) satr[r][v] = sat[g * 4 + r][v];

  __syncthreads();

  bf16x8 af2[4];
#pragma unroll
  for (int kk = 0; kk < 4; ++kk)
    af2[kk] = *reinterpret_cast<const bf16x8*>(&lsS[c][col][kk * 32 + g * 8]);

  const float p = upd[0];
  const float cc = 1.f / (1.f + __expf(-p));
  const float c_old = rsqrtf(cc * cc + 1.f);
  const float c_new = cc * c_old;

#pragma unroll
  for (int nt = 0; nt < 8; ++nt) {
    float fin[4] = {0.f, 0.f, 0.f, 0.f};
#pragma unroll
    for (int v = 0; v < 4; ++v) {
      f32x4 tmp = {0.f, 0.f, 0.f, 0.f};
#pragma unroll
      for (int kk = 0; kk < 4; ++kk) {
        bf16x8 bf = *reinterpret_cast<const bf16x8*>(&WST[(size_t)(nt * 16 + col) * 512 + v * 128 + kk * 32 + g * 8]);
        tmp = __builtin_amdgcn_mfma_f32_16x16x32_bf16(af2[kk], bf, tmp, 0, 0, 0);
      }
#pragma unroll
      for (int r = 0; r < 4; ++r) fin[r] += satr[r][v] * tmp[r];
    }
#pragma unroll
    for (int r = 0; r < 4; ++r) {
      int nd = nb + g * 4 + r;
      if (nd < N) {
        float val = c_old * Sreg[nt][r] + c_new * fin[r] * kINV_SK;
        out[((size_t)nd * 128 + nt * 16 + col) * 4 + c] = val;
      }
    }
  }
}

extern "C" void kernel_launch(void* const* d_in, const int* in_sizes, int n_in,
                              void* d_out, int out_size, void* d_ws, size_t ws_size,
                              hipStream_t stream) {
  const float* node_attrs = (const float*)d_in[0];
  const float* node_feats = (const float*)d_in[1];
  const float* edge_attrs = (const float*)d_in[2];
  const float* edge_feats = (const float*)d_in[3];
  const int*   edge_index = (const int*)d_in[4];
  const float* W_up0  = (const float*)d_in[5];
  const float* W_up1  = (const float*)d_in[6];
  const float* W_mlp1 = (const float*)d_in[7];
  const float* W_mlp2 = (const float*)d_in[8];
  const float* W_mlp3 = (const float*)d_in[9];
  const float* W_lin0 = (const float*)d_in[10];
  const float* W_lin1 = (const float*)d_in[11];
  const float* W_skip0 = (const float*)d_in[12];
  const float* W_skip1 = (const float*)d_in[13];
  const float* upd = (const float*)d_in[14];
  float* out = (float*)d_out;

  const int N = in_sizes[0] / 4;
  const int E = in_sizes[4] / 2;

  float* ws = (float*)d_ws;
  float* s_up = ws;                          // N*128
  float* v_up = s_up + (size_t)N * 128;      // N*384  [n][i][u]
  float* Ms   = v_up + (size_t)N * 384;      // N*256
  float* Mv   = Ms + (size_t)N * 256;        // N*768  [n][i][u]
  int* cnt    = (int*)(Mv + (size_t)N * 768); // N
  int* offs   = cnt + N;                      // N+1
  int* cursor = offs + N + 1;                 // N
  int* sorted = cursor + N;                   // E

  short* wbase = (short*)((((uintptr_t)(sorted + E)) + 15) & ~(uintptr_t)15);
  short* W0T   = wbase;            // 128*128
  short* W1T   = W0T + 16384;      // 128*128
  short* Wl0T  = W1T + 16384;      // 128*256
  short* Wl1T  = Wl0T + 32768;     // 128*256
  short* Wsk0T = Wl1T + 32768;     // 128*512
  short* Wsk1T = Wsk0T + 65536;    // 128*512
  short* W2T   = Wsk1T + 65536;    // 64*64
  short* W3T   = W2T + 4096;       // 512*64
  unsigned* tpw2 = (unsigned*)(W3T + 32768); // E*256 dwords

  const int CVT_B = (266240 + 255) / 256;      // 1040
  const int CNT_B = (E + 255) / 256;
  const int MLP_B = (E + 127) / 128;
  const int UP_B  = (N + 15) / 16;
  const int SC_B  = (E + 255) / 256;
  const int SB    = (N + 3) / 4;

  hipMemsetAsync(cnt, 0, (size_t)N * sizeof(int), stream);

  k_cvtcnt<<<CVT_B + CNT_B, 256, 0, stream>>>(
      W_up0, W_up1, W_lin0, W_lin1, W_skip0, W_skip1, W_mlp2, W_mlp3,
      W0T, W1T, Wl0T, Wl1T, Wsk0T, Wsk1T, W2T, W3T,
      edge_index, cnt, E, CVT_B);
  k_scan<<<1, 1024, 0, stream>>>(cnt, offs, cursor, N);
  k_fused3<<<MLP_B + UP_B + SC_B, 256, 0, stream>>>(
      edge_index, cursor, sorted,
      node_feats, W0T, W1T, s_up, v_up,
      edge_feats, W_mlp1, W2T, W3T, tpw2, N, E, MLP_B, UP_B);
  k_gather<<<2 * SB, 256, 0, stream>>>(sorted, offs, tpw2, edge_attrs, edge_index,
                                       s_up, v_up, Ms, Mv, N, SB);
  k_linskip<<<(N + 15) / 16, 256, 0, stream>>>(Ms, Mv, Wl0T, Wl1T, Wsk0T, Wsk1T,
                                               node_attrs, upd, out, N);
}

// Round 9
// 277.354 us; speedup vs baseline: 32.4678x; 1.0176x over previous
//
#include <hip/hip_runtime.h>

#define MUL 128

typedef __attribute__((ext_vector_type(8))) short bf16x8;
typedef __attribute__((ext_vector_type(4))) short bf16x4;
typedef __attribute__((ext_vector_type(4))) float f32x4;

__device__ __constant__ float kINV_UP   = 0.08838834764831845f;  // 1/sqrt(128)
__device__ __constant__ float kINV_L1   = 0.35355339059327373f;  // 1/sqrt(8)
__device__ __constant__ float kINV_L2   = 0.125f;                // 1/sqrt(64)
__device__ __constant__ float kINV_L3   = 0.125f;
__device__ __constant__ float kINV_LIN  = 0.00390625f;           // 1/(sqrt(256)*16)
__device__ __constant__ float kINV_SK   = 0.044194173824159216f; // 1/sqrt(512)
__device__ __constant__ float kINV_SQ3  = 0.5773502691896258f;   // 1/sqrt(3)

// intra-wave LDS ordering: drain ds ops; memory clobber keeps ds_reads below.
#define WAVE_LDS_SYNC() asm volatile("s_waitcnt lgkmcnt(0)" ::: "memory")

static __device__ __forceinline__ short f2bf(float f) {
  unsigned u = __float_as_uint(f);
  unsigned r = (u + 0x7FFFu + ((u >> 16) & 1u)) >> 16;  // RNE
  return (short)r;
}

// ---------------------------------------------------------------------------
// K1 (fused): weight conversion (blocks [0,CVT_B)) | receiver count (rest).
// ---------------------------------------------------------------------------
__global__ __launch_bounds__(256) void k_cvtcnt(
    const float* __restrict__ W_up0, const float* __restrict__ W_up1,
    const float* __restrict__ W_lin0, const float* __restrict__ W_lin1,
    const float* __restrict__ W_sk0, const float* __restrict__ W_sk1,
    const float* __restrict__ W_mlp2, const float* __restrict__ W_mlp3,
    short* __restrict__ W0T, short* __restrict__ W1T,
    short* __restrict__ Wl0T, short* __restrict__ Wl1T,
    short* __restrict__ Wsk0T, short* __restrict__ Wsk1T,
    short* __restrict__ W2T, short* __restrict__ W3T,
    const int* __restrict__ eidx, int* __restrict__ cnt, int E, int CVT_B) {
  int blk = blockIdx.x;
  if (blk >= CVT_B) {
    int e = (blk - CVT_B) * 256 + threadIdx.x;
    if (e < E) atomicAdd(&cnt[eidx[E + e]], 1);
    return;
  }
  int id = blk * 256 + threadIdx.x;
  if (id < 16384) {
    int w = id >> 7, u = id & 127;
    W0T[id] = f2bf(W_up0[u * 128 + w]);
    return;
  }
  id -= 16384;
  if (id < 16384) {
    int w = id >> 7, u = id & 127;
    W1T[id] = f2bf(W_up1[u * 128 + w]);
    return;
  }
  id -= 16384;
  if (id < 32768) {
    int w = id >> 8, u = id & 255;
    Wl0T[id] = f2bf(W_lin0[u * 128 + w]);
    return;
  }
  id -= 32768;
  if (id < 32768) {
    int w = id >> 8, u = id & 255;
    Wl1T[id] = f2bf(W_lin1[u * 128 + w]);
    return;
  }
  id -= 32768;
  if (id < 65536) {
    int w = id >> 9, k = id & 511;
    int v = k >> 7, u = k & 127;
    Wsk0T[id] = f2bf(W_sk0[(u * 4 + v) * 128 + w]);
    return;
  }
  id -= 65536;
  if (id < 65536) {
    int w = id >> 9, k = id & 511;
    int v = k >> 7, u = k & 127;
    Wsk1T[id] = f2bf(W_sk1[(u * 4 + v) * 128 + w]);
    return;
  }
  id -= 65536;
  if (id < 4096) {
    int c = id >> 6, k = id & 63;
    W2T[id] = f2bf(W_mlp2[k * 64 + c]);
    return;
  }
  id -= 4096;
  if (id < 32768) {
    int c = id >> 6, k = id & 63;
    W3T[id] = f2bf(W_mlp3[k * 512 + c]);
  }
}

// ---------------------------------------------------------------------------
// K2: exclusive scan over counts (1 block).
// ---------------------------------------------------------------------------
__global__ __launch_bounds__(1024) void k_scan(const int* __restrict__ cnt,
                                               int* __restrict__ offs,
                                               int* __restrict__ cursor, int N) {
  __shared__ int part[1024];
  const int t = threadIdx.x;
  int CH = (N + 1023) >> 10;
  if (CH > 16) CH = 16;
  const int base = t * CH;
  int loc[16];
  int s = 0;
  for (int i = 0; i < CH; ++i) {
    int idx = base + i;
    loc[i] = (idx < N) ? cnt[idx] : 0;
    s += loc[i];
  }
  part[t] = s;
  __syncthreads();
  for (int off = 1; off < 1024; off <<= 1) {
    int v = part[t];
    int add = (t >= off) ? part[t - off] : 0;
    __syncthreads();
    part[t] = v + add;
    __syncthreads();
  }
  int excl = part[t] - s;
  for (int i = 0; i < CH; ++i) {
    int idx = base + i;
    if (idx < N) { offs[idx] = excl; cursor[idx] = excl; }
    excl += loc[i];
  }
  if (t == 1023) offs[N] = part[1023];
}

// ---------------------------------------------------------------------------
// K3 (fused, block-range dispatch):
//   [0, MLP_B)            : per-edge MLP -> tpw2[eid], 128 edges/block,
//                           32 edges/WAVE (2 MFMA B-sets), sw-pipelined L3
//   [MLP_B, MLP_B+UP_B)   : node up-projection (MFMA)
//   [MLP_B+UP_B, ...)     : scatter -> recs[p] = {eid, sender}
// ---------------------------------------------------------------------------
__global__ __launch_bounds__(256) void k_fused3(
    const int* __restrict__ eidx, int* __restrict__ cursor, uint2* __restrict__ recs,
    const float* __restrict__ nf, const short* __restrict__ W0T,
    const short* __restrict__ W1T, float* __restrict__ s_up, float* __restrict__ v_up,
    const float* __restrict__ ef, const float* __restrict__ W1f,
    const short* __restrict__ W2T, const short* __restrict__ W3T,
    unsigned* __restrict__ tpw2, int N, int E, int MLP_B, int UP_B) {
  __shared__ __align__(16) char smem[48128];
  const int t = threadIdx.x;
  int blk = blockIdx.x;

  if (blk < MLP_B) {
    // ---------------- MLP role: 128 edges/block, 32 edges per wave ---------
    float* sW1  = (float*)smem;
    short* sW2T = (short*)(smem + 2048);
    short* sh1  = (short*)(smem + 11264);
    short* sh2  = (short*)(smem + 29696);

    for (int i = t * 4; i < 512; i += 1024)
      *reinterpret_cast<float4*>(&sW1[i]) = *reinterpret_cast<const float4*>(W1f + i);
    for (int i = t * 8; i < 4096; i += 2048) {
      int r = i >> 6, c = i & 63;
      *reinterpret_cast<bf16x8*>(&sW2T[r * 72 + c]) =
          *reinterpret_cast<const bf16x8*>(&W2T[r * 64 + c]);
    }
    __syncthreads();  // weights visible; no more block barriers

    const int w = t >> 6, l = t & 63, li = l & 15, g = l >> 4;
    const int eb = blk * 128 + w * 32;
    const int es0 = eb + li, es1 = eb + 16 + li;
    short* h1r0 = sh1 + (w * 32 + li) * 72;
    short* h1r1 = sh1 + (w * 32 + 16 + li) * 72;
    short* h2r0 = sh2 + (w * 32 + li) * 72;
    short* h2r1 = sh2 + (w * 32 + 16 + li) * 72;

    // layer 1
    {
#pragma unroll
      for (int s = 0; s < 2; ++s) {
        const int e = s ? es1 : es0;
        short* h1row = s ? h1r1 : h1r0;
        float4 qa = {0.f, 0.f, 0.f, 0.f}, qb = {0.f, 0.f, 0.f, 0.f};
        if (e < E) {
          qa = *reinterpret_cast<const float4*>(ef + (size_t)e * 8);
          qb = *reinterpret_cast<const float4*>(ef + (size_t)e * 8 + 4);
        }
        const float x[8] = {qa.x, qa.y, qa.z, qa.w, qb.x, qb.y, qb.z, qb.w};
        bf16x8 p0, p1;
#pragma unroll
        for (int j = 0; j < 16; ++j) {
          int col = g * 16 + j;
          float a = 0.f;
#pragma unroll
          for (int k = 0; k < 8; ++k) a += x[k] * sW1[k * 64 + col];
          a *= kINV_L1;
          short hv = f2bf(a / (1.f + __expf(-a)));
          if (j < 8) p0[j] = hv; else p1[j - 8] = hv;
        }
        *reinterpret_cast<bf16x8*>(&h1row[g * 16])     = p0;
        *reinterpret_cast<bf16x8*>(&h1row[g * 16 + 8]) = p1;
      }
    }
    WAVE_LDS_SYNC();

    // layer 2 (MFMA, swapped)
    {
      bf16x8 hb0[2], hb1[2];
      hb0[0] = *reinterpret_cast<const bf16x8*>(&h1r0[g * 8]);
      hb1[0] = *reinterpret_cast<const bf16x8*>(&h1r0[32 + g * 8]);
      hb0[1] = *reinterpret_cast<const bf16x8*>(&h1r1[g * 8]);
      hb1[1] = *reinterpret_cast<const bf16x8*>(&h1r1[32 + g * 8]);
#pragma unroll
      for (int ct = 0; ct < 4; ++ct) {
        const short* wrow = &sW2T[(ct * 16 + li) * 72];
        bf16x8 a0 = *reinterpret_cast<const bf16x8*>(&wrow[g * 8]);
        bf16x8 a1 = *reinterpret_cast<const bf16x8*>(&wrow[32 + g * 8]);
#pragma unroll
        for (int s = 0; s < 2; ++s) {
          f32x4 acc = {0.f, 0.f, 0.f, 0.f};
          acc = __builtin_amdgcn_mfma_f32_16x16x32_bf16(a0, hb0[s], acc, 0, 0, 0);
          acc = __builtin_amdgcn_mfma_f32_16x16x32_bf16(a1, hb1[s], acc, 0, 0, 0);
          bf16x4 hq;
#pragma unroll
          for (int r = 0; r < 4; ++r) {
            float a = acc[r] * kINV_L2;
            hq[r] = f2bf(a / (1.f + __expf(-a)));
          }
          *reinterpret_cast<bf16x4*>(&((s ? h2r1 : h2r0)[ct * 16 + g * 4])) = hq;
        }
      }
    }
    WAVE_LDS_SYNC();

    // layer 3 (MFMA, swapped, 2-deep software pipeline on W3T A-fragments)
    {
      bf16x8 b0[2], b1[2];
      b0[0] = *reinterpret_cast<const bf16x8*>(&h2r0[g * 8]);
      b1[0] = *reinterpret_cast<const bf16x8*>(&h2r0[32 + g * 8]);
      b0[1] = *reinterpret_cast<const bf16x8*>(&h2r1[g * 8]);
      b1[1] = *reinterpret_cast<const bf16x8*>(&h2r1[32 + g * 8]);
      const bool ok0 = es0 < E, ok1 = es1 < E;

      bf16x8 c0, c1, c2, c3;
      {
        const int rowA = li;
        c0 = *reinterpret_cast<const bf16x8*>(&W3T[(size_t)rowA * 64 + g * 8]);
        c1 = *reinterpret_cast<const bf16x8*>(&W3T[(size_t)rowA * 64 + 32 + g * 8]);
        c2 = *reinterpret_cast<const bf16x8*>(&W3T[(size_t)(rowA + 256) * 64 + g * 8]);
        c3 = *reinterpret_cast<const bf16x8*>(&W3T[(size_t)(rowA + 256) * 64 + 32 + g * 8]);
      }
#pragma unroll
      for (int rt = 0; rt < 16; ++rt) {
        bf16x8 n0, n1, n2, n3;
        const bool pf = (rt < 15);
        if (pf) {
          const int rowA = (rt + 1) * 16 + li;
          n0 = *reinterpret_cast<const bf16x8*>(&W3T[(size_t)rowA * 64 + g * 8]);
          n1 = *reinterpret_cast<const bf16x8*>(&W3T[(size_t)rowA * 64 + 32 + g * 8]);
          n2 = *reinterpret_cast<const bf16x8*>(&W3T[(size_t)(rowA + 256) * 64 + g * 8]);
          n3 = *reinterpret_cast<const bf16x8*>(&W3T[(size_t)(rowA + 256) * 64 + 32 + g * 8]);
        }
#pragma unroll
        for (int s = 0; s < 2; ++s) {
          f32x4 accA = {0.f, 0.f, 0.f, 0.f};
          f32x4 accB = {0.f, 0.f, 0.f, 0.f};
          accA = __builtin_amdgcn_mfma_f32_16x16x32_bf16(c0, b0[s], accA, 0, 0, 0);
          accA = __builtin_amdgcn_mfma_f32_16x16x32_bf16(c1, b1[s], accA, 0, 0, 0);
          accB = __builtin_amdgcn_mfma_f32_16x16x32_bf16(c2, b0[s], accB, 0, 0, 0);
          accB = __builtin_amdgcn_mfma_f32_16x16x32_bf16(c3, b1[s], accB, 0, 0, 0);
          if (s ? ok1 : ok0) {
            uint4 d;
            unsigned* dp = &d.x;
#pragma unroll
            for (int r = 0; r < 4; ++r) {
              unsigned lo = (unsigned)(unsigned short)f2bf(accA[r] * kINV_L3);
              unsigned hi = (unsigned)(unsigned short)f2bf(accB[r] * kINV_L3);
              dp[r] = lo | (hi << 16);
            }
            *reinterpret_cast<uint4*>(
                &tpw2[(size_t)(s ? es1 : es0) * 256 + rt * 16 + g * 4]) = d;
          }
        }
        if (pf) { c0 = n0; c1 = n1; c2 = n2; c3 = n3; }
      }
    }
    return;
  }
  blk -= MLP_B;

  if (blk < UP_B) {
    // ---------------- UP role: node up-projection (MFMA) -------------------
    short* lsA = (short*)smem;  // [4][16][136]
    const int nb = blk * 16;

    for (int base = t * 8; base < 16 * 512; base += 256 * 8) {
      int n = base >> 9, j0 = base & 511;
      float vals[8];
      if (nb + n < N) {
        float4 q0 = *reinterpret_cast<const float4*>(nf + (size_t)(nb + n) * 512 + j0);
        float4 q1 = *reinterpret_cast<const float4*>(nf + (size_t)(nb + n) * 512 + j0 + 4);
        vals[0] = q0.x; vals[1] = q0.y; vals[2] = q0.z; vals[3] = q0.w;
        vals[4] = q1.x; vals[5] = q1.y; vals[6] = q1.z; vals[7] = q1.w;
      } else {
#pragma unroll
        for (int e = 0; e < 8; ++e) vals[e] = 0.f;
      }
#pragma unroll
      for (int e = 0; e < 8; ++e) {
        int idx = j0 + e;
        if (idx < 128) {
          lsA[(0 * 16 + n) * 136 + idx] = f2bf(vals[e]);
        } else {
          unsigned q = idx - 128;
          unsigned u = q / 3u;
          unsigned i = q - u * 3u;
          lsA[((1 + i) * 16 + n) * 136 + u] = f2bf(vals[e]);
        }
      }
    }
    __syncthreads();

    const int c = t >> 6;
    const int lane = t & 63;
    const int col = lane & 15;
    const int g = lane >> 4;

    const short* WT = c ? W1T : W0T;

    bf16x8 af[4];
#pragma unroll
    for (int kk = 0; kk < 4; ++kk)
      af[kk] = *reinterpret_cast<const bf16x8*>(&lsA[(c * 16 + col) * 136 + kk * 32 + g * 8]);

#pragma unroll
    for (int nt = 0; nt < 8; ++nt) {
      f32x4 acc = {0.f, 0.f, 0.f, 0.f};
#pragma unroll
      for (int kk = 0; kk < 4; ++kk) {
        bf16x8 bf = *reinterpret_cast<const bf16x8*>(&WT[(size_t)(nt * 16 + col) * 128 + kk * 32 + g * 8]);
        acc = __builtin_amdgcn_mfma_f32_16x16x32_bf16(af[kk], bf, acc, 0, 0, 0);
      }
#pragma unroll
      for (int r = 0; r < 4; ++r) {
        int nd = nb + g * 4 + r;
        if (nd < N) {
          float val = acc[r] * kINV_UP;
          if (c == 0) s_up[(size_t)nd * 128 + nt * 16 + col] = val;
          else        v_up[(size_t)nd * 384 + (c - 1) * 128 + nt * 16 + col] = val;
        }
      }
    }
    return;
  }
  blk -= UP_B;

  // ---------------- SCATTER role: recs[p] = {eid, sender} -------------------
  int e = blk * 256 + t;
  if (e < E) {
    int r = eidx[E + e];
    int snd = eidx[e];
    int p = atomicAdd(&cursor[r], 1);
    recs[p] = make_uint2((unsigned)e, (unsigned)snd);
  }
}

// ---------------------------------------------------------------------------
// K4: gather, one WAVE per node doing BOTH sides (s and v), 2-stage software
// pipeline: compute edge p with data issued last iteration; issue data for
// p+1 from rec[p+1]; prefetch rec[p+2]. Indices clamped (no divergence).
// Lane owns cols {u0,u0+1} of each 128-half. No LDS, no barriers.
// ---------------------------------------------------------------------------
__global__ __launch_bounds__(256) void k_gather(
    const uint2* __restrict__ recs, const int* __restrict__ offs,
    const unsigned* __restrict__ tpw2, const float* __restrict__ eattr,
    const float* __restrict__ s_up, const float* __restrict__ v_up,
    float* __restrict__ Ms, float* __restrict__ Mv, int N) {
  const int t = threadIdx.x;
  const int n = blockIdx.x * 4 + (t >> 6);
  if (n >= N) return;
  const int l = t & 63;
  const int u0 = l * 2;

  float aMsS0 = 0.f, aMsS1 = 0.f;   // m0 -> Ms[0:128)
  float aMsV0 = 0.f, aMsV1 = 0.f;   // m1 -> Ms[128:256)
  float aVs[3][2] = {};             // m2 -> Mv[i][0:128)
  float aVv[3][2] = {};             // m3 -> Mv[i][128:256)

  const int e0 = offs[n], e1 = offs[n + 1];

  if (e0 < e1) {
    const int last = e1 - 1;
    // prologue: current edge data
    uint2 rec_c = recs[e0];
    uint2 rec_n = recs[min(e0 + 1, last)];
    float4 ea_c = *reinterpret_cast<const float4*>(eattr + (size_t)rec_c.x * 4);
    uint2 qs_c = *reinterpret_cast<const uint2*>(tpw2 + (size_t)rec_c.x * 256 + u0);
    uint2 qv_c = *reinterpret_cast<const uint2*>(tpw2 + (size_t)rec_c.x * 256 + 128 + u0);
    float2 xs_c = *reinterpret_cast<const float2*>(s_up + (size_t)rec_c.y * 128 + u0);
    const float* xvp = v_up + (size_t)rec_c.y * 384 + u0;
    float2 x0_c = *reinterpret_cast<const float2*>(xvp);
    float2 x1_c = *reinterpret_cast<const float2*>(xvp + 128);
    float2 x2_c = *reinterpret_cast<const float2*>(xvp + 256);

    for (int p = e0; p < e1; ++p) {
      // issue next-edge data (clamped; redundant on last iter, cache-hot)
      float4 ea_n = *reinterpret_cast<const float4*>(eattr + (size_t)rec_n.x * 4);
      uint2 qs_n = *reinterpret_cast<const uint2*>(tpw2 + (size_t)rec_n.x * 256 + u0);
      uint2 qv_n = *reinterpret_cast<const uint2*>(tpw2 + (size_t)rec_n.x * 256 + 128 + u0);
      float2 xs_n = *reinterpret_cast<const float2*>(s_up + (size_t)rec_n.y * 128 + u0);
      const float* xvn = v_up + (size_t)rec_n.y * 384 + u0;
      float2 x0_n = *reinterpret_cast<const float2*>(xvn);
      float2 x1_n = *reinterpret_cast<const float2*>(xvn + 128);
      float2 x2_n = *reinterpret_cast<const float2*>(xvn + 256);
      uint2 rec_n2 = recs[min(p + 2, last)];

      // ---- compute with current (in flight since previous iteration) ----
      // s-side: m0 and m2
      {
        float tA0 = __uint_as_float(qs_c.x << 16);
        float tB0 = __uint_as_float(qs_c.x & 0xFFFF0000u);
        float tA1 = __uint_as_float(qs_c.y << 16);
        float tB1 = __uint_as_float(qs_c.y & 0xFFFF0000u);
        aMsS0 += tA0 * xs_c.x * ea_c.x;
        aMsS1 += tA1 * xs_c.y * ea_c.x;
        float wc0 = tB0 * xs_c.x, wc1 = tB1 * xs_c.y;
        aVs[0][0] += wc0 * ea_c.y; aVs[0][1] += wc1 * ea_c.y;
        aVs[1][0] += wc0 * ea_c.z; aVs[1][1] += wc1 * ea_c.z;
        aVs[2][0] += wc0 * ea_c.w; aVs[2][1] += wc1 * ea_c.w;
      }
      // v-side: m1 and m3
      {
        float tA0 = __uint_as_float(qv_c.x << 16);
        float tB0 = __uint_as_float(qv_c.x & 0xFFFF0000u);
        float tA1 = __uint_as_float(qv_c.y << 16);
        float tB1 = __uint_as_float(qv_c.y & 0xFFFF0000u);
        float dot0 = x0_c.x * ea_c.y + x1_c.x * ea_c.z + x2_c.x * ea_c.w;
        float dot1 = x0_c.y * ea_c.y + x1_c.y * ea_c.z + x2_c.y * ea_c.w;
        aMsV0 += tA0 * dot0 * kINV_SQ3;
        aMsV1 += tA1 * dot1 * kINV_SQ3;
        float wd0 = tB0 * ea_c.x, wd1 = tB1 * ea_c.x;
        aVv[0][0] += wd0 * x0_c.x; aVv[0][1] += wd1 * x0_c.y;
        aVv[1][0] += wd0 * x1_c.x; aVv[1][1] += wd1 * x1_c.y;
        aVv[2][0] += wd0 * x2_c.x; aVv[2][1] += wd1 * x2_c.y;
      }

      // rotate pipeline registers
      ea_c = ea_n; qs_c = qs_n; qv_c = qv_n; xs_c = xs_n;
      x0_c = x0_n; x1_c = x1_n; x2_c = x2_n;
      rec_n = rec_n2;
    }
  }

  *reinterpret_cast<float2*>(Ms + (size_t)n * 256 + u0)       = make_float2(aMsS0, aMsS1);
  *reinterpret_cast<float2*>(Ms + (size_t)n * 256 + 128 + u0) = make_float2(aMsV0, aMsV1);
#pragma unroll
  for (int i = 0; i < 3; ++i) {
    *reinterpret_cast<float2*>(Mv + (size_t)n * 768 + i * 256 + u0) =
        make_float2(aVs[i][0], aVs[i][1]);
    *reinterpret_cast<float2*>(Mv + (size_t)n * 768 + i * 256 + 128 + u0) =
        make_float2(aVv[i][0], aVv[i][1]);
  }
}

// ---------------------------------------------------------------------------
// K5 (MFMA): fused lin + skip + combine (unchanged — passed).
// ---------------------------------------------------------------------------
__global__ __launch_bounds__(256) void k_linskip(
    const float* __restrict__ Ms, const float* __restrict__ Mv,
    const short* __restrict__ Wl0T, const short* __restrict__ Wl1T,
    const short* __restrict__ Wsk0T, const short* __restrict__ Wsk1T,
    const float* __restrict__ attrs, const float* __restrict__ upd,
    float* __restrict__ out, int N) {
  __shared__ __align__(16) short lsA[4][16][264];
  __shared__ __align__(16) short lsS[4][16][136];
  __shared__ float sat[16][4];
  const int nb = blockIdx.x * 16;
  const int t = threadIdx.x;

  for (int base = t * 4; base < 16 * 1024; base += 1024) {
    int n = base >> 10, j = base & 1023;
    int comp = j >> 8, u = j & 255;
    float4 q = {0.f, 0.f, 0.f, 0.f};
    if (nb + n < N) {
      const float* src = (comp == 0) ? (Ms + (size_t)(nb + n) * 256 + u)
                                     : (Mv + (size_t)(nb + n) * 768 + (size_t)(comp - 1) * 256 + u);
      q = *reinterpret_cast<const float4*>(src);
    }
    lsA[comp][n][u + 0] = f2bf(q.x);
    lsA[comp][n][u + 1] = f2bf(q.y);
    lsA[comp][n][u + 2] = f2bf(q.z);
    lsA[comp][n][u + 3] = f2bf(q.w);
  }
  if (t < 64) {
    int n = t >> 2, v = t & 3;
    sat[n][v] = (nb + n < N) ? attrs[(size_t)(nb + n) * 4 + v] : 0.f;
  }
  __syncthreads();

  const int c = t >> 6;
  const int lane = t & 63;
  const int col = lane & 15;
  const int g = lane >> 4;

  const short* WLT = c ? Wl1T : Wl0T;
  const short* WST = c ? Wsk1T : Wsk0T;

  bf16x8 af1[8];
#pragma unroll
  for (int kk = 0; kk < 8; ++kk)
    af1[kk] = *reinterpret_cast<const bf16x8*>(&lsA[c][col][kk * 32 + g * 8]);

  f32x4 Sreg[8];
#pragma unroll
  for (int nt = 0; nt < 8; ++nt) {
    f32x4 acc = {0.f, 0.f, 0.f, 0.f};
#pragma unroll
    for (int kk = 0; kk < 8; ++kk) {
      bf16x8 bf = *reinterpret_cast<const bf16x8*>(&WLT[(size_t)(nt * 16 + col) * 256 + kk * 32 + g * 8]);
      acc = __builtin_amdgcn_mfma_f32_16x16x32_bf16(af1[kk], bf, acc, 0, 0, 0);
    }
#pragma unroll
    for (int r = 0; r < 4; ++r) acc[r] *= kINV_LIN;
    Sreg[nt] = acc;
#pragma unroll
    for (int r = 0; r < 4; ++r)
      lsS[c][g * 4 + r][nt * 16 + col] = f2bf(acc[r]);
  }

  float satr[4][4];
#pragma unroll
  for (int r = 0; r < 4; ++r)
#pragma unroll
    for (int v = 0; v < 4; ++v) satr[r][v] = sat[g * 4 + r][v];

  __syncthreads();

  bf16x8 af2[4];
#pragma unroll
  for (int kk = 0; kk < 4; ++kk)
    af2[kk] = *reinterpret_cast<const bf16x8*>(&lsS[c][col][kk * 32 + g * 8]);

  const float p = upd[0];
  const float cc = 1.f / (1.f + __expf(-p));
  const float c_old = rsqrtf(cc * cc + 1.f);
  const float c_new = cc * c_old;

#pragma unroll
  for (int nt = 0; nt < 8; ++nt) {
    float fin[4] = {0.f, 0.f, 0.f, 0.f};
#pragma unroll
    for (int v = 0; v < 4; ++v) {
      f32x4 tmp = {0.f, 0.f, 0.f, 0.f};
#pragma unroll
      for (int kk = 0; kk < 4; ++kk) {
        bf16x8 bf = *reinterpret_cast<const bf16x8*>(&WST[(size_t)(nt * 16 + col) * 512 + v * 128 + kk * 32 + g * 8]);
        tmp = __builtin_amdgcn_mfma_f32_16x16x32_bf16(af2[kk], bf, tmp, 0, 0, 0);
      }
#pragma unroll
      for (int r = 0; r < 4; ++r) fin[r] += satr[r][v] * tmp[r];
    }
#pragma unroll
    for (int r = 0; r < 4; ++r) {
      int nd = nb + g * 4 + r;
      if (nd < N) {
        float val = c_old * Sreg[nt][r] + c_new * fin[r] * kINV_SK;
        out[((size_t)nd * 128 + nt * 16 + col) * 4 + c] = val;
      }
    }
  }
}

extern "C" void kernel_launch(void* const* d_in, const int* in_sizes, int n_in,
                              void* d_out, int out_size, void* d_ws, size_t ws_size,
                              hipStream_t stream) {
  const float* node_attrs = (const float*)d_in[0];
  const float* node_feats = (const float*)d_in[1];
  const float* edge_attrs = (const float*)d_in[2];
  const float* edge_feats = (const float*)d_in[3];
  const int*   edge_index = (const int*)d_in[4];
  const float* W_up0  = (const float*)d_in[5];
  const float* W_up1  = (const float*)d_in[6];
  const float* W_mlp1 = (const float*)d_in[7];
  const float* W_mlp2 = (const float*)d_in[8];
  const float* W_mlp3 = (const float*)d_in[9];
  const float* W_lin0 = (const float*)d_in[10];
  const float* W_lin1 = (const float*)d_in[11];
  const float* W_skip0 = (const float*)d_in[12];
  const float* W_skip1 = (const float*)d_in[13];
  const float* upd = (const float*)d_in[14];
  float* out = (float*)d_out;

  const int N = in_sizes[0] / 4;
  const int E = in_sizes[4] / 2;

  float* ws = (float*)d_ws;
  float* s_up = ws;                          // N*128
  float* v_up = s_up + (size_t)N * 128;      // N*384  [n][i][u]
  float* Ms   = v_up + (size_t)N * 384;      // N*256
  float* Mv   = Ms + (size_t)N * 256;        // N*768  [n][i][u]
  int* cnt    = (int*)(Mv + (size_t)N * 768); // N
  int* offs   = cnt + N;                      // N+1
  int* cursor = offs + N + 1;                 // N
  uint2* recs = (uint2*)((((uintptr_t)(cursor + N)) + 7) & ~(uintptr_t)7);  // E uint2

  short* wbase = (short*)((((uintptr_t)(recs + E)) + 15) & ~(uintptr_t)15);
  short* W0T   = wbase;            // 128*128
  short* W1T   = W0T + 16384;      // 128*128
  short* Wl0T  = W1T + 16384;      // 128*256
  short* Wl1T  = Wl0T + 32768;     // 128*256
  short* Wsk0T = Wl1T + 32768;     // 128*512
  short* Wsk1T = Wsk0T + 65536;    // 128*512
  short* W2T   = Wsk1T + 65536;    // 64*64
  short* W3T   = W2T + 4096;       // 512*64
  unsigned* tpw2 = (unsigned*)(W3T + 32768); // E*256 dwords

  const int CVT_B = (266240 + 255) / 256;      // 1040
  const int CNT_B = (E + 255) / 256;
  const int MLP_B = (E + 127) / 128;
  const int UP_B  = (N + 15) / 16;
  const int SC_B  = (E + 255) / 256;

  hipMemsetAsync(cnt, 0, (size_t)N * sizeof(int), stream);

  k_cvtcnt<<<CVT_B + CNT_B, 256, 0, stream>>>(
      W_up0, W_up1, W_lin0, W_lin1, W_skip0, W_skip1, W_mlp2, W_mlp3,
      W0T, W1T, Wl0T, Wl1T, Wsk0T, Wsk1T, W2T, W3T,
      edge_index, cnt, E, CVT_B);
  k_scan<<<1, 1024, 0, stream>>>(cnt, offs, cursor, N);
  k_fused3<<<MLP_B + UP_B + SC_B, 256, 0, stream>>>(
      edge_index, cursor, recs,
      node_feats, W0T, W1T, s_up, v_up,
      edge_feats, W_mlp1, W2T, W3T, tpw2, N, E, MLP_B, UP_B);
  k_gather<<<(N + 3) / 4, 256, 0, stream>>>(recs, offs, tpw2, edge_attrs,
                                            s_up, v_up, Ms, Mv, N);
  k_linskip<<<(N + 15) / 16, 256, 0, stream>>>(Ms, Mv, Wl0T, Wl1T, Wsk0T, Wsk1T,
                                               node_attrs, upd, out, N);
}